// Round 11
// baseline (158.036 us; speedup 1.0000x reference)
//
#include <hip/hip_runtime.h>
#include <math.h>

// Problem constants (ShowAttendTellCore)
//   B=1024, D_MODEL=512, N_HEADS=8, D_HEAD=64, N_LEVELS=4, N_POINTS=4
//   T_TOTAL=1920, RNN=512, ENC=512, ATT_HID=512
// Output layout (f32): h2 (524288) | h1 | h2 | c1 | c2   (total 2621440)

typedef __attribute__((ext_vector_type(8))) short          s16x8;
typedef __attribute__((ext_vector_type(8))) unsigned short u16x8;
typedef __attribute__((ext_vector_type(4))) float          f32x4;

#define LOG2E  1.4426950408889634f
#define LOG2E2 2.8853900817779268f

__device__ __forceinline__ float rcpf(float x) { return __builtin_amdgcn_rcpf(x); }
__device__ __forceinline__ float exp2f_fast(float x) { return __builtin_amdgcn_exp2f(x); }
__device__ __forceinline__ float sigf(float x) {
    return rcpf(1.0f + exp2f_fast(-x * LOG2E));
}
__device__ __forceinline__ float tanhf_fast(float x) {
    const float xc = fminf(fmaxf(x, -15.0f), 15.0f);
    const float e2 = exp2f_fast(xc * LOG2E2);
    return 1.0f - 2.0f * rcpf(e2 + 1.0f);
}
__device__ __forceinline__ unsigned short f2bf(float f) {   // RNE f32->bf16
    unsigned u = __float_as_uint(f);
    u += 0x7FFF + ((u >> 16) & 1);
    return (unsigned short)(u >> 16);
}
__device__ __forceinline__ float bf2f(unsigned short h) {
    return __uint_as_float(((unsigned)h) << 16);
}
// async global->LDS, 16B per lane
__device__ __forceinline__ void gld_lds16(const unsigned short* g, unsigned short* l) {
    __builtin_amdgcn_global_load_lds(
        (const __attribute__((address_space(1))) void*)g,
        (__attribute__((address_space(3))) void*)l, 16, 0, 0);
}

// ---------------- batched f32 -> bf16 strided converts (one launch) --------
// ilv != 0: LSTM gate-interleave of dst rows: row' = (row%512)*4 + row/512.
struct CvtJob { const float* src; unsigned short* dst; int sld, dld, cols, total, ilv; };
struct CvtJobs { CvtJob j[11]; };
__global__ __launch_bounds__(256) void cvt_bf16(CvtJobs cj) {
    const CvtJob jb = cj.j[blockIdx.y];
    const int i = (blockIdx.x * 256 + threadIdx.x) * 4;
    if (i >= jb.total) return;
    const int r = i / jb.cols, c = i - r * jb.cols;
    const int rd = jb.ilv ? (((r & 511) << 2) | (r >> 9)) : r;
    const float4 v4 = *(const float4*)&jb.src[(size_t)r * jb.sld + c];
    ushort4 o;
    o.x = f2bf(v4.x); o.y = f2bf(v4.y); o.z = f2bf(v4.z); o.w = f2bf(v4.w);
    *(ushort4*)&jb.dst[(size_t)rd * jb.dld + c] = o;
}

// transpose-convert via 32x32 LDS tile; src==nullptr -> zeros.
struct TJob { const float* src; unsigned short* dst; int N_, dld, K_, total; };
struct TJobs { TJob j[6]; };
__global__ __launch_bounds__(256) void tcvt_bf16(TJobs tj) {
    const TJob jb = tj.j[blockIdx.y];
    const int tilesN = jb.N_ >> 5, tilesK = jb.K_ >> 5;
    const int tile = blockIdx.x;
    if (tile >= tilesN * tilesK) return;
    const int tn0 = (tile % tilesN) << 5, tk0 = (tile / tilesN) << 5;
    __shared__ float lds[32][33];
    const int t = threadIdx.x;
    if (jb.src) {
#pragma unroll
        for (int q = 0; q < 4; ++q) {
            const int e = t + (q << 8);
            lds[e >> 5][e & 31] = jb.src[(size_t)(tk0 + (e >> 5)) * jb.N_ + tn0 + (e & 31)];
        }
        __syncthreads();
#pragma unroll
        for (int q = 0; q < 4; ++q) {
            const int e = t + (q << 8);
            const int n = e >> 5, k = e & 31;
            jb.dst[(size_t)(tn0 + n) * jb.dld + tk0 + k] = f2bf(lds[k][n]);
        }
    } else {
#pragma unroll
        for (int q = 0; q < 4; ++q) {
            const int e = t + (q << 8);
            jb.dst[(size_t)(tn0 + (e >> 5)) * jb.dld + tk0 + (e & 31)] = 0;
        }
    }
}

// bcat = [boff(128) | battw(128) | bh2a(512)]
__global__ __launch_bounds__(768) void bias_cat3(const float* __restrict__ a,
                                                 const float* __restrict__ b,
                                                 const float* __restrict__ c,
                                                 float* __restrict__ dst) {
    const int t = threadIdx.x;
    dst[t] = (t < 128) ? a[t] : (t < 256 ? b[t - 128] : c[t - 256]);
}

// ===== 3-deep pipelined staging (T3/T4): counted vmcnt + RAW s_barrier =====
// __syncthreads() would force a compiler-emitted vmcnt(0) drain each step
// (the m97 stall); raw s_barrier + explicit counted vmcnt keeps the next
// tile's 3 loads in flight across the barrier.

// ---------------- LDS-staged bf16 MFMA GEMM ---------------------------------
// C(MxN f32) = A(MxK bf16 rm) @ B^T (B NxK bf16 rm) + bias
// BM=64 BN=128 BK=32; grid=(N/128, M/64); 4 waves (2x2), wave=32x64.
__global__ __launch_bounds__(256) void sgemm(
    const unsigned short* __restrict__ A, int lda,
    const unsigned short* __restrict__ B, int ldb,
    const float* __restrict__ bias, float* __restrict__ C, int ldc, int K)
{
    __shared__ unsigned short As[3][64 * 32];    // 12 KB
    __shared__ unsigned short Bs[3][128 * 32];   // 24 KB

    const int tid = threadIdx.x;
    const int w = tid >> 6, lane = tid & 63;
    const int wr = w >> 1, wc = w & 1;
    const int lr = lane & 15, lg = lane >> 4;
    const int bm = blockIdx.y, bn = blockIdx.x;

    const int srow = tid >> 2, sk = (tid & 3) << 3;
    const unsigned short* Ag  = A + (size_t)(bm * 64 + srow) * lda + sk;
    const unsigned short* Bg0 = B + (size_t)(bn * 128 + srow) * ldb + sk;
    const unsigned short* Bg1 = B + (size_t)(bn * 128 + 64 + srow) * ldb + sk;

    f32x4 acc[2][4];
#pragma unroll
    for (int mt = 0; mt < 2; ++mt)
#pragma unroll
        for (int nt = 0; nt < 4; ++nt) acc[mt][nt] = (f32x4){0.f, 0.f, 0.f, 0.f};

    const int nsteps = K >> 5;
    // prologue: stage tiles 0 and 1
    gld_lds16(Ag,  &As[0][tid * 8]);
    gld_lds16(Bg0, &Bs[0][tid * 8]);
    gld_lds16(Bg1, &Bs[0][2048 + tid * 8]);
    if (nsteps > 1) {
        gld_lds16(Ag + 32,  &As[1][tid * 8]);
        gld_lds16(Bg0 + 32, &Bs[1][tid * 8]);
        gld_lds16(Bg1 + 32, &Bs[1][2048 + tid * 8]);
        asm volatile("s_waitcnt vmcnt(3)" ::: "memory");   // tile0 resident
    } else {
        asm volatile("s_waitcnt vmcnt(0)" ::: "memory");
    }
    __builtin_amdgcn_s_barrier();

    int cur = 0;
    for (int t = 0; t < nsteps; ++t) {
        if (t + 2 < nsteps) {                 // stage tile t+2 into buf (cur+2)%3
            const int bw = (cur >= 1) ? cur - 1 : 2;
            const int kk = (t + 2) << 5;
            gld_lds16(Ag + kk,  &As[bw][tid * 8]);
            gld_lds16(Bg0 + kk, &Bs[bw][tid * 8]);
            gld_lds16(Bg1 + kk, &Bs[bw][2048 + tid * 8]);
        }
        const unsigned short* Ab = &As[cur][0];
        const unsigned short* Bb = &Bs[cur][0];
        s16x8 a[2], bfr[4];
#pragma unroll
        for (int mt = 0; mt < 2; ++mt)
            a[mt] = *(const s16x8*)&Ab[(wr * 32 + mt * 16 + lr) * 32 + lg * 8];
#pragma unroll
        for (int nt = 0; nt < 4; ++nt)
            bfr[nt] = *(const s16x8*)&Bb[(wc * 64 + nt * 16 + lr) * 32 + lg * 8];
#pragma unroll
        for (int mt = 0; mt < 2; ++mt)
#pragma unroll
            for (int nt = 0; nt < 4; ++nt)
                acc[mt][nt] = __builtin_amdgcn_mfma_f32_16x16x32_bf16(
                    a[mt], bfr[nt], acc[mt][nt], 0, 0, 0);
        if (t + 1 < nsteps) {
            if (t + 2 < nsteps) asm volatile("s_waitcnt vmcnt(3)" ::: "memory");
            else                asm volatile("s_waitcnt vmcnt(0)" ::: "memory");
            __builtin_amdgcn_s_barrier();
        }
        cur = (cur < 2) ? cur + 1 : 0;
    }
#pragma unroll
    for (int nt = 0; nt < 4; ++nt) {
        const int col = bn * 128 + wc * 64 + nt * 16 + lr;
        const float bb = bias ? bias[col] : 0.0f;
#pragma unroll
        for (int mt = 0; mt < 2; ++mt) {
            const int rbase = bm * 64 + wr * 32 + mt * 16 + lg * 4;
#pragma unroll
            for (int r = 0; r < 4; ++r)
                C[(size_t)(rbase + r) * ldc + col] = acc[mt][nt][r] + bb;
        }
    }
}

// ---------------- 3-deep pipelined GEMM + fused LSTM epilogue --------------
// B rows gate-interleaved (col = 4*unit + gate, gate order i,f,g,o).
__global__ __launch_bounds__(256) void sgemm_lstm(
    const unsigned short* __restrict__ A, int lda,
    const unsigned short* __restrict__ B, int ldb,
    const float* __restrict__ c_in,
    float* __restrict__ h_a, float* __restrict__ h_b,
    unsigned short* __restrict__ hbf, int hbf_ld,
    float* __restrict__ c_out, int K)
{
    __shared__ unsigned short As[3][64 * 32];
    __shared__ unsigned short Bs[3][128 * 32];

    const int tid = threadIdx.x;
    const int w = tid >> 6, lane = tid & 63;
    const int wr = w >> 1, wc = w & 1;
    const int lr = lane & 15, lg = lane >> 4;
    const int bm = blockIdx.y, bn = blockIdx.x;

    const int srow = tid >> 2, sk = (tid & 3) << 3;
    const unsigned short* Ag  = A + (size_t)(bm * 64 + srow) * lda + sk;
    const unsigned short* Bg0 = B + (size_t)(bn * 128 + srow) * ldb + sk;
    const unsigned short* Bg1 = B + (size_t)(bn * 128 + 64 + srow) * ldb + sk;

    f32x4 acc[2][4];
#pragma unroll
    for (int mt = 0; mt < 2; ++mt)
#pragma unroll
        for (int nt = 0; nt < 4; ++nt) acc[mt][nt] = (f32x4){0.f, 0.f, 0.f, 0.f};

    const int nsteps = K >> 5;
    gld_lds16(Ag,  &As[0][tid * 8]);
    gld_lds16(Bg0, &Bs[0][tid * 8]);
    gld_lds16(Bg1, &Bs[0][2048 + tid * 8]);
    if (nsteps > 1) {
        gld_lds16(Ag + 32,  &As[1][tid * 8]);
        gld_lds16(Bg0 + 32, &Bs[1][tid * 8]);
        gld_lds16(Bg1 + 32, &Bs[1][2048 + tid * 8]);
        asm volatile("s_waitcnt vmcnt(3)" ::: "memory");
    } else {
        asm volatile("s_waitcnt vmcnt(0)" ::: "memory");
    }
    __builtin_amdgcn_s_barrier();

    int cur = 0;
    for (int t = 0; t < nsteps; ++t) {
        if (t + 2 < nsteps) {
            const int bw = (cur >= 1) ? cur - 1 : 2;
            const int kk = (t + 2) << 5;
            gld_lds16(Ag + kk,  &As[bw][tid * 8]);
            gld_lds16(Bg0 + kk, &Bs[bw][tid * 8]);
            gld_lds16(Bg1 + kk, &Bs[bw][2048 + tid * 8]);
        }
        const unsigned short* Ab = &As[cur][0];
        const unsigned short* Bb = &Bs[cur][0];
        s16x8 a[2], bfr[4];
#pragma unroll
        for (int mt = 0; mt < 2; ++mt)
            a[mt] = *(const s16x8*)&Ab[(wr * 32 + mt * 16 + lr) * 32 + lg * 8];
#pragma unroll
        for (int nt = 0; nt < 4; ++nt)
            bfr[nt] = *(const s16x8*)&Bb[(wc * 64 + nt * 16 + lr) * 32 + lg * 8];
#pragma unroll
        for (int mt = 0; mt < 2; ++mt)
#pragma unroll
            for (int nt = 0; nt < 4; ++nt)
                acc[mt][nt] = __builtin_amdgcn_mfma_f32_16x16x32_bf16(
                    a[mt], bfr[nt], acc[mt][nt], 0, 0, 0);
        if (t + 1 < nsteps) {
            if (t + 2 < nsteps) asm volatile("s_waitcnt vmcnt(3)" ::: "memory");
            else                asm volatile("s_waitcnt vmcnt(0)" ::: "memory");
            __builtin_amdgcn_s_barrier();
        }
        cur = (cur < 2) ? cur + 1 : 0;
    }
    // epilogue: col = bn*128 + wc*64 + nt*16 + lr; gate = col&3 = lane&3
    const int gte  = lane & 3;
    const int base = lane & ~3;
#pragma unroll
    for (int nt = 0; nt < 4; ++nt) {
        const int col = bn * 128 + wc * 64 + nt * 16 + lr;
        const int u = col >> 2;     // unit index in [0,512)
#pragma unroll
        for (int mt = 0; mt < 2; ++mt) {
            const int rbase = bm * 64 + wr * 32 + mt * 16 + lg * 4;
#pragma unroll
            for (int r = 0; r < 4; ++r) {
                const float vv = acc[mt][nt][r];
                const float a  = (gte == 2) ? tanhf_fast(vv) : sigf(vv);
                const float ai = __shfl(a, base + 0);
                const float af = __shfl(a, base + 1);
                const float ag = __shfl(a, base + 2);
                const float ao = __shfl(a, base + 3);
                const int row = rbase + r;
                const float c  = c_in[(size_t)row * 512 + u];
                const float c2 = af * c + ai * ag;
                const float h2 = ao * tanhf_fast(c2);
                if (gte == 0)      c_out[(size_t)row * 512 + u] = c2;
                else if (gte == 1) h_a[(size_t)row * 512 + u] = h2;
                else if (gte == 2) { if (h_b) h_b[(size_t)row * 512 + u] = h2; }
                else if (hbf)      hbf[(size_t)row * hbf_ld + u] = f2bf(h2);
            }
        }
    }
}

// ---------------- direct-global bf16 MFMA GEMM (small GEMMs only) ----------
__global__ __launch_bounds__(256) void mgemm(
    const unsigned short* __restrict__ A, int lda,
    const unsigned short* __restrict__ B, int ldb,
    const float* __restrict__ bias, float* __restrict__ C, int ldc, int K)
{
    const int tid = threadIdx.x;
    const int w = tid >> 6, lane = tid & 63;
    const int wm = w >> 1, wn = w & 1;
    const int lr = lane & 15, lg = lane >> 4;
    const int row0 = blockIdx.y * 64 + wm * 32;
    const int col0 = blockIdx.x * 64 + wn * 32;

    const unsigned short* Ap = A + (size_t)(row0 + lr) * lda + lg * 8;
    const unsigned short* Bp = B + (size_t)(col0 + lr) * ldb + lg * 8;

    f32x4 acc[2][2];
#pragma unroll
    for (int mt = 0; mt < 2; ++mt)
#pragma unroll
        for (int nt = 0; nt < 2; ++nt) acc[mt][nt] = (f32x4){0.f, 0.f, 0.f, 0.f};

    for (int k0 = 0; k0 < K; k0 += 64) {
        s16x8 a[2][2], bf[2][2];
#pragma unroll
        for (int mt = 0; mt < 2; ++mt)
#pragma unroll
            for (int u = 0; u < 2; ++u)
                a[mt][u] = *(const s16x8*)&Ap[(size_t)mt * 16 * lda + k0 + u * 32];
#pragma unroll
        for (int nt = 0; nt < 2; ++nt)
#pragma unroll
            for (int u = 0; u < 2; ++u)
                bf[nt][u] = *(const s16x8*)&Bp[(size_t)nt * 16 * ldb + k0 + u * 32];
#pragma unroll
        for (int u = 0; u < 2; ++u)
#pragma unroll
            for (int mt = 0; mt < 2; ++mt)
#pragma unroll
                for (int nt = 0; nt < 2; ++nt)
                    acc[mt][nt] = __builtin_amdgcn_mfma_f32_16x16x32_bf16(
                        a[mt][u], bf[nt][u], acc[mt][nt], 0, 0, 0);
    }
#pragma unroll
    for (int nt = 0; nt < 2; ++nt) {
        const int col = col0 + nt * 16 + lr;
        const float bb = bias ? bias[col] : 0.0f;
#pragma unroll
        for (int mt = 0; mt < 2; ++mt) {
            const int rbase = row0 + mt * 16 + lg * 4;
#pragma unroll
            for (int r = 0; r < 4; ++r)
                C[(size_t)(rbase + r) * ldc + col] = acc[mt][nt][r] + bb;
        }
    }
}

// ---------------- fused deformable sampling + context attention ------------
// obat (B,768) = [off(128) | aw_raw(128) | atth(512)]  (biases included)
__global__ __launch_bounds__(512, 2) void fused_att(
    const float* __restrict__ v,       // (1920, 512)
    const float* __restrict__ obat,    // (B, 768)
    const float* __restrict__ refp,    // (B, 4)
    const int*   __restrict__ shapes,  // (4,)
    const int*   __restrict__ starts,  // (4,)
    const unsigned short* __restrict__ Wb,  // (512, 64) bf16, = Wctx^T
    const float* __restrict__ bctx,    // (512,)
    const float* __restrict__ walpha,  // (512,)
    unsigned short* __restrict__ attdst)    // bf16, row stride 2048
{
    __shared__ unsigned short cf[128 * 64];   // 16 KB, XOR chunk-swizzled
    __shared__ float ba[512];                 // bctx + atth[b]
    __shared__ float wal[512];
    __shared__ float awb[128];
    __shared__ float dsum[128];
    __shared__ float dots4[4][128];

    const int b   = blockIdx.x;
    const int tid = threadIdx.x;

    // phase 0: attention-weight softmax (16 per head)
    if (tid < 128) awb[tid] = obat[b * 768 + 128 + tid];
    __syncthreads();
    if (tid < 8) {
        float mx = -1e30f;
        for (int i = 0; i < 16; ++i) mx = fmaxf(mx, awb[tid * 16 + i]);
        float sum = 0.f;
        for (int i = 0; i < 16; ++i) { float e = exp2f_fast((awb[tid * 16 + i] - mx) * LOG2E); awb[tid * 16 + i] = e; sum += e; }
        float inv = rcpf(sum);
        for (int i = 0; i < 16; ++i) awb[tid * 16 + i] *= inv;
    }
    __syncthreads();

    // phase 1: bilinear sampling -> cf[p][d] = bf16(samp[d] * aw[p]); stage ba/wal
    ba[tid]  = bctx[tid] + obat[b * 768 + 256 + tid];
    wal[tid] = walpha[tid];
    {
        const int pg  = tid >> 2;
        const int sub = tid & 3;
        const int d0  = sub * 16;
        const int h   = pg >> 4;
        const int l   = (pg & 15) >> 2;
        const int Tlen = shapes[l];
        const int st   = starts[l];
        const float T  = (float)Tlen;
        const float refv = refp[b * 4 + l];
        const float offv = obat[b * 768 + pg];
        const float awv  = awb[pg];
        const float x   = (refv + offv * rcpf(T)) * T - 0.5f;  // exact: T is 2^k
        const float x0f = floorf(x);
        const float w1  = x - x0f;
        const int   x0  = (int)x0f;
        const float w0s = (x0 >= 0 && x0 < Tlen) ? (1.0f - w1) : 0.0f;
        const float w1s = (x0 + 1 >= 0 && x0 + 1 < Tlen) ? w1 : 0.0f;
        const int i0 = (min(max(x0, 0), Tlen - 1) + st) * 512 + h * 64;
        const int i1 = (min(max(x0 + 1, 0), Tlen - 1) + st) * 512 + h * 64;
        u16x8 o0, o1;
#pragma unroll
        for (int q = 0; q < 4; ++q) {
            const float4 a  = *(const float4*)&v[i0 + d0 + q * 4];
            const float4 bq = *(const float4*)&v[i1 + d0 + q * 4];
            unsigned short e0 = f2bf((a.x * w0s + bq.x * w1s) * awv);
            unsigned short e1 = f2bf((a.y * w0s + bq.y * w1s) * awv);
            unsigned short e2 = f2bf((a.z * w0s + bq.z * w1s) * awv);
            unsigned short e3 = f2bf((a.w * w0s + bq.w * w1s) * awv);
            if (q == 0) { o0[0] = e0; o0[1] = e1; o0[2] = e2; o0[3] = e3; }
            if (q == 1) { o0[4] = e0; o0[5] = e1; o0[6] = e2; o0[7] = e3; }
            if (q == 2) { o1[0] = e0; o1[1] = e1; o1[2] = e2; o1[3] = e3; }
            if (q == 3) { o1[4] = e0; o1[5] = e1; o1[6] = e2; o1[7] = e3; }
        }
        const int c0 = (sub * 2)     ^ (pg & 7);
        const int c1 = (sub * 2 + 1) ^ (pg & 7);
        *(u16x8*)&cf[pg * 64 + c0 * 8] = o0;
        *(u16x8*)&cf[pg * 64 + c1 * 8] = o1;
    }
    __syncthreads();

    // phase 2: dots[p] = sum_j tanh((cf@Wctx)[p][j] + ba[j]) * wal[j]  via MFMA
    {
        const int w    = tid >> 6, lane = tid & 63;
        const int wm   = w >> 2, wn = w & 3;
        const int lr   = lane & 15, lg = lane >> 4;

        s16x8 afrag[4][2];
#pragma unroll
        for (int mt = 0; mt < 4; ++mt) {
            const int row = wm * 64 + mt * 16 + lr;
#pragma unroll
            for (int ks = 0; ks < 2; ++ks) {
                const int ch = (ks * 4 + lg) ^ (row & 7);
                afrag[mt][ks] = *(const s16x8*)&cf[row * 64 + ch * 8];
            }
        }
        f32x4 part[4];
#pragma unroll
        for (int mt = 0; mt < 4; ++mt) part[mt] = (f32x4){0.f, 0.f, 0.f, 0.f};

#pragma clang loop unroll(disable)
        for (int nt = 0; nt < 8; ++nt) {
            const int ct  = wn * 8 + nt;
            const int col = ct * 16 + lr;
            const s16x8 b0 = *(const s16x8*)&Wb[col * 64 + lg * 8];
            const s16x8 b1 = *(const s16x8*)&Wb[col * 64 + 32 + lg * 8];
            const float bav = ba[col], wav = wal[col];
#pragma unroll
            for (int mt = 0; mt < 4; ++mt) {
                f32x4 acc = {0.f, 0.f, 0.f, 0.f};
                acc = __builtin_amdgcn_mfma_f32_16x16x32_bf16(afrag[mt][0], b0, acc, 0, 0, 0);
                acc = __builtin_amdgcn_mfma_f32_16x16x32_bf16(afrag[mt][1], b1, acc, 0, 0, 0);
#pragma unroll
                for (int r = 0; r < 4; ++r)
                    part[mt][r] += tanhf_fast(acc[r] + bav) * wav;
            }
        }
#pragma unroll
        for (int mt = 0; mt < 4; ++mt) {
#pragma unroll
            for (int r = 0; r < 4; ++r) {
                float s = part[mt][r];
                s += __shfl_xor(s, 1); s += __shfl_xor(s, 2);
                s += __shfl_xor(s, 4); s += __shfl_xor(s, 8);
                if (lr == 0) dots4[wn][wm * 64 + mt * 16 + lg * 4 + r] = s;
            }
        }
    }
    __syncthreads();
    if (tid < 128)
        dsum[tid] = dots4[0][tid] + dots4[1][tid] + dots4[2][tid] + dots4[3][tid];
    __syncthreads();

    // phase 3: softmax over the 16 points of each head
    if (tid < 8) {
        float mx = -1e30f;
        for (int i = 0; i < 16; ++i) mx = fmaxf(mx, dsum[tid * 16 + i]);
        float sum = 0.f;
        for (int i = 0; i < 16; ++i) { float e = exp2f_fast((dsum[tid * 16 + i] - mx) * LOG2E); dsum[tid * 16 + i] = e; sum += e; }
        float inv = rcpf(sum);
        for (int i = 0; i < 16; ++i) dsum[tid * 16 + i] *= inv;
    }
    __syncthreads();

    // phase 4: att_res (bf16 into Acat)
    {
        const int h = tid >> 6, d = tid & 63;
        const int ch = d >> 3, e = d & 7;
        float s = 0.f;
#pragma unroll
        for (int p = 0; p < 16; ++p) {
            const int row = h * 16 + p;
            s += dsum[h * 16 + p] * bf2f(cf[row * 64 + ((ch ^ (row & 7)) * 8) + e]);
        }
        attdst[(size_t)b * 2048 + tid] = f2bf(s);
    }
}

extern "C" void kernel_launch(void* const* d_in, const int* in_sizes, int n_in,
                              void* d_out, int out_size, void* d_ws, size_t ws_size,
                              hipStream_t stream) {
    const float* xt     = (const float*)d_in[0];
    const float* h0     = (const float*)d_in[1];   // (2,1024,512)
    const float* c0     = (const float*)d_in[2];
    const float* query  = (const float*)d_in[3];   // (1,1024,512)
    const float* refp   = (const float*)d_in[4];   // (1,1024,4,1)
    const float* inflat = (const float*)d_in[5];   // (1,1920,512)
    const int*   shapes = (const int*)d_in[6];
    const int*   starts = (const int*)d_in[7];
    const float* Wv     = (const float*)d_in[9];   // (512,512) (K,N)
    const float* bv     = (const float*)d_in[10];
    const float* Woff   = (const float*)d_in[11];  // (1024,128) (K,N)
    const float* boff   = (const float*)d_in[12];
    const float* Wattw  = (const float*)d_in[13];  // (1024,128)
    const float* battw  = (const float*)d_in[14];
    const float* Wctx   = (const float*)d_in[15];  // (64,512)
    const float* bctx   = (const float*)d_in[16];
    const float* Wh2a   = (const float*)d_in[17];  // (512,512) (K,N)
    const float* bh2a   = (const float*)d_in[18];
    const float* walpha = (const float*)d_in[19];
    const float* Wih0   = (const float*)d_in[21];  // (2048,1536) (N,K)
    const float* Whh0   = (const float*)d_in[22];  // (2048,512)
    const float* Wih1   = (const float*)d_in[23];  // (2048,512)
    const float* Whh1   = (const float*)d_in[24];  // (2048,512)

    float* out = (float*)d_out;
    float* ws  = (float*)d_ws;

    // ws layout (f32 units), lifetime-overlapped
    float*          v     = ws;                                   // 983040
    float*          obat  = ws + 983040;                          // 1024x768 [off|aw|atth]
    unsigned short* Acat  = (unsigned short*)(ws + 1769472);      // 1024x2048 bf16
    unsigned short* Bcat0 = (unsigned short*)(ws + 2818048);      // 2048x2048 bf16 (gate-ilv)
    unsigned short* Ainf  = (unsigned short*)(ws + 4915200);      // 1920x512 bf16
    unsigned short* Wvt   = (unsigned short*)(ws + 5406720);      // 512x512 bf16
    unsigned short* Wcat  = (unsigned short*)(ws + 5537792);      // 768x1024 bf16
    unsigned short* Ahq   = (unsigned short*)(ws + 5931008);      // 1024x1024 bf16
    unsigned short* Wb    = (unsigned short*)(ws + 6455296);      // 512x64 bf16 (Wctx^T)
    float*          bcat  = ws + 6471680;                         // 768
    unsigned short* Ag1   = (unsigned short*)(ws + 7012352);      // 1024x1024 bf16
    unsigned short* Bcat1 = (unsigned short*)(ws + 7536640);      // 2048x1024 bf16 (gate-ilv)

    const float* h00    = h0;
    const float* h_last = h0 + 524288;     // h0[1]
    float* h1  = out + 524288;             // h_new[0]
    float* c1  = out + 1572864;            // c_new[0]
    float* h2a = out;                      // first output
    float* h2b = out + 1048576;            // h_new[1]
    float* c2  = out + 2097152;            // c_new[1]

    // --- prep: converts (1 launch), tiled transposes + zero-pad (1 launch), biases ---
    { CvtJobs cj;
      cj.j[0]  = { xt,     Acat,          512,  2048, 512,  524288,  0 };
      cj.j[1]  = { query,  Acat + 1024,   512,  2048, 512,  524288,  0 };
      cj.j[2]  = { h00,    Acat + 1536,   512,  2048, 512,  524288,  0 };
      cj.j[3]  = { h_last, Ahq,           512,  1024, 512,  524288,  0 };
      cj.j[4]  = { query,  Ahq + 512,     512,  1024, 512,  524288,  0 };
      cj.j[5]  = { h_last, Ag1 + 512,     512,  1024, 512,  524288,  0 };
      cj.j[6]  = { Wih0,   Bcat0,         1536, 2048, 1536, 3145728, 1 };
      cj.j[7]  = { Whh0,   Bcat0 + 1536,  512,  2048, 512,  1048576, 1 };
      cj.j[8]  = { Wih1,   Bcat1,         512,  1024, 512,  1048576, 1 };
      cj.j[9]  = { Whh1,   Bcat1 + 512,   512,  1024, 512,  1048576, 1 };
      cj.j[10] = { inflat, Ainf,          512,  512,  512,  983040,  0 };
      cvt_bf16<<<dim3(3072, 11), 256, 0, stream>>>(cj); }
    { TJobs tj;
      tj.j[0] = { Wv,      Wvt,                     512, 512,  512, 0 };
      tj.j[1] = { Woff,    Wcat,                    128, 1024, 1024, 0 };
      tj.j[2] = { Wattw,   Wcat + 128 * 1024,       128, 1024, 1024, 0 };
      tj.j[3] = { Wh2a,    Wcat + 256 * 1024,       512, 1024, 512, 0 };
      tj.j[4] = { Wctx,    Wb,                      512, 64,   64,  0 };
      tj.j[5] = { nullptr, Wcat + 256 * 1024 + 512, 512, 1024, 512, 0 }; // zero K-pad
      tcvt_bf16<<<dim3(256, 6), 256, 0, stream>>>(tj); }
    bias_cat3<<<1, 768, 0, stream>>>(boff, battw, bh2a, bcat);

    // --- GEMMs (bf16 MFMA) ---
    // value: v = inflat @ Wv + bv          (1920x512, K=512)
    sgemm<<<dim3(4, 30), 256, 0, stream>>>(Ainf, 512, Wvt, 512, bv, v, 512, 512);
    // obat = [h_last|query] @ [Woff|Wattw|Wh2a pad] + [boff|battw|bh2a]  (1024x768, K=1024)
    mgemm<<<dim3(12, 16), 256, 0, stream>>>(Ahq, 1024, Wcat, 1024, bcat, obat, 768, 1024);

    // --- fused deformable sampling + context attention (writes Acat[:,512:1024]) ---
    fused_att<<<1024, 512, 0, stream>>>(v, obat, refp, shapes, starts,
                                        Wb, bctx, walpha, Acat + 512);

    // LSTM0: gates+activation fused; writes h1, c1, Ag1[:, :512] (bf16)
    sgemm_lstm<<<dim3(16, 16), 256, 0, stream>>>(Acat, 2048, Bcat0, 2048,
                                                 c0, h1, nullptr, Ag1, 1024, c1, 2048);
    // LSTM1: writes h2 (outputs 0 and h_new[1]), c2
    sgemm_lstm<<<dim3(16, 16), 256, 0, stream>>>(Ag1, 1024, Bcat1, 1024,
                                                 c0 + 524288, h1 - 524288, h2b, nullptr, 0, c2, 1024);
}

// Round 12
// 137.349 us; speedup vs baseline: 1.1506x; 1.1506x over previous
//
#include <hip/hip_runtime.h>
#include <math.h>

// Problem constants (ShowAttendTellCore)
//   B=1024, D_MODEL=512, N_HEADS=8, D_HEAD=64, N_LEVELS=4, N_POINTS=4
//   T_TOTAL=1920, RNN=512, ENC=512, ATT_HID=512
// Output layout (f32): h2 (524288) | h1 | h2 | c1 | c2   (total 2621440)

typedef __attribute__((ext_vector_type(8))) short          s16x8;
typedef __attribute__((ext_vector_type(8))) unsigned short u16x8;
typedef __attribute__((ext_vector_type(4))) float          f32x4;

#define LOG2E  1.4426950408889634f
#define LOG2E2 2.8853900817779268f

__device__ __forceinline__ float rcpf(float x) { return __builtin_amdgcn_rcpf(x); }
__device__ __forceinline__ float exp2f_fast(float x) { return __builtin_amdgcn_exp2f(x); }
__device__ __forceinline__ float sigf(float x) {
    return rcpf(1.0f + exp2f_fast(-x * LOG2E));
}
__device__ __forceinline__ float tanhf_fast(float x) {
    const float xc = fminf(fmaxf(x, -15.0f), 15.0f);
    const float e2 = exp2f_fast(xc * LOG2E2);
    return 1.0f - 2.0f * rcpf(e2 + 1.0f);
}
__device__ __forceinline__ unsigned short f2bf(float f) {   // RNE f32->bf16
    unsigned u = __float_as_uint(f);
    u += 0x7FFF + ((u >> 16) & 1);
    return (unsigned short)(u >> 16);
}
__device__ __forceinline__ float bf2f(unsigned short h) {
    return __uint_as_float(((unsigned)h) << 16);
}
// async global->LDS, 16B per lane
__device__ __forceinline__ void gld_lds16(const unsigned short* g, unsigned short* l) {
    __builtin_amdgcn_global_load_lds(
        (const __attribute__((address_space(1))) void*)g,
        (__attribute__((address_space(3))) void*)l, 16, 0, 0);
}

// ---------------- batched f32 -> bf16 strided converts (one launch) --------
// ilv != 0: LSTM gate-interleave of dst rows: row' = (row%512)*4 + row/512.
struct CvtJob { const float* src; unsigned short* dst; int sld, dld, cols, total, ilv; };
struct CvtJobs { CvtJob j[11]; };
__global__ __launch_bounds__(256) void cvt_bf16(CvtJobs cj) {
    const CvtJob jb = cj.j[blockIdx.y];
    const int i = (blockIdx.x * 256 + threadIdx.x) * 4;
    if (i >= jb.total) return;
    const int r = i / jb.cols, c = i - r * jb.cols;
    const int rd = jb.ilv ? (((r & 511) << 2) | (r >> 9)) : r;
    const float4 v4 = *(const float4*)&jb.src[(size_t)r * jb.sld + c];
    ushort4 o;
    o.x = f2bf(v4.x); o.y = f2bf(v4.y); o.z = f2bf(v4.z); o.w = f2bf(v4.w);
    *(ushort4*)&jb.dst[(size_t)rd * jb.dld + c] = o;
}

// transpose-convert via 32x32 LDS tile; src==nullptr -> zeros.
struct TJob { const float* src; unsigned short* dst; int N_, dld, K_, total; };
struct TJobs { TJob j[6]; };
__global__ __launch_bounds__(256) void tcvt_bf16(TJobs tj) {
    const TJob jb = tj.j[blockIdx.y];
    const int tilesN = jb.N_ >> 5, tilesK = jb.K_ >> 5;
    const int tile = blockIdx.x;
    if (tile >= tilesN * tilesK) return;
    const int tn0 = (tile % tilesN) << 5, tk0 = (tile / tilesN) << 5;
    __shared__ float lds[32][33];
    const int t = threadIdx.x;
    if (jb.src) {
#pragma unroll
        for (int q = 0; q < 4; ++q) {
            const int e = t + (q << 8);
            lds[e >> 5][e & 31] = jb.src[(size_t)(tk0 + (e >> 5)) * jb.N_ + tn0 + (e & 31)];
        }
        __syncthreads();
#pragma unroll
        for (int q = 0; q < 4; ++q) {
            const int e = t + (q << 8);
            const int n = e >> 5, k = e & 31;
            jb.dst[(size_t)(tn0 + n) * jb.dld + tk0 + k] = f2bf(lds[k][n]);
        }
    } else {
#pragma unroll
        for (int q = 0; q < 4; ++q) {
            const int e = t + (q << 8);
            jb.dst[(size_t)(tn0 + (e >> 5)) * jb.dld + tk0 + (e & 31)] = 0;
        }
    }
}

// bcat = [boff(128) | battw(128) | bh2a(512)]
__global__ __launch_bounds__(768) void bias_cat3(const float* __restrict__ a,
                                                 const float* __restrict__ b,
                                                 const float* __restrict__ c,
                                                 float* __restrict__ dst) {
    const int t = threadIdx.x;
    dst[t] = (t < 128) ? a[t] : (t < 256 ? b[t - 128] : c[t - 256]);
}

// ===== 64x64-tile staged GEMMs: 2 blocks/CU (2 waves/SIMD TLP) ============
// R11 post-mortem: 128-wide tiles gave grid=256 = 1 block/CU = 1 wave/SIMD —
// zero TLP, all latency exposed (MfmaUtil 6%). 64x64 doubles the grid.
// 3-buffer staging, counted vmcnt(2), raw s_barrier (no compiler drain).

// ---------------- LDS-staged bf16 MFMA GEMM (BM=BN=64, BK=32) --------------
// C(MxN f32) = A(MxK bf16 rm) @ B^T (B NxK bf16 rm) + bias
// grid=(N/64, M/64); 4 waves (2x2), wave=32x32 (acc 2x2).
__global__ __launch_bounds__(256) void sgemm(
    const unsigned short* __restrict__ A, int lda,
    const unsigned short* __restrict__ B, int ldb,
    const float* __restrict__ bias, float* __restrict__ C, int ldc, int K)
{
    __shared__ unsigned short As[3][64 * 32];    // 4KB x3
    __shared__ unsigned short Bs[3][64 * 32];    // 4KB x3

    const int tid = threadIdx.x;
    const int w = tid >> 6, lane = tid & 63;
    const int wr = w >> 1, wc = w & 1;
    const int lr = lane & 15, lg = lane >> 4;
    const int bm = blockIdx.y, bn = blockIdx.x;

    const int srow = tid >> 2, sk = (tid & 3) << 3;
    const unsigned short* Ag = A + (size_t)(bm * 64 + srow) * lda + sk;
    const unsigned short* Bg = B + (size_t)(bn * 64 + srow) * ldb + sk;

    f32x4 acc[2][2];
#pragma unroll
    for (int mt = 0; mt < 2; ++mt)
#pragma unroll
        for (int nt = 0; nt < 2; ++nt) acc[mt][nt] = (f32x4){0.f, 0.f, 0.f, 0.f};

    const int nsteps = K >> 5;
    // prologue: stage tiles 0 and 1 (2 loads each)
    gld_lds16(Ag, &As[0][tid * 8]);
    gld_lds16(Bg, &Bs[0][tid * 8]);
    if (nsteps > 1) {
        gld_lds16(Ag + 32, &As[1][tid * 8]);
        gld_lds16(Bg + 32, &Bs[1][tid * 8]);
        asm volatile("s_waitcnt vmcnt(2)" ::: "memory");   // tile0 resident
    } else {
        asm volatile("s_waitcnt vmcnt(0)" ::: "memory");
    }
    __builtin_amdgcn_s_barrier();

    int cur = 0;
    for (int t = 0; t < nsteps; ++t) {
        if (t + 2 < nsteps) {                 // stage tile t+2
            const int bw = (cur >= 1) ? cur - 1 : 2;
            const int kk = (t + 2) << 5;
            gld_lds16(Ag + kk, &As[bw][tid * 8]);
            gld_lds16(Bg + kk, &Bs[bw][tid * 8]);
        }
        const unsigned short* Ab = &As[cur][0];
        const unsigned short* Bb = &Bs[cur][0];
        s16x8 a[2], bfr[2];
#pragma unroll
        for (int mt = 0; mt < 2; ++mt)
            a[mt] = *(const s16x8*)&Ab[(wr * 32 + mt * 16 + lr) * 32 + lg * 8];
#pragma unroll
        for (int nt = 0; nt < 2; ++nt)
            bfr[nt] = *(const s16x8*)&Bb[(wc * 32 + nt * 16 + lr) * 32 + lg * 8];
#pragma unroll
        for (int mt = 0; mt < 2; ++mt)
#pragma unroll
            for (int nt = 0; nt < 2; ++nt)
                acc[mt][nt] = __builtin_amdgcn_mfma_f32_16x16x32_bf16(
                    a[mt], bfr[nt], acc[mt][nt], 0, 0, 0);
        if (t + 1 < nsteps) {
            if (t + 2 < nsteps) asm volatile("s_waitcnt vmcnt(2)" ::: "memory");
            else                asm volatile("s_waitcnt vmcnt(0)" ::: "memory");
            __builtin_amdgcn_s_barrier();
        }
        cur = (cur < 2) ? cur + 1 : 0;
    }
#pragma unroll
    for (int nt = 0; nt < 2; ++nt) {
        const int col = bn * 64 + wc * 32 + nt * 16 + lr;
        const float bb = bias ? bias[col] : 0.0f;
#pragma unroll
        for (int mt = 0; mt < 2; ++mt) {
            const int rbase = bm * 64 + wr * 32 + mt * 16 + lg * 4;
#pragma unroll
            for (int r = 0; r < 4; ++r)
                C[(size_t)(rbase + r) * ldc + col] = acc[mt][nt][r] + bb;
        }
    }
}

// ---------------- staged GEMM + fused LSTM activation epilogue -------------
// B rows gate-interleaved (col = 4*unit + gate, gate order i,f,g,o).
__global__ __launch_bounds__(256) void sgemm_lstm(
    const unsigned short* __restrict__ A, int lda,
    const unsigned short* __restrict__ B, int ldb,
    const float* __restrict__ c_in,
    float* __restrict__ h_a, float* __restrict__ h_b,
    unsigned short* __restrict__ hbf, int hbf_ld,
    float* __restrict__ c_out, int K)
{
    __shared__ unsigned short As[3][64 * 32];
    __shared__ unsigned short Bs[3][64 * 32];

    const int tid = threadIdx.x;
    const int w = tid >> 6, lane = tid & 63;
    const int wr = w >> 1, wc = w & 1;
    const int lr = lane & 15, lg = lane >> 4;
    const int bm = blockIdx.y, bn = blockIdx.x;

    const int srow = tid >> 2, sk = (tid & 3) << 3;
    const unsigned short* Ag = A + (size_t)(bm * 64 + srow) * lda + sk;
    const unsigned short* Bg = B + (size_t)(bn * 64 + srow) * ldb + sk;

    f32x4 acc[2][2];
#pragma unroll
    for (int mt = 0; mt < 2; ++mt)
#pragma unroll
        for (int nt = 0; nt < 2; ++nt) acc[mt][nt] = (f32x4){0.f, 0.f, 0.f, 0.f};

    const int nsteps = K >> 5;
    gld_lds16(Ag, &As[0][tid * 8]);
    gld_lds16(Bg, &Bs[0][tid * 8]);
    if (nsteps > 1) {
        gld_lds16(Ag + 32, &As[1][tid * 8]);
        gld_lds16(Bg + 32, &Bs[1][tid * 8]);
        asm volatile("s_waitcnt vmcnt(2)" ::: "memory");
    } else {
        asm volatile("s_waitcnt vmcnt(0)" ::: "memory");
    }
    __builtin_amdgcn_s_barrier();

    int cur = 0;
    for (int t = 0; t < nsteps; ++t) {
        if (t + 2 < nsteps) {
            const int bw = (cur >= 1) ? cur - 1 : 2;
            const int kk = (t + 2) << 5;
            gld_lds16(Ag + kk, &As[bw][tid * 8]);
            gld_lds16(Bg + kk, &Bs[bw][tid * 8]);
        }
        const unsigned short* Ab = &As[cur][0];
        const unsigned short* Bb = &Bs[cur][0];
        s16x8 a[2], bfr[2];
#pragma unroll
        for (int mt = 0; mt < 2; ++mt)
            a[mt] = *(const s16x8*)&Ab[(wr * 32 + mt * 16 + lr) * 32 + lg * 8];
#pragma unroll
        for (int nt = 0; nt < 2; ++nt)
            bfr[nt] = *(const s16x8*)&Bb[(wc * 32 + nt * 16 + lr) * 32 + lg * 8];
#pragma unroll
        for (int mt = 0; mt < 2; ++mt)
#pragma unroll
            for (int nt = 0; nt < 2; ++nt)
                acc[mt][nt] = __builtin_amdgcn_mfma_f32_16x16x32_bf16(
                    a[mt], bfr[nt], acc[mt][nt], 0, 0, 0);
        if (t + 1 < nsteps) {
            if (t + 2 < nsteps) asm volatile("s_waitcnt vmcnt(2)" ::: "memory");
            else                asm volatile("s_waitcnt vmcnt(0)" ::: "memory");
            __builtin_amdgcn_s_barrier();
        }
        cur = (cur < 2) ? cur + 1 : 0;
    }
    // epilogue: col = bn*64 + wc*32 + nt*16 + lr; gate = col&3 = lane&3
    const int gte  = lane & 3;
    const int base = lane & ~3;
#pragma unroll
    for (int nt = 0; nt < 2; ++nt) {
        const int col = bn * 64 + wc * 32 + nt * 16 + lr;
        const int u = col >> 2;     // unit index in [0,512)
#pragma unroll
        for (int mt = 0; mt < 2; ++mt) {
            const int rbase = bm * 64 + wr * 32 + mt * 16 + lg * 4;
#pragma unroll
            for (int r = 0; r < 4; ++r) {
                const float vv = acc[mt][nt][r];
                const float a  = (gte == 2) ? tanhf_fast(vv) : sigf(vv);
                const float ai = __shfl(a, base + 0);
                const float af = __shfl(a, base + 1);
                const float ag = __shfl(a, base + 2);
                const float ao = __shfl(a, base + 3);
                const int row = rbase + r;
                const float c  = c_in[(size_t)row * 512 + u];
                const float c2 = af * c + ai * ag;
                const float h2 = ao * tanhf_fast(c2);
                if (gte == 0)      c_out[(size_t)row * 512 + u] = c2;
                else if (gte == 1) h_a[(size_t)row * 512 + u] = h2;
                else if (gte == 2) { if (h_b) h_b[(size_t)row * 512 + u] = h2; }
                else if (hbf)      hbf[(size_t)row * hbf_ld + u] = f2bf(h2);
            }
        }
    }
}

// ---------------- fused deformable sampling + context attention ------------
// obat (B,768) = [off(128) | aw_raw(128) | atth(512)]  (biases included)
__global__ __launch_bounds__(512, 2) void fused_att(
    const float* __restrict__ v,       // (1920, 512)
    const float* __restrict__ obat,    // (B, 768)
    const float* __restrict__ refp,    // (B, 4)
    const int*   __restrict__ shapes,  // (4,)
    const int*   __restrict__ starts,  // (4,)
    const unsigned short* __restrict__ Wb,  // (512, 64) bf16, = Wctx^T
    const float* __restrict__ bctx,    // (512,)
    const float* __restrict__ walpha,  // (512,)
    unsigned short* __restrict__ attdst)    // bf16, row stride 2048
{
    __shared__ unsigned short cf[128 * 64];   // 16 KB, XOR chunk-swizzled
    __shared__ float ba[512];                 // bctx + atth[b]
    __shared__ float wal[512];
    __shared__ float awb[128];
    __shared__ float dsum[128];
    __shared__ float dots4[4][128];

    const int b   = blockIdx.x;
    const int tid = threadIdx.x;

    // phase 0: attention-weight softmax (16 per head)
    if (tid < 128) awb[tid] = obat[b * 768 + 128 + tid];
    __syncthreads();
    if (tid < 8) {
        float mx = -1e30f;
        for (int i = 0; i < 16; ++i) mx = fmaxf(mx, awb[tid * 16 + i]);
        float sum = 0.f;
        for (int i = 0; i < 16; ++i) { float e = exp2f_fast((awb[tid * 16 + i] - mx) * LOG2E); awb[tid * 16 + i] = e; sum += e; }
        float inv = rcpf(sum);
        for (int i = 0; i < 16; ++i) awb[tid * 16 + i] *= inv;
    }
    __syncthreads();

    // phase 1: bilinear sampling -> cf[p][d] = bf16(samp[d] * aw[p]); stage ba/wal
    ba[tid]  = bctx[tid] + obat[b * 768 + 256 + tid];
    wal[tid] = walpha[tid];
    {
        const int pg  = tid >> 2;
        const int sub = tid & 3;
        const int d0  = sub * 16;
        const int h   = pg >> 4;
        const int l   = (pg & 15) >> 2;
        const int Tlen = shapes[l];
        const int st   = starts[l];
        const float T  = (float)Tlen;
        const float refv = refp[b * 4 + l];
        const float offv = obat[b * 768 + pg];
        const float awv  = awb[pg];
        const float x   = (refv + offv * rcpf(T)) * T - 0.5f;  // exact: T is 2^k
        const float x0f = floorf(x);
        const float w1  = x - x0f;
        const int   x0  = (int)x0f;
        const float w0s = (x0 >= 0 && x0 < Tlen) ? (1.0f - w1) : 0.0f;
        const float w1s = (x0 + 1 >= 0 && x0 + 1 < Tlen) ? w1 : 0.0f;
        const int i0 = (min(max(x0, 0), Tlen - 1) + st) * 512 + h * 64;
        const int i1 = (min(max(x0 + 1, 0), Tlen - 1) + st) * 512 + h * 64;
        u16x8 o0, o1;
#pragma unroll
        for (int q = 0; q < 4; ++q) {
            const float4 a  = *(const float4*)&v[i0 + d0 + q * 4];
            const float4 bq = *(const float4*)&v[i1 + d0 + q * 4];
            unsigned short e0 = f2bf((a.x * w0s + bq.x * w1s) * awv);
            unsigned short e1 = f2bf((a.y * w0s + bq.y * w1s) * awv);
            unsigned short e2 = f2bf((a.z * w0s + bq.z * w1s) * awv);
            unsigned short e3 = f2bf((a.w * w0s + bq.w * w1s) * awv);
            if (q == 0) { o0[0] = e0; o0[1] = e1; o0[2] = e2; o0[3] = e3; }
            if (q == 1) { o0[4] = e0; o0[5] = e1; o0[6] = e2; o0[7] = e3; }
            if (q == 2) { o1[0] = e0; o1[1] = e1; o1[2] = e2; o1[3] = e3; }
            if (q == 3) { o1[4] = e0; o1[5] = e1; o1[6] = e2; o1[7] = e3; }
        }
        const int c0 = (sub * 2)     ^ (pg & 7);
        const int c1 = (sub * 2 + 1) ^ (pg & 7);
        *(u16x8*)&cf[pg * 64 + c0 * 8] = o0;
        *(u16x8*)&cf[pg * 64 + c1 * 8] = o1;
    }
    __syncthreads();

    // phase 2: dots[p] = sum_j tanh((cf@Wctx)[p][j] + ba[j]) * wal[j]  via MFMA
    {
        const int w    = tid >> 6, lane = tid & 63;
        const int wm   = w >> 2, wn = w & 3;
        const int lr   = lane & 15, lg = lane >> 4;

        s16x8 afrag[4][2];
#pragma unroll
        for (int mt = 0; mt < 4; ++mt) {
            const int row = wm * 64 + mt * 16 + lr;
#pragma unroll
            for (int ks = 0; ks < 2; ++ks) {
                const int ch = (ks * 4 + lg) ^ (row & 7);
                afrag[mt][ks] = *(const s16x8*)&cf[row * 64 + ch * 8];
            }
        }
        f32x4 part[4];
#pragma unroll
        for (int mt = 0; mt < 4; ++mt) part[mt] = (f32x4){0.f, 0.f, 0.f, 0.f};

#pragma clang loop unroll(disable)
        for (int nt = 0; nt < 8; ++nt) {
            const int ct  = wn * 8 + nt;
            const int col = ct * 16 + lr;
            const s16x8 b0 = *(const s16x8*)&Wb[col * 64 + lg * 8];
            const s16x8 b1 = *(const s16x8*)&Wb[col * 64 + 32 + lg * 8];
            const float bav = ba[col], wav = wal[col];
#pragma unroll
            for (int mt = 0; mt < 4; ++mt) {
                f32x4 acc = {0.f, 0.f, 0.f, 0.f};
                acc = __builtin_amdgcn_mfma_f32_16x16x32_bf16(afrag[mt][0], b0, acc, 0, 0, 0);
                acc = __builtin_amdgcn_mfma_f32_16x16x32_bf16(afrag[mt][1], b1, acc, 0, 0, 0);
#pragma unroll
                for (int r = 0; r < 4; ++r)
                    part[mt][r] += tanhf_fast(acc[r] + bav) * wav;
            }
        }
#pragma unroll
        for (int mt = 0; mt < 4; ++mt) {
#pragma unroll
            for (int r = 0; r < 4; ++r) {
                float s = part[mt][r];
                s += __shfl_xor(s, 1); s += __shfl_xor(s, 2);
                s += __shfl_xor(s, 4); s += __shfl_xor(s, 8);
                if (lr == 0) dots4[wn][wm * 64 + mt * 16 + lg * 4 + r] = s;
            }
        }
    }
    __syncthreads();
    if (tid < 128)
        dsum[tid] = dots4[0][tid] + dots4[1][tid] + dots4[2][tid] + dots4[3][tid];
    __syncthreads();

    // phase 3: softmax over the 16 points of each head
    if (tid < 8) {
        float mx = -1e30f;
        for (int i = 0; i < 16; ++i) mx = fmaxf(mx, dsum[tid * 16 + i]);
        float sum = 0.f;
        for (int i = 0; i < 16; ++i) { float e = exp2f_fast((dsum[tid * 16 + i] - mx) * LOG2E); dsum[tid * 16 + i] = e; sum += e; }
        float inv = rcpf(sum);
        for (int i = 0; i < 16; ++i) dsum[tid * 16 + i] *= inv;
    }
    __syncthreads();

    // phase 4: att_res (bf16 into Acat)
    {
        const int h = tid >> 6, d = tid & 63;
        const int ch = d >> 3, e = d & 7;
        float s = 0.f;
#pragma unroll
        for (int p = 0; p < 16; ++p) {
            const int row = h * 16 + p;
            s += dsum[h * 16 + p] * bf2f(cf[row * 64 + ((ch ^ (row & 7)) * 8) + e]);
        }
        attdst[(size_t)b * 2048 + tid] = f2bf(s);
    }
}

extern "C" void kernel_launch(void* const* d_in, const int* in_sizes, int n_in,
                              void* d_out, int out_size, void* d_ws, size_t ws_size,
                              hipStream_t stream) {
    const float* xt     = (const float*)d_in[0];
    const float* h0     = (const float*)d_in[1];   // (2,1024,512)
    const float* c0     = (const float*)d_in[2];
    const float* query  = (const float*)d_in[3];   // (1,1024,512)
    const float* refp   = (const float*)d_in[4];   // (1,1024,4,1)
    const float* inflat = (const float*)d_in[5];   // (1,1920,512)
    const int*   shapes = (const int*)d_in[6];
    const int*   starts = (const int*)d_in[7];
    const float* Wv     = (const float*)d_in[9];   // (512,512) (K,N)
    const float* bv     = (const float*)d_in[10];
    const float* Woff   = (const float*)d_in[11];  // (1024,128) (K,N)
    const float* boff   = (const float*)d_in[12];
    const float* Wattw  = (const float*)d_in[13];  // (1024,128)
    const float* battw  = (const float*)d_in[14];
    const float* Wctx   = (const float*)d_in[15];  // (64,512)
    const float* bctx   = (const float*)d_in[16];
    const float* Wh2a   = (const float*)d_in[17];  // (512,512) (K,N)
    const float* bh2a   = (const float*)d_in[18];
    const float* walpha = (const float*)d_in[19];
    const float* Wih0   = (const float*)d_in[21];  // (2048,1536) (N,K)
    const float* Whh0   = (const float*)d_in[22];  // (2048,512)
    const float* Wih1   = (const float*)d_in[23];  // (2048,512)
    const float* Whh1   = (const float*)d_in[24];  // (2048,512)

    float* out = (float*)d_out;
    float* ws  = (float*)d_ws;

    // ws layout (f32 units), lifetime-overlapped
    float*          v     = ws;                                   // 983040
    float*          obat  = ws + 983040;                          // 1024x768 [off|aw|atth]
    unsigned short* Acat  = (unsigned short*)(ws + 1769472);      // 1024x2048 bf16
    unsigned short* Bcat0 = (unsigned short*)(ws + 2818048);      // 2048x2048 bf16 (gate-ilv)
    unsigned short* Ainf  = (unsigned short*)(ws + 4915200);      // 1920x512 bf16
    unsigned short* Wvt   = (unsigned short*)(ws + 5406720);      // 512x512 bf16
    unsigned short* Wcat  = (unsigned short*)(ws + 5537792);      // 768x1024 bf16
    unsigned short* Ahq   = (unsigned short*)(ws + 5931008);      // 1024x1024 bf16
    unsigned short* Wb    = (unsigned short*)(ws + 6455296);      // 512x64 bf16 (Wctx^T)
    float*          bcat  = ws + 6471680;                         // 768
    unsigned short* Ag1   = (unsigned short*)(ws + 7012352);      // 1024x1024 bf16
    unsigned short* Bcat1 = (unsigned short*)(ws + 7536640);      // 2048x1024 bf16 (gate-ilv)

    const float* h00    = h0;
    const float* h_last = h0 + 524288;     // h0[1]
    float* h1  = out + 524288;             // h_new[0]
    float* c1  = out + 1572864;            // c_new[0]
    float* h2a = out;                      // first output
    float* h2b = out + 1048576;            // h_new[1]
    float* c2  = out + 2097152;            // c_new[1]

    // --- prep: converts (1 launch), tiled transposes + zero-pad (1 launch), biases ---
    { CvtJobs cj;
      cj.j[0]  = { xt,     Acat,          512,  2048, 512,  524288,  0 };
      cj.j[1]  = { query,  Acat + 1024,   512,  2048, 512,  524288,  0 };
      cj.j[2]  = { h00,    Acat + 1536,   512,  2048, 512,  524288,  0 };
      cj.j[3]  = { h_last, Ahq,           512,  1024, 512,  524288,  0 };
      cj.j[4]  = { query,  Ahq + 512,     512,  1024, 512,  524288,  0 };
      cj.j[5]  = { h_last, Ag1 + 512,     512,  1024, 512,  524288,  0 };
      cj.j[6]  = { Wih0,   Bcat0,         1536, 2048, 1536, 3145728, 1 };
      cj.j[7]  = { Whh0,   Bcat0 + 1536,  512,  2048, 512,  1048576, 1 };
      cj.j[8]  = { Wih1,   Bcat1,         512,  1024, 512,  1048576, 1 };
      cj.j[9]  = { Whh1,   Bcat1 + 512,   512,  1024, 512,  1048576, 1 };
      cj.j[10] = { inflat, Ainf,          512,  512,  512,  983040,  0 };
      cvt_bf16<<<dim3(3072, 11), 256, 0, stream>>>(cj); }
    { TJobs tj;
      tj.j[0] = { Wv,      Wvt,                     512, 512,  512, 0 };
      tj.j[1] = { Woff,    Wcat,                    128, 1024, 1024, 0 };
      tj.j[2] = { Wattw,   Wcat + 128 * 1024,       128, 1024, 1024, 0 };
      tj.j[3] = { Wh2a,    Wcat + 256 * 1024,       512, 1024, 512, 0 };
      tj.j[4] = { Wctx,    Wb,                      512, 64,   64,  0 };
      tj.j[5] = { nullptr, Wcat + 256 * 1024 + 512, 512, 1024, 512, 0 }; // zero K-pad
      tcvt_bf16<<<dim3(256, 6), 256, 0, stream>>>(tj); }
    bias_cat3<<<1, 768, 0, stream>>>(boff, battw, bh2a, bcat);

    // --- GEMMs (bf16 MFMA, 64x64 staged) ---
    // value: v = inflat @ Wv + bv          (1920x512, K=512)
    sgemm<<<dim3(8, 30), 256, 0, stream>>>(Ainf, 512, Wvt, 512, bv, v, 512, 512);
    // obat = [h_last|query] @ [Woff|Wattw|Wh2a pad] + [boff|battw|bh2a]  (1024x768, K=1024)
    sgemm<<<dim3(12, 16), 256, 0, stream>>>(Ahq, 1024, Wcat, 1024, bcat, obat, 768, 1024);

    // --- fused deformable sampling + context attention (writes Acat[:,512:1024]) ---
    fused_att<<<1024, 512, 0, stream>>>(v, obat, refp, shapes, starts,
                                        Wb, bctx, walpha, Acat + 512);

    // LSTM0: gates+activation fused; writes h1, c1, Ag1[:, :512] (bf16)
    sgemm_lstm<<<dim3(32, 16), 256, 0, stream>>>(Acat, 2048, Bcat0, 2048,
                                                 c0, h1, nullptr, Ag1, 1024, c1, 2048);
    // LSTM1: writes h2 (outputs 0 and h_new[1]), c2
    sgemm_lstm<<<dim3(32, 16), 256, 0, stream>>>(Ag1, 1024, Bcat1, 1024,
                                                 c0 + 524288, h1 - 524288, h2b, nullptr, 0, c2, 1024);
}

// Round 13
// 123.210 us; speedup vs baseline: 1.2827x; 1.1148x over previous
//
#include <hip/hip_runtime.h>
#include <math.h>

// Problem constants (ShowAttendTellCore)
//   B=1024, D_MODEL=512, N_HEADS=8, D_HEAD=64, N_LEVELS=4, N_POINTS=4
//   T_TOTAL=1920, RNN=512, ENC=512, ATT_HID=512
// Output layout (f32): h2 (524288) | h1 | h2 | c1 | c2   (total 2621440)

typedef __attribute__((ext_vector_type(8))) short          s16x8;
typedef __attribute__((ext_vector_type(8))) unsigned short u16x8;
typedef __attribute__((ext_vector_type(4))) float          f32x4;

#define LOG2E  1.4426950408889634f
#define LOG2E2 2.8853900817779268f

__device__ __forceinline__ float rcpf(float x) { return __builtin_amdgcn_rcpf(x); }
__device__ __forceinline__ float exp2f_fast(float x) { return __builtin_amdgcn_exp2f(x); }
__device__ __forceinline__ float sigf(float x) {
    return rcpf(1.0f + exp2f_fast(-x * LOG2E));
}
__device__ __forceinline__ float tanhf_fast(float x) {
    const float xc = fminf(fmaxf(x, -15.0f), 15.0f);
    const float e2 = exp2f_fast(xc * LOG2E2);
    return 1.0f - 2.0f * rcpf(e2 + 1.0f);
}
__device__ __forceinline__ unsigned short f2bf(float f) {   // RNE f32->bf16
    unsigned u = __float_as_uint(f);
    u += 0x7FFF + ((u >> 16) & 1);
    return (unsigned short)(u >> 16);
}
__device__ __forceinline__ float bf2f(unsigned short h) {
    return __uint_as_float(((unsigned)h) << 16);
}
// async global->LDS, 16B per lane
__device__ __forceinline__ void gld_lds16(const unsigned short* g, unsigned short* l) {
    __builtin_amdgcn_global_load_lds(
        (const __attribute__((address_space(1))) void*)g,
        (__attribute__((address_space(3))) void*)l, 16, 0, 0);
}

// ---------------- batched f32 -> bf16 strided converts (one launch) --------
// ilv != 0: LSTM gate-interleave of dst rows: row' = (row%512)*4 + row/512.
struct CvtJob { const float* src; unsigned short* dst; int sld, dld, cols, total, ilv; };
struct CvtJobs { CvtJob j[11]; };
__global__ __launch_bounds__(256) void cvt_bf16(CvtJobs cj) {
    const CvtJob jb = cj.j[blockIdx.y];
    const int i = (blockIdx.x * 256 + threadIdx.x) * 4;
    if (i >= jb.total) return;
    const int r = i / jb.cols, c = i - r * jb.cols;
    const int rd = jb.ilv ? (((r & 511) << 2) | (r >> 9)) : r;
    const float4 v4 = *(const float4*)&jb.src[(size_t)r * jb.sld + c];
    ushort4 o;
    o.x = f2bf(v4.x); o.y = f2bf(v4.y); o.z = f2bf(v4.z); o.w = f2bf(v4.w);
    *(ushort4*)&jb.dst[(size_t)rd * jb.dld + c] = o;
}

// transpose-convert via 32x32 LDS tile; src==nullptr -> zeros.
struct TJob { const float* src; unsigned short* dst; int N_, dld, K_, total; };
struct TJobs { TJob j[6]; };
__global__ __launch_bounds__(256) void tcvt_bf16(TJobs tj) {
    const TJob jb = tj.j[blockIdx.y];
    const int tilesN = jb.N_ >> 5, tilesK = jb.K_ >> 5;
    const int tile = blockIdx.x;
    if (tile >= tilesN * tilesK) return;
    const int tn0 = (tile % tilesN) << 5, tk0 = (tile / tilesN) << 5;
    __shared__ float lds[32][33];
    const int t = threadIdx.x;
    if (jb.src) {
#pragma unroll
        for (int q = 0; q < 4; ++q) {
            const int e = t + (q << 8);
            lds[e >> 5][e & 31] = jb.src[(size_t)(tk0 + (e >> 5)) * jb.N_ + tn0 + (e & 31)];
        }
        __syncthreads();
#pragma unroll
        for (int q = 0; q < 4; ++q) {
            const int e = t + (q << 8);
            const int n = e >> 5, k = e & 31;
            jb.dst[(size_t)(tn0 + n) * jb.dld + tk0 + k] = f2bf(lds[k][n]);
        }
    } else {
#pragma unroll
        for (int q = 0; q < 4; ++q) {
            const int e = t + (q << 8);
            jb.dst[(size_t)(tn0 + (e >> 5)) * jb.dld + tk0 + (e & 31)] = 0;
        }
    }
}

// bcat = [boff(128) | battw(128) | bh2a(512)]
__global__ __launch_bounds__(768) void bias_cat3(const float* __restrict__ a,
                                                 const float* __restrict__ b,
                                                 const float* __restrict__ c,
                                                 float* __restrict__ dst) {
    const int t = threadIdx.x;
    dst[t] = (t < 128) ? a[t] : (t < 256 ? b[t - 128] : c[t - 256]);
}

// ===== 64x64-tile, BK=64 staged GEMMs =====================================
// R12 post-mortem: BK=32 had 64 sync events for 4-MFMA steps (~80% idle).
// BK=64 halves the steps, doubles work per sync. LDS tile [64 rows][8 chunks
// of 16B]; linear layout at 128B row stride would be a 16-way conflict, so:
// XOR swizzle (rule #21): linear LDS dest (gld_lds16 requirement), thread t
// (slot s) loads global chunk (s&7)^(row&7); ds_read at slot row*8+(c^(row&7)).
// 3 buffers, counted vmcnt(4) (never 0 in-loop), raw s_barrier.

// ---------------- LDS-staged bf16 MFMA GEMM (BM=BN=64, BK=64) --------------
// C(MxN f32) = A(MxK bf16 rm) @ B^T (B NxK bf16 rm) + bias
// grid=(N/64, M/64); 4 waves (2x2), wave=32x32 (acc 2x2). K % 64 == 0.
__global__ __launch_bounds__(256) void sgemm(
    const unsigned short* __restrict__ A, int lda,
    const unsigned short* __restrict__ B, int ldb,
    const float* __restrict__ bias, float* __restrict__ C, int ldc, int K)
{
    __shared__ unsigned short As[3][64 * 64];    // 8KB x3
    __shared__ unsigned short Bs[3][64 * 64];    // 8KB x3

    const int tid = threadIdx.x;
    const int w = tid >> 6, lane = tid & 63;
    const int wr = w >> 1, wc = w & 1;
    const int lr = lane & 15, lg = lane >> 4;
    const int bm = blockIdx.y, bn = blockIdx.x;

    // staging slots s = tid, tid+256; slot s = row s>>3, global chunk (s&7)^(row&7)
    const int s1 = tid, s2 = tid + 256;
    const int r1 = s1 >> 3, c1 = ((s1 & 7) ^ (r1 & 7)) << 3;
    const int r2 = s2 >> 3, c2 = ((s2 & 7) ^ (r2 & 7)) << 3;
    const unsigned short* Ag1 = A + (size_t)(bm * 64 + r1) * lda + c1;
    const unsigned short* Ag2 = A + (size_t)(bm * 64 + r2) * lda + c2;
    const unsigned short* Bg1 = B + (size_t)(bn * 64 + r1) * ldb + c1;
    const unsigned short* Bg2 = B + (size_t)(bn * 64 + r2) * ldb + c2;

    f32x4 acc[2][2];
#pragma unroll
    for (int mt = 0; mt < 2; ++mt)
#pragma unroll
        for (int nt = 0; nt < 2; ++nt) acc[mt][nt] = (f32x4){0.f, 0.f, 0.f, 0.f};

#define STAGE_T(buf, k0) do { \
        gld_lds16(Ag1 + (k0), &As[buf][s1 * 8]); \
        gld_lds16(Ag2 + (k0), &As[buf][s2 * 8]); \
        gld_lds16(Bg1 + (k0), &Bs[buf][s1 * 8]); \
        gld_lds16(Bg2 + (k0), &Bs[buf][s2 * 8]); } while (0)

    const int nsteps = K >> 6;
    STAGE_T(0, 0);
    if (nsteps > 1) {
        STAGE_T(1, 64);
        asm volatile("s_waitcnt vmcnt(4)" ::: "memory");   // tile0 resident
    } else {
        asm volatile("s_waitcnt vmcnt(0)" ::: "memory");
    }
    __builtin_amdgcn_s_barrier();

    int cur = 0;
    for (int t = 0; t < nsteps; ++t) {
        if (t + 2 < nsteps) {                 // stage tile t+2
            const int bw = (cur >= 1) ? cur - 1 : 2;
            STAGE_T(bw, (t + 2) << 6);
        }
        const unsigned short* Ab = &As[cur][0];
        const unsigned short* Bb = &Bs[cur][0];
        s16x8 a[2][2], bfr[2][2];
#pragma unroll
        for (int mt = 0; mt < 2; ++mt) {
            const int ar = wr * 32 + mt * 16 + lr;
#pragma unroll
            for (int ks = 0; ks < 2; ++ks)
                a[mt][ks] = *(const s16x8*)&Ab[(ar * 8 + ((ks * 4 + lg) ^ (ar & 7))) * 8];
        }
#pragma unroll
        for (int nt = 0; nt < 2; ++nt) {
            const int br = wc * 32 + nt * 16 + lr;
#pragma unroll
            for (int ks = 0; ks < 2; ++ks)
                bfr[nt][ks] = *(const s16x8*)&Bb[(br * 8 + ((ks * 4 + lg) ^ (br & 7))) * 8];
        }
#pragma unroll
        for (int ks = 0; ks < 2; ++ks)
#pragma unroll
            for (int mt = 0; mt < 2; ++mt)
#pragma unroll
                for (int nt = 0; nt < 2; ++nt)
                    acc[mt][nt] = __builtin_amdgcn_mfma_f32_16x16x32_bf16(
                        a[mt][ks], bfr[nt][ks], acc[mt][nt], 0, 0, 0);
        if (t + 1 < nsteps) {
            if (t + 2 < nsteps) asm volatile("s_waitcnt vmcnt(4)" ::: "memory");
            else                asm volatile("s_waitcnt vmcnt(0)" ::: "memory");
            __builtin_amdgcn_s_barrier();
        }
        cur = (cur < 2) ? cur + 1 : 0;
    }
#pragma unroll
    for (int nt = 0; nt < 2; ++nt) {
        const int col = bn * 64 + wc * 32 + nt * 16 + lr;
        const float bb = bias ? bias[col] : 0.0f;
#pragma unroll
        for (int mt = 0; mt < 2; ++mt) {
            const int rbase = bm * 64 + wr * 32 + mt * 16 + lg * 4;
#pragma unroll
            for (int r = 0; r < 4; ++r)
                C[(size_t)(rbase + r) * ldc + col] = acc[mt][nt][r] + bb;
        }
    }
}

// ---------------- BK=64 staged GEMM + fused LSTM activation epilogue -------
// B rows gate-interleaved (col = 4*unit + gate, gate order i,f,g,o).
__global__ __launch_bounds__(256) void sgemm_lstm(
    const unsigned short* __restrict__ A, int lda,
    const unsigned short* __restrict__ B, int ldb,
    const float* __restrict__ c_in,
    float* __restrict__ h_a, float* __restrict__ h_b,
    unsigned short* __restrict__ hbf, int hbf_ld,
    float* __restrict__ c_out, int K)
{
    __shared__ unsigned short As[3][64 * 64];
    __shared__ unsigned short Bs[3][64 * 64];

    const int tid = threadIdx.x;
    const int w = tid >> 6, lane = tid & 63;
    const int wr = w >> 1, wc = w & 1;
    const int lr = lane & 15, lg = lane >> 4;
    const int bm = blockIdx.y, bn = blockIdx.x;

    const int s1 = tid, s2 = tid + 256;
    const int r1 = s1 >> 3, c1 = ((s1 & 7) ^ (r1 & 7)) << 3;
    const int r2 = s2 >> 3, c2 = ((s2 & 7) ^ (r2 & 7)) << 3;
    const unsigned short* Ag1 = A + (size_t)(bm * 64 + r1) * lda + c1;
    const unsigned short* Ag2 = A + (size_t)(bm * 64 + r2) * lda + c2;
    const unsigned short* Bg1 = B + (size_t)(bn * 64 + r1) * ldb + c1;
    const unsigned short* Bg2 = B + (size_t)(bn * 64 + r2) * ldb + c2;

    f32x4 acc[2][2];
#pragma unroll
    for (int mt = 0; mt < 2; ++mt)
#pragma unroll
        for (int nt = 0; nt < 2; ++nt) acc[mt][nt] = (f32x4){0.f, 0.f, 0.f, 0.f};

    const int nsteps = K >> 6;
    STAGE_T(0, 0);
    if (nsteps > 1) {
        STAGE_T(1, 64);
        asm volatile("s_waitcnt vmcnt(4)" ::: "memory");
    } else {
        asm volatile("s_waitcnt vmcnt(0)" ::: "memory");
    }
    __builtin_amdgcn_s_barrier();

    int cur = 0;
    for (int t = 0; t < nsteps; ++t) {
        if (t + 2 < nsteps) {
            const int bw = (cur >= 1) ? cur - 1 : 2;
            STAGE_T(bw, (t + 2) << 6);
        }
        const unsigned short* Ab = &As[cur][0];
        const unsigned short* Bb = &Bs[cur][0];
        s16x8 a[2][2], bfr[2][2];
#pragma unroll
        for (int mt = 0; mt < 2; ++mt) {
            const int ar = wr * 32 + mt * 16 + lr;
#pragma unroll
            for (int ks = 0; ks < 2; ++ks)
                a[mt][ks] = *(const s16x8*)&Ab[(ar * 8 + ((ks * 4 + lg) ^ (ar & 7))) * 8];
        }
#pragma unroll
        for (int nt = 0; nt < 2; ++nt) {
            const int br = wc * 32 + nt * 16 + lr;
#pragma unroll
            for (int ks = 0; ks < 2; ++ks)
                bfr[nt][ks] = *(const s16x8*)&Bb[(br * 8 + ((ks * 4 + lg) ^ (br & 7))) * 8];
        }
#pragma unroll
        for (int ks = 0; ks < 2; ++ks)
#pragma unroll
            for (int mt = 0; mt < 2; ++mt)
#pragma unroll
                for (int nt = 0; nt < 2; ++nt)
                    acc[mt][nt] = __builtin_amdgcn_mfma_f32_16x16x32_bf16(
                        a[mt][ks], bfr[nt][ks], acc[mt][nt], 0, 0, 0);
        if (t + 1 < nsteps) {
            if (t + 2 < nsteps) asm volatile("s_waitcnt vmcnt(4)" ::: "memory");
            else                asm volatile("s_waitcnt vmcnt(0)" ::: "memory");
            __builtin_amdgcn_s_barrier();
        }
        cur = (cur < 2) ? cur + 1 : 0;
    }
    // epilogue: col = bn*64 + wc*32 + nt*16 + lr; gate = col&3 = lane&3
    const int gte  = lane & 3;
    const int base = lane & ~3;
#pragma unroll
    for (int nt = 0; nt < 2; ++nt) {
        const int col = bn * 64 + wc * 32 + nt * 16 + lr;
        const int u = col >> 2;     // unit index in [0,512)
#pragma unroll
        for (int mt = 0; mt < 2; ++mt) {
            const int rbase = bm * 64 + wr * 32 + mt * 16 + lg * 4;
#pragma unroll
            for (int r = 0; r < 4; ++r) {
                const float vv = acc[mt][nt][r];
                const float a  = (gte == 2) ? tanhf_fast(vv) : sigf(vv);
                const float ai = __shfl(a, base + 0);
                const float af = __shfl(a, base + 1);
                const float ag = __shfl(a, base + 2);
                const float ao = __shfl(a, base + 3);
                const int row = rbase + r;
                const float c  = c_in[(size_t)row * 512 + u];
                const float c2 = af * c + ai * ag;
                const float h2 = ao * tanhf_fast(c2);
                if (gte == 0)      c_out[(size_t)row * 512 + u] = c2;
                else if (gte == 1) h_a[(size_t)row * 512 + u] = h2;
                else if (gte == 2) { if (h_b) h_b[(size_t)row * 512 + u] = h2; }
                else if (hbf)      hbf[(size_t)row * hbf_ld + u] = f2bf(h2);
            }
        }
    }
}
#undef STAGE_T

// ---------------- fused deformable sampling + context attention ------------
// obat (B,768) = [off(128) | aw_raw(128) | atth(512)]  (biases included)
__global__ __launch_bounds__(512, 2) void fused_att(
    const float* __restrict__ v,       // (1920, 512)
    const float* __restrict__ obat,    // (B, 768)
    const float* __restrict__ refp,    // (B, 4)
    const int*   __restrict__ shapes,  // (4,)
    const int*   __restrict__ starts,  // (4,)
    const unsigned short* __restrict__ Wb,  // (512, 64) bf16, = Wctx^T
    const float* __restrict__ bctx,    // (512,)
    const float* __restrict__ walpha,  // (512,)
    unsigned short* __restrict__ attdst)    // bf16, row stride 2048
{
    __shared__ unsigned short cf[128 * 64];   // 16 KB, XOR chunk-swizzled
    __shared__ float ba[512];                 // bctx + atth[b]
    __shared__ float wal[512];
    __shared__ float awb[128];
    __shared__ float dsum[128];
    __shared__ float dots4[4][128];

    const int b   = blockIdx.x;
    const int tid = threadIdx.x;

    // phase 0: attention-weight softmax (16 per head)
    if (tid < 128) awb[tid] = obat[b * 768 + 128 + tid];
    __syncthreads();
    if (tid < 8) {
        float mx = -1e30f;
        for (int i = 0; i < 16; ++i) mx = fmaxf(mx, awb[tid * 16 + i]);
        float sum = 0.f;
        for (int i = 0; i < 16; ++i) { float e = exp2f_fast((awb[tid * 16 + i] - mx) * LOG2E); awb[tid * 16 + i] = e; sum += e; }
        float inv = rcpf(sum);
        for (int i = 0; i < 16; ++i) awb[tid * 16 + i] *= inv;
    }
    __syncthreads();

    // phase 1: bilinear sampling -> cf[p][d] = bf16(samp[d] * aw[p]); stage ba/wal
    ba[tid]  = bctx[tid] + obat[b * 768 + 256 + tid];
    wal[tid] = walpha[tid];
    {
        const int pg  = tid >> 2;
        const int sub = tid & 3;
        const int d0  = sub * 16;
        const int h   = pg >> 4;
        const int l   = (pg & 15) >> 2;
        const int Tlen = shapes[l];
        const int st   = starts[l];
        const float T  = (float)Tlen;
        const float refv = refp[b * 4 + l];
        const float offv = obat[b * 768 + pg];
        const float awv  = awb[pg];
        const float x   = (refv + offv * rcpf(T)) * T - 0.5f;  // exact: T is 2^k
        const float x0f = floorf(x);
        const float w1  = x - x0f;
        const int   x0  = (int)x0f;
        const float w0s = (x0 >= 0 && x0 < Tlen) ? (1.0f - w1) : 0.0f;
        const float w1s = (x0 + 1 >= 0 && x0 + 1 < Tlen) ? w1 : 0.0f;
        const int i0 = (min(max(x0, 0), Tlen - 1) + st) * 512 + h * 64;
        const int i1 = (min(max(x0 + 1, 0), Tlen - 1) + st) * 512 + h * 64;
        u16x8 o0, o1;
#pragma unroll
        for (int q = 0; q < 4; ++q) {
            const float4 a  = *(const float4*)&v[i0 + d0 + q * 4];
            const float4 bq = *(const float4*)&v[i1 + d0 + q * 4];
            unsigned short e0 = f2bf((a.x * w0s + bq.x * w1s) * awv);
            unsigned short e1 = f2bf((a.y * w0s + bq.y * w1s) * awv);
            unsigned short e2 = f2bf((a.z * w0s + bq.z * w1s) * awv);
            unsigned short e3 = f2bf((a.w * w0s + bq.w * w1s) * awv);
            if (q == 0) { o0[0] = e0; o0[1] = e1; o0[2] = e2; o0[3] = e3; }
            if (q == 1) { o0[4] = e0; o0[5] = e1; o0[6] = e2; o0[7] = e3; }
            if (q == 2) { o1[0] = e0; o1[1] = e1; o1[2] = e2; o1[3] = e3; }
            if (q == 3) { o1[4] = e0; o1[5] = e1; o1[6] = e2; o1[7] = e3; }
        }
        const int c0 = (sub * 2)     ^ (pg & 7);
        const int c1 = (sub * 2 + 1) ^ (pg & 7);
        *(u16x8*)&cf[pg * 64 + c0 * 8] = o0;
        *(u16x8*)&cf[pg * 64 + c1 * 8] = o1;
    }
    __syncthreads();

    // phase 2: dots[p] = sum_j tanh((cf@Wctx)[p][j] + ba[j]) * wal[j]  via MFMA
    {
        const int w    = tid >> 6, lane = tid & 63;
        const int wm   = w >> 2, wn = w & 3;
        const int lr   = lane & 15, lg = lane >> 4;

        s16x8 afrag[4][2];
#pragma unroll
        for (int mt = 0; mt < 4; ++mt) {
            const int row = wm * 64 + mt * 16 + lr;
#pragma unroll
            for (int ks = 0; ks < 2; ++ks) {
                const int ch = (ks * 4 + lg) ^ (row & 7);
                afrag[mt][ks] = *(const s16x8*)&cf[row * 64 + ch * 8];
            }
        }
        f32x4 part[4];
#pragma unroll
        for (int mt = 0; mt < 4; ++mt) part[mt] = (f32x4){0.f, 0.f, 0.f, 0.f};

#pragma clang loop unroll(disable)
        for (int nt = 0; nt < 8; ++nt) {
            const int ct  = wn * 8 + nt;
            const int col = ct * 16 + lr;
            const s16x8 b0 = *(const s16x8*)&Wb[col * 64 + lg * 8];
            const s16x8 b1 = *(const s16x8*)&Wb[col * 64 + 32 + lg * 8];
            const float bav = ba[col], wav = wal[col];
#pragma unroll
            for (int mt = 0; mt < 4; ++mt) {
                f32x4 acc = {0.f, 0.f, 0.f, 0.f};
                acc = __builtin_amdgcn_mfma_f32_16x16x32_bf16(afrag[mt][0], b0, acc, 0, 0, 0);
                acc = __builtin_amdgcn_mfma_f32_16x16x32_bf16(afrag[mt][1], b1, acc, 0, 0, 0);
#pragma unroll
                for (int r = 0; r < 4; ++r)
                    part[mt][r] += tanhf_fast(acc[r] + bav) * wav;
            }
        }
#pragma unroll
        for (int mt = 0; mt < 4; ++mt) {
#pragma unroll
            for (int r = 0; r < 4; ++r) {
                float s = part[mt][r];
                s += __shfl_xor(s, 1); s += __shfl_xor(s, 2);
                s += __shfl_xor(s, 4); s += __shfl_xor(s, 8);
                if (lr == 0) dots4[wn][wm * 64 + mt * 16 + lg * 4 + r] = s;
            }
        }
    }
    __syncthreads();
    if (tid < 128)
        dsum[tid] = dots4[0][tid] + dots4[1][tid] + dots4[2][tid] + dots4[3][tid];
    __syncthreads();

    // phase 3: softmax over the 16 points of each head
    if (tid < 8) {
        float mx = -1e30f;
        for (int i = 0; i < 16; ++i) mx = fmaxf(mx, dsum[tid * 16 + i]);
        float sum = 0.f;
        for (int i = 0; i < 16; ++i) { float e = exp2f_fast((dsum[tid * 16 + i] - mx) * LOG2E); dsum[tid * 16 + i] = e; sum += e; }
        float inv = rcpf(sum);
        for (int i = 0; i < 16; ++i) dsum[tid * 16 + i] *= inv;
    }
    __syncthreads();

    // phase 4: att_res (bf16 into Acat)
    {
        const int h = tid >> 6, d = tid & 63;
        const int ch = d >> 3, e = d & 7;
        float s = 0.f;
#pragma unroll
        for (int p = 0; p < 16; ++p) {
            const int row = h * 16 + p;
            s += dsum[h * 16 + p] * bf2f(cf[row * 64 + ((ch ^ (row & 7)) * 8) + e]);
        }
        attdst[(size_t)b * 2048 + tid] = f2bf(s);
    }
}

extern "C" void kernel_launch(void* const* d_in, const int* in_sizes, int n_in,
                              void* d_out, int out_size, void* d_ws, size_t ws_size,
                              hipStream_t stream) {
    const float* xt     = (const float*)d_in[0];
    const float* h0     = (const float*)d_in[1];   // (2,1024,512)
    const float* c0     = (const float*)d_in[2];
    const float* query  = (const float*)d_in[3];   // (1,1024,512)
    const float* refp   = (const float*)d_in[4];   // (1,1024,4,1)
    const float* inflat = (const float*)d_in[5];   // (1,1920,512)
    const int*   shapes = (const int*)d_in[6];
    const int*   starts = (const int*)d_in[7];
    const float* Wv     = (const float*)d_in[9];   // (512,512) (K,N)
    const float* bv     = (const float*)d_in[10];
    const float* Woff   = (const float*)d_in[11];  // (1024,128) (K,N)
    const float* boff   = (const float*)d_in[12];
    const float* Wattw  = (const float*)d_in[13];  // (1024,128)
    const float* battw  = (const float*)d_in[14];
    const float* Wctx   = (const float*)d_in[15];  // (64,512)
    const float* bctx   = (const float*)d_in[16];
    const float* Wh2a   = (const float*)d_in[17];  // (512,512) (K,N)
    const float* bh2a   = (const float*)d_in[18];
    const float* walpha = (const float*)d_in[19];
    const float* Wih0   = (const float*)d_in[21];  // (2048,1536) (N,K)
    const float* Whh0   = (const float*)d_in[22];  // (2048,512)
    const float* Wih1   = (const float*)d_in[23];  // (2048,512)
    const float* Whh1   = (const float*)d_in[24];  // (2048,512)

    float* out = (float*)d_out;
    float* ws  = (float*)d_ws;

    // ws layout (f32 units), lifetime-overlapped
    float*          v     = ws;                                   // 983040
    float*          obat  = ws + 983040;                          // 1024x768 [off|aw|atth]
    unsigned short* Acat  = (unsigned short*)(ws + 1769472);      // 1024x2048 bf16
    unsigned short* Bcat0 = (unsigned short*)(ws + 2818048);      // 2048x2048 bf16 (gate-ilv)
    unsigned short* Ainf  = (unsigned short*)(ws + 4915200);      // 1920x512 bf16
    unsigned short* Wvt   = (unsigned short*)(ws + 5406720);      // 512x512 bf16
    unsigned short* Wcat  = (unsigned short*)(ws + 5537792);      // 768x1024 bf16
    unsigned short* Ahq   = (unsigned short*)(ws + 5931008);      // 1024x1024 bf16
    unsigned short* Wb    = (unsigned short*)(ws + 6455296);      // 512x64 bf16 (Wctx^T)
    float*          bcat  = ws + 6471680;                         // 768
    unsigned short* Ag1   = (unsigned short*)(ws + 7012352);      // 1024x1024 bf16
    unsigned short* Bcat1 = (unsigned short*)(ws + 7536640);      // 2048x1024 bf16 (gate-ilv)

    const float* h00    = h0;
    const float* h_last = h0 + 524288;     // h0[1]
    float* h1  = out + 524288;             // h_new[0]
    float* c1  = out + 1572864;            // c_new[0]
    float* h2a = out;                      // first output
    float* h2b = out + 1048576;            // h_new[1]
    float* c2  = out + 2097152;            // c_new[1]

    // --- prep: converts (1 launch), tiled transposes + zero-pad (1 launch), biases ---
    { CvtJobs cj;
      cj.j[0]  = { xt,     Acat,          512,  2048, 512,  524288,  0 };
      cj.j[1]  = { query,  Acat + 1024,   512,  2048, 512,  524288,  0 };
      cj.j[2]  = { h00,    Acat + 1536,   512,  2048, 512,  524288,  0 };
      cj.j[3]  = { h_last, Ahq,           512,  1024, 512,  524288,  0 };
      cj.j[4]  = { query,  Ahq + 512,     512,  1024, 512,  524288,  0 };
      cj.j[5]  = { h_last, Ag1 + 512,     512,  1024, 512,  524288,  0 };
      cj.j[6]  = { Wih0,   Bcat0,         1536, 2048, 1536, 3145728, 1 };
      cj.j[7]  = { Whh0,   Bcat0 + 1536,  512,  2048, 512,  1048576, 1 };
      cj.j[8]  = { Wih1,   Bcat1,         512,  1024, 512,  1048576, 1 };
      cj.j[9]  = { Whh1,   Bcat1 + 512,   512,  1024, 512,  1048576, 1 };
      cj.j[10] = { inflat, Ainf,          512,  512,  512,  983040,  0 };
      cvt_bf16<<<dim3(3072, 11), 256, 0, stream>>>(cj); }
    { TJobs tj;
      tj.j[0] = { Wv,      Wvt,                     512, 512,  512, 0 };
      tj.j[1] = { Woff,    Wcat,                    128, 1024, 1024, 0 };
      tj.j[2] = { Wattw,   Wcat + 128 * 1024,       128, 1024, 1024, 0 };
      tj.j[3] = { Wh2a,    Wcat + 256 * 1024,       512, 1024, 512, 0 };
      tj.j[4] = { Wctx,    Wb,                      512, 64,   64,  0 };
      tj.j[5] = { nullptr, Wcat + 256 * 1024 + 512, 512, 1024, 512, 0 }; // zero K-pad
      tcvt_bf16<<<dim3(256, 6), 256, 0, stream>>>(tj); }
    bias_cat3<<<1, 768, 0, stream>>>(boff, battw, bh2a, bcat);

    // --- GEMMs (bf16 MFMA, 64x64 tile, BK=64 staged) ---
    // value: v = inflat @ Wv + bv          (1920x512, K=512)
    sgemm<<<dim3(8, 30), 256, 0, stream>>>(Ainf, 512, Wvt, 512, bv, v, 512, 512);
    // obat = [h_last|query] @ [Woff|Wattw|Wh2a pad] + [boff|battw|bh2a]  (1024x768, K=1024)
    sgemm<<<dim3(12, 16), 256, 0, stream>>>(Ahq, 1024, Wcat, 1024, bcat, obat, 768, 1024);

    // --- fused deformable sampling + context attention (writes Acat[:,512:1024]) ---
    fused_att<<<1024, 512, 0, stream>>>(v, obat, refp, shapes, starts,
                                        Wb, bctx, walpha, Acat + 512);

    // LSTM0: gates+activation fused; writes h1, c1, Ag1[:, :512] (bf16)
    sgemm_lstm<<<dim3(32, 16), 256, 0, stream>>>(Acat, 2048, Bcat0, 2048,
                                                 c0, h1, nullptr, Ag1, 1024, c1, 2048);
    // LSTM1: writes h2 (outputs 0 and h_new[1]), c2
    sgemm_lstm<<<dim3(32, 16), 256, 0, stream>>>(Ag1, 1024, Bcat1, 1024,
                                                 c0 + 524288, h1 - 524288, h2b, nullptr, 0, c2, 1024);
}

// Round 14
// 120.627 us; speedup vs baseline: 1.3101x; 1.0214x over previous
//
#include <hip/hip_runtime.h>
#include <math.h>

// Problem constants (ShowAttendTellCore)
//   B=1024, D_MODEL=512, N_HEADS=8, D_HEAD=64, N_LEVELS=4, N_POINTS=4
//   T_TOTAL=1920, RNN=512, ENC=512, ATT_HID=512
// Output layout (f32): h2 (524288) | h1 | h2 | c1 | c2   (total 2621440)

typedef __attribute__((ext_vector_type(8))) short          s16x8;
typedef __attribute__((ext_vector_type(8))) unsigned short u16x8;
typedef __attribute__((ext_vector_type(4))) float          f32x4;

#define LOG2E  1.4426950408889634f
#define LOG2E2 2.8853900817779268f

__device__ __forceinline__ float rcpf(float x) { return __builtin_amdgcn_rcpf(x); }
__device__ __forceinline__ float exp2f_fast(float x) { return __builtin_amdgcn_exp2f(x); }
__device__ __forceinline__ float sigf(float x) {
    return rcpf(1.0f + exp2f_fast(-x * LOG2E));
}
__device__ __forceinline__ float tanhf_fast(float x) {
    const float xc = fminf(fmaxf(x, -15.0f), 15.0f);
    const float e2 = exp2f_fast(xc * LOG2E2);
    return 1.0f - 2.0f * rcpf(e2 + 1.0f);
}
__device__ __forceinline__ unsigned short f2bf(float f) {   // RNE f32->bf16
    unsigned u = __float_as_uint(f);
    u += 0x7FFF + ((u >> 16) & 1);
    return (unsigned short)(u >> 16);
}
__device__ __forceinline__ float bf2f(unsigned short h) {
    return __uint_as_float(((unsigned)h) << 16);
}
// async global->LDS, 16B per lane
__device__ __forceinline__ void gld_lds16(const unsigned short* g, unsigned short* l) {
    __builtin_amdgcn_global_load_lds(
        (const __attribute__((address_space(1))) void*)g,
        (__attribute__((address_space(3))) void*)l, 16, 0, 0);
}

// ---------------- batched f32 -> bf16 strided converts (one launch) --------
// ilv != 0: LSTM gate-interleave of dst rows: row' = (row%512)*4 + row/512.
struct CvtJob { const float* src; unsigned short* dst; int sld, dld, cols, total, ilv; };
struct CvtJobs { CvtJob j[11]; };
__global__ __launch_bounds__(256) void cvt_bf16(CvtJobs cj) {
    const CvtJob jb = cj.j[blockIdx.y];
    const int i = (blockIdx.x * 256 + threadIdx.x) * 4;
    if (i >= jb.total) return;
    const int r = i / jb.cols, c = i - r * jb.cols;
    const int rd = jb.ilv ? (((r & 511) << 2) | (r >> 9)) : r;
    const float4 v4 = *(const float4*)&jb.src[(size_t)r * jb.sld + c];
    ushort4 o;
    o.x = f2bf(v4.x); o.y = f2bf(v4.y); o.z = f2bf(v4.z); o.w = f2bf(v4.w);
    *(ushort4*)&jb.dst[(size_t)rd * jb.dld + c] = o;
}

// transpose-convert via 32x32 LDS tile; src==nullptr -> zeros.
struct TJob { const float* src; unsigned short* dst; int N_, dld, K_, total; };
struct TJobs { TJob j[6]; };
__global__ __launch_bounds__(256) void tcvt_bf16(TJobs tj) {
    const TJob jb = tj.j[blockIdx.y];
    const int tilesN = jb.N_ >> 5, tilesK = jb.K_ >> 5;
    const int tile = blockIdx.x;
    if (tile >= tilesN * tilesK) return;
    const int tn0 = (tile % tilesN) << 5, tk0 = (tile / tilesN) << 5;
    __shared__ float lds[32][33];
    const int t = threadIdx.x;
    if (jb.src) {
#pragma unroll
        for (int q = 0; q < 4; ++q) {
            const int e = t + (q << 8);
            lds[e >> 5][e & 31] = jb.src[(size_t)(tk0 + (e >> 5)) * jb.N_ + tn0 + (e & 31)];
        }
        __syncthreads();
#pragma unroll
        for (int q = 0; q < 4; ++q) {
            const int e = t + (q << 8);
            const int n = e >> 5, k = e & 31;
            jb.dst[(size_t)(tn0 + n) * jb.dld + tk0 + k] = f2bf(lds[k][n]);
        }
    } else {
#pragma unroll
        for (int q = 0; q < 4; ++q) {
            const int e = t + (q << 8);
            jb.dst[(size_t)(tn0 + (e >> 5)) * jb.dld + tk0 + (e & 31)] = 0;
        }
    }
}

// bcat = [boff(128) | battw(128) | bh2a(512)]
__global__ __launch_bounds__(768) void bias_cat3(const float* __restrict__ a,
                                                 const float* __restrict__ b,
                                                 const float* __restrict__ c,
                                                 float* __restrict__ dst) {
    const int t = threadIdx.x;
    dst[t] = (t < 128) ? a[t] : (t < 256 ? b[t - 128] : c[t - 256]);
}

// ===== 64x64-tile, BK=64, 4-buffer deep-pipelined staged GEMMs =============
// R13 post-mortem: 3-buf kept only ~1.5 steps of lookahead; HBM miss ~900cy
// exposed per step (t_step ~1950cy vs ~300cy issue work). 4 buffers + 3-step
// prefetch distance: iter = {wait vmcnt(8); s_barrier; stage(t+3); compute t}.
// Wait/barrier BEFORE stage seals the WAR on buf (t+3)%4 == (t-1)%4.
// LDS 64KB/block -> 2 blocks/CU. XOR swizzle per rule #21 as in R13.

#define STAGE_T(buf, k0) do { \
        gld_lds16(Ag1 + (k0), &As[buf][s1 * 8]); \
        gld_lds16(Ag2 + (k0), &As[buf][s2 * 8]); \
        gld_lds16(Bg1 + (k0), &Bs[buf][s1 * 8]); \
        gld_lds16(Bg2 + (k0), &Bs[buf][s2 * 8]); } while (0)

#define WAIT_INFL(t) do { \
        const int infl_ = nsteps - 1 - (t); \
        if (infl_ >= 2)      asm volatile("s_waitcnt vmcnt(8)" ::: "memory"); \
        else if (infl_ == 1) asm volatile("s_waitcnt vmcnt(4)" ::: "memory"); \
        else                 asm volatile("s_waitcnt vmcnt(0)" ::: "memory"); \
        __builtin_amdgcn_s_barrier(); } while (0)

// ---------------- LDS-staged bf16 MFMA GEMM (BM=BN=64, BK=64) --------------
// C(MxN f32) = A(MxK bf16 rm) @ B^T (B NxK bf16 rm) + bias
// grid=(N/64, M/64); 4 waves (2x2), wave=32x32 (acc 2x2). K % 64 == 0.
__global__ __launch_bounds__(256) void sgemm(
    const unsigned short* __restrict__ A, int lda,
    const unsigned short* __restrict__ B, int ldb,
    const float* __restrict__ bias, float* __restrict__ C, int ldc, int K)
{
    __shared__ unsigned short As[4][64 * 64];    // 8KB x4
    __shared__ unsigned short Bs[4][64 * 64];    // 8KB x4

    const int tid = threadIdx.x;
    const int w = tid >> 6, lane = tid & 63;
    const int wr = w >> 1, wc = w & 1;
    const int lr = lane & 15, lg = lane >> 4;
    const int bm = blockIdx.y, bn = blockIdx.x;

    // staging slots s = tid, tid+256; slot s = row s>>3, global chunk (s&7)^(row&7)
    const int s1 = tid, s2 = tid + 256;
    const int r1 = s1 >> 3, c1 = ((s1 & 7) ^ (r1 & 7)) << 3;
    const int r2 = s2 >> 3, c2 = ((s2 & 7) ^ (r2 & 7)) << 3;
    const unsigned short* Ag1 = A + (size_t)(bm * 64 + r1) * lda + c1;
    const unsigned short* Ag2 = A + (size_t)(bm * 64 + r2) * lda + c2;
    const unsigned short* Bg1 = B + (size_t)(bn * 64 + r1) * ldb + c1;
    const unsigned short* Bg2 = B + (size_t)(bn * 64 + r2) * ldb + c2;

    f32x4 acc[2][2];
#pragma unroll
    for (int mt = 0; mt < 2; ++mt)
#pragma unroll
        for (int nt = 0; nt < 2; ++nt) acc[mt][nt] = (f32x4){0.f, 0.f, 0.f, 0.f};

    const int nsteps = K >> 6;
    // prologue: stage up to 3 tiles ahead
    STAGE_T(0, 0);
    if (nsteps > 1) STAGE_T(1, 64);
    if (nsteps > 2) STAGE_T(2, 128);

    for (int t = 0; t < nsteps; ++t) {
        WAIT_INFL(t);                          // tile t resident on ALL waves
        if (t + 3 < nsteps)                    // stage t+3 into buf (t+3)&3
            STAGE_T((t + 3) & 3, (t + 3) << 6);
        const unsigned short* Ab = &As[t & 3][0];
        const unsigned short* Bb = &Bs[t & 3][0];
        s16x8 a[2][2], bfr[2][2];
#pragma unroll
        for (int mt = 0; mt < 2; ++mt) {
            const int ar = wr * 32 + mt * 16 + lr;
#pragma unroll
            for (int ks = 0; ks < 2; ++ks)
                a[mt][ks] = *(const s16x8*)&Ab[(ar * 8 + ((ks * 4 + lg) ^ (ar & 7))) * 8];
        }
#pragma unroll
        for (int nt = 0; nt < 2; ++nt) {
            const int br = wc * 32 + nt * 16 + lr;
#pragma unroll
            for (int ks = 0; ks < 2; ++ks)
                bfr[nt][ks] = *(const s16x8*)&Bb[(br * 8 + ((ks * 4 + lg) ^ (br & 7))) * 8];
        }
#pragma unroll
        for (int ks = 0; ks < 2; ++ks)
#pragma unroll
            for (int mt = 0; mt < 2; ++mt)
#pragma unroll
                for (int nt = 0; nt < 2; ++nt)
                    acc[mt][nt] = __builtin_amdgcn_mfma_f32_16x16x32_bf16(
                        a[mt][ks], bfr[nt][ks], acc[mt][nt], 0, 0, 0);
    }
#pragma unroll
    for (int nt = 0; nt < 2; ++nt) {
        const int col = bn * 64 + wc * 32 + nt * 16 + lr;
        const float bb = bias ? bias[col] : 0.0f;
#pragma unroll
        for (int mt = 0; mt < 2; ++mt) {
            const int rbase = bm * 64 + wr * 32 + mt * 16 + lg * 4;
#pragma unroll
            for (int r = 0; r < 4; ++r)
                C[(size_t)(rbase + r) * ldc + col] = acc[mt][nt][r] + bb;
        }
    }
}

// ---------------- deep-pipelined GEMM + fused LSTM activation epilogue -----
// B rows gate-interleaved (col = 4*unit + gate, gate order i,f,g,o).
__global__ __launch_bounds__(256) void sgemm_lstm(
    const unsigned short* __restrict__ A, int lda,
    const unsigned short* __restrict__ B, int ldb,
    const float* __restrict__ c_in,
    float* __restrict__ h_a, float* __restrict__ h_b,
    unsigned short* __restrict__ hbf, int hbf_ld,
    float* __restrict__ c_out, int K)
{
    __shared__ unsigned short As[4][64 * 64];
    __shared__ unsigned short Bs[4][64 * 64];

    const int tid = threadIdx.x;
    const int w = tid >> 6, lane = tid & 63;
    const int wr = w >> 1, wc = w & 1;
    const int lr = lane & 15, lg = lane >> 4;
    const int bm = blockIdx.y, bn = blockIdx.x;

    const int s1 = tid, s2 = tid + 256;
    const int r1 = s1 >> 3, c1 = ((s1 & 7) ^ (r1 & 7)) << 3;
    const int r2 = s2 >> 3, c2 = ((s2 & 7) ^ (r2 & 7)) << 3;
    const unsigned short* Ag1 = A + (size_t)(bm * 64 + r1) * lda + c1;
    const unsigned short* Ag2 = A + (size_t)(bm * 64 + r2) * lda + c2;
    const unsigned short* Bg1 = B + (size_t)(bn * 64 + r1) * ldb + c1;
    const unsigned short* Bg2 = B + (size_t)(bn * 64 + r2) * ldb + c2;

    f32x4 acc[2][2];
#pragma unroll
    for (int mt = 0; mt < 2; ++mt)
#pragma unroll
        for (int nt = 0; nt < 2; ++nt) acc[mt][nt] = (f32x4){0.f, 0.f, 0.f, 0.f};

    const int nsteps = K >> 6;
    STAGE_T(0, 0);
    if (nsteps > 1) STAGE_T(1, 64);
    if (nsteps > 2) STAGE_T(2, 128);

    for (int t = 0; t < nsteps; ++t) {
        WAIT_INFL(t);
        if (t + 3 < nsteps)
            STAGE_T((t + 3) & 3, (t + 3) << 6);
        const unsigned short* Ab = &As[t & 3][0];
        const unsigned short* Bb = &Bs[t & 3][0];
        s16x8 a[2][2], bfr[2][2];
#pragma unroll
        for (int mt = 0; mt < 2; ++mt) {
            const int ar = wr * 32 + mt * 16 + lr;
#pragma unroll
            for (int ks = 0; ks < 2; ++ks)
                a[mt][ks] = *(const s16x8*)&Ab[(ar * 8 + ((ks * 4 + lg) ^ (ar & 7))) * 8];
        }
#pragma unroll
        for (int nt = 0; nt < 2; ++nt) {
            const int br = wc * 32 + nt * 16 + lr;
#pragma unroll
            for (int ks = 0; ks < 2; ++ks)
                bfr[nt][ks] = *(const s16x8*)&Bb[(br * 8 + ((ks * 4 + lg) ^ (br & 7))) * 8];
        }
#pragma unroll
        for (int ks = 0; ks < 2; ++ks)
#pragma unroll
            for (int mt = 0; mt < 2; ++mt)
#pragma unroll
                for (int nt = 0; nt < 2; ++nt)
                    acc[mt][nt] = __builtin_amdgcn_mfma_f32_16x16x32_bf16(
                        a[mt][ks], bfr[nt][ks], acc[mt][nt], 0, 0, 0);
    }
    // epilogue: col = bn*64 + wc*32 + nt*16 + lr; gate = col&3 = lane&3
    const int gte  = lane & 3;
    const int base = lane & ~3;
#pragma unroll
    for (int nt = 0; nt < 2; ++nt) {
        const int col = bn * 64 + wc * 32 + nt * 16 + lr;
        const int u = col >> 2;     // unit index in [0,512)
#pragma unroll
        for (int mt = 0; mt < 2; ++mt) {
            const int rbase = bm * 64 + wr * 32 + mt * 16 + lg * 4;
#pragma unroll
            for (int r = 0; r < 4; ++r) {
                const float vv = acc[mt][nt][r];
                const float a  = (gte == 2) ? tanhf_fast(vv) : sigf(vv);
                const float ai = __shfl(a, base + 0);
                const float af = __shfl(a, base + 1);
                const float ag = __shfl(a, base + 2);
                const float ao = __shfl(a, base + 3);
                const int row = rbase + r;
                const float c  = c_in[(size_t)row * 512 + u];
                const float c2 = af * c + ai * ag;
                const float h2 = ao * tanhf_fast(c2);
                if (gte == 0)      c_out[(size_t)row * 512 + u] = c2;
                else if (gte == 1) h_a[(size_t)row * 512 + u] = h2;
                else if (gte == 2) { if (h_b) h_b[(size_t)row * 512 + u] = h2; }
                else if (hbf)      hbf[(size_t)row * hbf_ld + u] = f2bf(h2);
            }
        }
    }
}
#undef STAGE_T
#undef WAIT_INFL

// ---------------- fused deformable sampling + context attention ------------
// obat (B,768) = [off(128) | aw_raw(128) | atth(512)]  (biases included)
__global__ __launch_bounds__(512, 2) void fused_att(
    const float* __restrict__ v,       // (1920, 512)
    const float* __restrict__ obat,    // (B, 768)
    const float* __restrict__ refp,    // (B, 4)
    const int*   __restrict__ shapes,  // (4,)
    const int*   __restrict__ starts,  // (4,)
    const unsigned short* __restrict__ Wb,  // (512, 64) bf16, = Wctx^T
    const float* __restrict__ bctx,    // (512,)
    const float* __restrict__ walpha,  // (512,)
    unsigned short* __restrict__ attdst)    // bf16, row stride 2048
{
    __shared__ unsigned short cf[128 * 64];   // 16 KB, XOR chunk-swizzled
    __shared__ float ba[512];                 // bctx + atth[b]
    __shared__ float wal[512];
    __shared__ float awb[128];
    __shared__ float dsum[128];
    __shared__ float dots4[4][128];

    const int b   = blockIdx.x;
    const int tid = threadIdx.x;

    // phase 0: attention-weight softmax (16 per head)
    if (tid < 128) awb[tid] = obat[b * 768 + 128 + tid];
    __syncthreads();
    if (tid < 8) {
        float mx = -1e30f;
        for (int i = 0; i < 16; ++i) mx = fmaxf(mx, awb[tid * 16 + i]);
        float sum = 0.f;
        for (int i = 0; i < 16; ++i) { float e = exp2f_fast((awb[tid * 16 + i] - mx) * LOG2E); awb[tid * 16 + i] = e; sum += e; }
        float inv = rcpf(sum);
        for (int i = 0; i < 16; ++i) awb[tid * 16 + i] *= inv;
    }
    __syncthreads();

    // phase 1: bilinear sampling -> cf[p][d] = bf16(samp[d] * aw[p]); stage ba/wal
    ba[tid]  = bctx[tid] + obat[b * 768 + 256 + tid];
    wal[tid] = walpha[tid];
    {
        const int pg  = tid >> 2;
        const int sub = tid & 3;
        const int d0  = sub * 16;
        const int h   = pg >> 4;
        const int l   = (pg & 15) >> 2;
        const int Tlen = shapes[l];
        const int st   = starts[l];
        const float T  = (float)Tlen;
        const float refv = refp[b * 4 + l];
        const float offv = obat[b * 768 + pg];
        const float awv  = awb[pg];
        const float x   = (refv + offv * rcpf(T)) * T - 0.5f;  // exact: T is 2^k
        const float x0f = floorf(x);
        const float w1  = x - x0f;
        const int   x0  = (int)x0f;
        const float w0s = (x0 >= 0 && x0 < Tlen) ? (1.0f - w1) : 0.0f;
        const float w1s = (x0 + 1 >= 0 && x0 + 1 < Tlen) ? w1 : 0.0f;
        const int i0 = (min(max(x0, 0), Tlen - 1) + st) * 512 + h * 64;
        const int i1 = (min(max(x0 + 1, 0), Tlen - 1) + st) * 512 + h * 64;
        u16x8 o0, o1;
#pragma unroll
        for (int q = 0; q < 4; ++q) {
            const float4 a  = *(const float4*)&v[i0 + d0 + q * 4];
            const float4 bq = *(const float4*)&v[i1 + d0 + q * 4];
            unsigned short e0 = f2bf((a.x * w0s + bq.x * w1s) * awv);
            unsigned short e1 = f2bf((a.y * w0s + bq.y * w1s) * awv);
            unsigned short e2 = f2bf((a.z * w0s + bq.z * w1s) * awv);
            unsigned short e3 = f2bf((a.w * w0s + bq.w * w1s) * awv);
            if (q == 0) { o0[0] = e0; o0[1] = e1; o0[2] = e2; o0[3] = e3; }
            if (q == 1) { o0[4] = e0; o0[5] = e1; o0[6] = e2; o0[7] = e3; }
            if (q == 2) { o1[0] = e0; o1[1] = e1; o1[2] = e2; o1[3] = e3; }
            if (q == 3) { o1[4] = e0; o1[5] = e1; o1[6] = e2; o1[7] = e3; }
        }
        const int c0 = (sub * 2)     ^ (pg & 7);
        const int c1 = (sub * 2 + 1) ^ (pg & 7);
        *(u16x8*)&cf[pg * 64 + c0 * 8] = o0;
        *(u16x8*)&cf[pg * 64 + c1 * 8] = o1;
    }
    __syncthreads();

    // phase 2: dots[p] = sum_j tanh((cf@Wctx)[p][j] + ba[j]) * wal[j]  via MFMA
    {
        const int w    = tid >> 6, lane = tid & 63;
        const int wm   = w >> 2, wn = w & 3;
        const int lr   = lane & 15, lg = lane >> 4;

        s16x8 afrag[4][2];
#pragma unroll
        for (int mt = 0; mt < 4; ++mt) {
            const int row = wm * 64 + mt * 16 + lr;
#pragma unroll
            for (int ks = 0; ks < 2; ++ks) {
                const int ch = (ks * 4 + lg) ^ (row & 7);
                afrag[mt][ks] = *(const s16x8*)&cf[row * 64 + ch * 8];
            }
        }
        f32x4 part[4];
#pragma unroll
        for (int mt = 0; mt < 4; ++mt) part[mt] = (f32x4){0.f, 0.f, 0.f, 0.f};

#pragma clang loop unroll(disable)
        for (int nt = 0; nt < 8; ++nt) {
            const int ct  = wn * 8 + nt;
            const int col = ct * 16 + lr;
            const s16x8 b0 = *(const s16x8*)&Wb[col * 64 + lg * 8];
            const s16x8 b1 = *(const s16x8*)&Wb[col * 64 + 32 + lg * 8];
            const float bav = ba[col], wav = wal[col];
#pragma unroll
            for (int mt = 0; mt < 4; ++mt) {
                f32x4 acc = {0.f, 0.f, 0.f, 0.f};
                acc = __builtin_amdgcn_mfma_f32_16x16x32_bf16(afrag[mt][0], b0, acc, 0, 0, 0);
                acc = __builtin_amdgcn_mfma_f32_16x16x32_bf16(afrag[mt][1], b1, acc, 0, 0, 0);
#pragma unroll
                for (int r = 0; r < 4; ++r)
                    part[mt][r] += tanhf_fast(acc[r] + bav) * wav;
            }
        }
#pragma unroll
        for (int mt = 0; mt < 4; ++mt) {
#pragma unroll
            for (int r = 0; r < 4; ++r) {
                float s = part[mt][r];
                s += __shfl_xor(s, 1); s += __shfl_xor(s, 2);
                s += __shfl_xor(s, 4); s += __shfl_xor(s, 8);
                if (lr == 0) dots4[wn][wm * 64 + mt * 16 + lg * 4 + r] = s;
            }
        }
    }
    __syncthreads();
    if (tid < 128)
        dsum[tid] = dots4[0][tid] + dots4[1][tid] + dots4[2][tid] + dots4[3][tid];
    __syncthreads();

    // phase 3: softmax over the 16 points of each head
    if (tid < 8) {
        float mx = -1e30f;
        for (int i = 0; i < 16; ++i) mx = fmaxf(mx, dsum[tid * 16 + i]);
        float sum = 0.f;
        for (int i = 0; i < 16; ++i) { float e = exp2f_fast((dsum[tid * 16 + i] - mx) * LOG2E); dsum[tid * 16 + i] = e; sum += e; }
        float inv = rcpf(sum);
        for (int i = 0; i < 16; ++i) dsum[tid * 16 + i] *= inv;
    }
    __syncthreads();

    // phase 4: att_res (bf16 into Acat)
    {
        const int h = tid >> 6, d = tid & 63;
        const int ch = d >> 3, e = d & 7;
        float s = 0.f;
#pragma unroll
        for (int p = 0; p < 16; ++p) {
            const int row = h * 16 + p;
            s += dsum[h * 16 + p] * bf2f(cf[row * 64 + ((ch ^ (row & 7)) * 8) + e]);
        }
        attdst[(size_t)b * 2048 + tid] = f2bf(s);
    }
}

extern "C" void kernel_launch(void* const* d_in, const int* in_sizes, int n_in,
                              void* d_out, int out_size, void* d_ws, size_t ws_size,
                              hipStream_t stream) {
    const float* xt     = (const float*)d_in[0];
    const float* h0     = (const float*)d_in[1];   // (2,1024,512)
    const float* c0     = (const float*)d_in[2];
    const float* query  = (const float*)d_in[3];   // (1,1024,512)
    const float* refp   = (const float*)d_in[4];   // (1,1024,4,1)
    const float* inflat = (const float*)d_in[5];   // (1,1920,512)
    const int*   shapes = (const int*)d_in[6];
    const int*   starts = (const int*)d_in[7];
    const float* Wv     = (const float*)d_in[9];   // (512,512) (K,N)
    const float* bv     = (const float*)d_in[10];
    const float* Woff   = (const float*)d_in[11];  // (1024,128) (K,N)
    const float* boff   = (const float*)d_in[12];
    const float* Wattw  = (const float*)d_in[13];  // (1024,128)
    const float* battw  = (const float*)d_in[14];
    const float* Wctx   = (const float*)d_in[15];  // (64,512)
    const float* bctx   = (const float*)d_in[16];
    const float* Wh2a   = (const float*)d_in[17];  // (512,512) (K,N)
    const float* bh2a   = (const float*)d_in[18];
    const float* walpha = (const float*)d_in[19];
    const float* Wih0   = (const float*)d_in[21];  // (2048,1536) (N,K)
    const float* Whh0   = (const float*)d_in[22];  // (2048,512)
    const float* Wih1   = (const float*)d_in[23];  // (2048,512)
    const float* Whh1   = (const float*)d_in[24];  // (2048,512)

    float* out = (float*)d_out;
    float* ws  = (float*)d_ws;

    // ws layout (f32 units), lifetime-overlapped
    float*          v     = ws;                                   // 983040
    float*          obat  = ws + 983040;                          // 1024x768 [off|aw|atth]
    unsigned short* Acat  = (unsigned short*)(ws + 1769472);      // 1024x2048 bf16
    unsigned short* Bcat0 = (unsigned short*)(ws + 2818048);      // 2048x2048 bf16 (gate-ilv)
    unsigned short* Ainf  = (unsigned short*)(ws + 4915200);      // 1920x512 bf16
    unsigned short* Wvt   = (unsigned short*)(ws + 5406720);      // 512x512 bf16
    unsigned short* Wcat  = (unsigned short*)(ws + 5537792);      // 768x1024 bf16
    unsigned short* Ahq   = (unsigned short*)(ws + 5931008);      // 1024x1024 bf16
    unsigned short* Wb    = (unsigned short*)(ws + 6455296);      // 512x64 bf16 (Wctx^T)
    float*          bcat  = ws + 6471680;                         // 768
    unsigned short* Ag1   = (unsigned short*)(ws + 7012352);      // 1024x1024 bf16
    unsigned short* Bcat1 = (unsigned short*)(ws + 7536640);      // 2048x1024 bf16 (gate-ilv)

    const float* h00    = h0;
    const float* h_last = h0 + 524288;     // h0[1]
    float* h1  = out + 524288;             // h_new[0]
    float* c1  = out + 1572864;            // c_new[0]
    float* h2a = out;                      // first output
    float* h2b = out + 1048576;            // h_new[1]
    float* c2  = out + 2097152;            // c_new[1]

    // --- prep: converts (1 launch), tiled transposes + zero-pad (1 launch), biases ---
    { CvtJobs cj;
      cj.j[0]  = { xt,     Acat,          512,  2048, 512,  524288,  0 };
      cj.j[1]  = { query,  Acat + 1024,   512,  2048, 512,  524288,  0 };
      cj.j[2]  = { h00,    Acat + 1536,   512,  2048, 512,  524288,  0 };
      cj.j[3]  = { h_last, Ahq,           512,  1024, 512,  524288,  0 };
      cj.j[4]  = { query,  Ahq + 512,     512,  1024, 512,  524288,  0 };
      cj.j[5]  = { h_last, Ag1 + 512,     512,  1024, 512,  524288,  0 };
      cj.j[6]  = { Wih0,   Bcat0,         1536, 2048, 1536, 3145728, 1 };
      cj.j[7]  = { Whh0,   Bcat0 + 1536,  512,  2048, 512,  1048576, 1 };
      cj.j[8]  = { Wih1,   Bcat1,         512,  1024, 512,  1048576, 1 };
      cj.j[9]  = { Whh1,   Bcat1 + 512,   512,  1024, 512,  1048576, 1 };
      cj.j[10] = { inflat, Ainf,          512,  512,  512,  983040,  0 };
      cvt_bf16<<<dim3(3072, 11), 256, 0, stream>>>(cj); }
    { TJobs tj;
      tj.j[0] = { Wv,      Wvt,                     512, 512,  512, 0 };
      tj.j[1] = { Woff,    Wcat,                    128, 1024, 1024, 0 };
      tj.j[2] = { Wattw,   Wcat + 128 * 1024,       128, 1024, 1024, 0 };
      tj.j[3] = { Wh2a,    Wcat + 256 * 1024,       512, 1024, 512, 0 };
      tj.j[4] = { Wctx,    Wb,                      512, 64,   64,  0 };
      tj.j[5] = { nullptr, Wcat + 256 * 1024 + 512, 512, 1024, 512, 0 }; // zero K-pad
      tcvt_bf16<<<dim3(256, 6), 256, 0, stream>>>(tj); }
    bias_cat3<<<1, 768, 0, stream>>>(boff, battw, bh2a, bcat);

    // --- GEMMs (bf16 MFMA, 64x64 tile, BK=64, 4-buf deep pipeline) ---
    // value: v = inflat @ Wv + bv          (1920x512, K=512)
    sgemm<<<dim3(8, 30), 256, 0, stream>>>(Ainf, 512, Wvt, 512, bv, v, 512, 512);
    // obat = [h_last|query] @ [Woff|Wattw|Wh2a pad] + [boff|battw|bh2a]  (1024x768, K=1024)
    sgemm<<<dim3(12, 16), 256, 0, stream>>>(Ahq, 1024, Wcat, 1024, bcat, obat, 768, 1024);

    // --- fused deformable sampling + context attention (writes Acat[:,512:1024]) ---
    fused_att<<<1024, 512, 0, stream>>>(v, obat, refp, shapes, starts,
                                        Wb, bctx, walpha, Acat + 512);

    // LSTM0: gates+activation fused; writes h1, c1, Ag1[:, :512] (bf16)
    sgemm_lstm<<<dim3(32, 16), 256, 0, stream>>>(Acat, 2048, Bcat0, 2048,
                                                 c0, h1, nullptr, Ag1, 1024, c1, 2048);
    // LSTM1: writes h2 (outputs 0 and h_new[1]), c2
    sgemm_lstm<<<dim3(32, 16), 256, 0, stream>>>(Ag1, 1024, Bcat1, 1024,
                                                 c0 + 524288, h1 - 524288, h2b, nullptr, 0, c2, 1024);
}

// Round 15
// 113.743 us; speedup vs baseline: 1.3894x; 1.0605x over previous
//
#include <hip/hip_runtime.h>
#include <math.h>

// Problem constants (ShowAttendTellCore)
//   B=1024, D_MODEL=512, N_HEADS=8, D_HEAD=64, N_LEVELS=4, N_POINTS=4
//   T_TOTAL=1920, RNN=512, ENC=512, ATT_HID=512
// Output layout (f32): h2 (524288) | h1 | h2 | c1 | c2   (total 2621440)

typedef __attribute__((ext_vector_type(8))) short          s16x8;
typedef __attribute__((ext_vector_type(8))) unsigned short u16x8;
typedef __attribute__((ext_vector_type(4))) float          f32x4;

#define LOG2E  1.4426950408889634f
#define LOG2E2 2.8853900817779268f

__device__ __forceinline__ float rcpf(float x) { return __builtin_amdgcn_rcpf(x); }
__device__ __forceinline__ float exp2f_fast(float x) { return __builtin_amdgcn_exp2f(x); }
__device__ __forceinline__ float sigf(float x) {
    return rcpf(1.0f + exp2f_fast(-x * LOG2E));
}
__device__ __forceinline__ float tanhf_fast(float x) {
    const float xc = fminf(fmaxf(x, -15.0f), 15.0f);
    const float e2 = exp2f_fast(xc * LOG2E2);
    return 1.0f - 2.0f * rcpf(e2 + 1.0f);
}
__device__ __forceinline__ unsigned short f2bf(float f) {   // RNE f32->bf16
    unsigned u = __float_as_uint(f);
    u += 0x7FFF + ((u >> 16) & 1);
    return (unsigned short)(u >> 16);
}
__device__ __forceinline__ float bf2f(unsigned short h) {
    return __uint_as_float(((unsigned)h) << 16);
}
// async global->LDS, 16B per lane
__device__ __forceinline__ void gld_lds16(const unsigned short* g, unsigned short* l) {
    __builtin_amdgcn_global_load_lds(
        (const __attribute__((address_space(1))) void*)g,
        (__attribute__((address_space(3))) void*)l, 16, 0, 0);
}

// ---------------- batched f32 -> bf16 strided converts (one launch) --------
// ilv != 0: LSTM gate-interleave of dst rows: row' = (row%512)*4 + row/512.
struct CvtJob { const float* src; unsigned short* dst; int sld, dld, cols, total, ilv; };
struct CvtJobs { CvtJob j[11]; };
__global__ __launch_bounds__(256) void cvt_bf16(CvtJobs cj) {
    const CvtJob jb = cj.j[blockIdx.y];
    const int i = (blockIdx.x * 256 + threadIdx.x) * 4;
    if (i >= jb.total) return;
    const int r = i / jb.cols, c = i - r * jb.cols;
    const int rd = jb.ilv ? (((r & 511) << 2) | (r >> 9)) : r;
    const float4 v4 = *(const float4*)&jb.src[(size_t)r * jb.sld + c];
    ushort4 o;
    o.x = f2bf(v4.x); o.y = f2bf(v4.y); o.z = f2bf(v4.z); o.w = f2bf(v4.w);
    *(ushort4*)&jb.dst[(size_t)rd * jb.dld + c] = o;
}

// transpose-convert via 32x32 LDS tile; src==nullptr -> zeros.
struct TJob { const float* src; unsigned short* dst; int N_, dld, K_, total; };
struct TJobs { TJob j[6]; };
__global__ __launch_bounds__(256) void tcvt_bf16(TJobs tj) {
    const TJob jb = tj.j[blockIdx.y];
    const int tilesN = jb.N_ >> 5, tilesK = jb.K_ >> 5;
    const int tile = blockIdx.x;
    if (tile >= tilesN * tilesK) return;
    const int tn0 = (tile % tilesN) << 5, tk0 = (tile / tilesN) << 5;
    __shared__ float lds[32][33];
    const int t = threadIdx.x;
    if (jb.src) {
#pragma unroll
        for (int q = 0; q < 4; ++q) {
            const int e = t + (q << 8);
            lds[e >> 5][e & 31] = jb.src[(size_t)(tk0 + (e >> 5)) * jb.N_ + tn0 + (e & 31)];
        }
        __syncthreads();
#pragma unroll
        for (int q = 0; q < 4; ++q) {
            const int e = t + (q << 8);
            const int n = e >> 5, k = e & 31;
            jb.dst[(size_t)(tn0 + n) * jb.dld + tk0 + k] = f2bf(lds[k][n]);
        }
    } else {
#pragma unroll
        for (int q = 0; q < 4; ++q) {
            const int e = t + (q << 8);
            jb.dst[(size_t)(tn0 + (e >> 5)) * jb.dld + tk0 + (e & 31)] = 0;
        }
    }
}

// bcat = [boff(128) | battw(128) | bh2a(512)]
__global__ __launch_bounds__(768) void bias_cat3(const float* __restrict__ a,
                                                 const float* __restrict__ b,
                                                 const float* __restrict__ c,
                                                 float* __restrict__ dst) {
    const int t = threadIdx.x;
    dst[t] = (t < 128) ? a[t] : (t < 256 ? b[t - 128] : c[t - 256]);
}

// ===== 64x64-tile, BK=64, 4-buffer deep-pipelined staged GEMMs =============
// iter = {wait vmcnt(8); s_barrier; stage(t+3); compute t}. Wait/barrier
// BEFORE stage seals the WAR on buf (t+3)%4 == (t-1)%4. XOR swizzle rule #21.

#define STAGE_T(buf, k0) do { \
        gld_lds16(Ag1 + (k0), &As[buf][s1 * 8]); \
        gld_lds16(Ag2 + (k0), &As[buf][s2 * 8]); \
        gld_lds16(Bg1 + (k0), &Bs[buf][s1 * 8]); \
        gld_lds16(Bg2 + (k0), &Bs[buf][s2 * 8]); } while (0)

#define WAIT_INFL(t) do { \
        const int infl_ = nsteps - 1 - (t); \
        if (infl_ >= 2)      asm volatile("s_waitcnt vmcnt(8)" ::: "memory"); \
        else if (infl_ == 1) asm volatile("s_waitcnt vmcnt(4)" ::: "memory"); \
        else                 asm volatile("s_waitcnt vmcnt(0)" ::: "memory"); \
        __builtin_amdgcn_s_barrier(); } while (0)

// ---------------- 2-job staged GEMM (value + obat in ONE launch) -----------
// C = A @ B^T + bias. Per job: grid rows nbx wide; 1D grid spans both jobs.
struct GJob { const unsigned short* A; int lda; const unsigned short* B; int ldb;
              const float* bias; float* C; int ldc; int K; int nbx; int count; };
struct GJobs { GJob j[2]; };
__global__ __launch_bounds__(256) void sgemm2(GJobs gj) {
    __shared__ unsigned short As[4][64 * 64];
    __shared__ unsigned short Bs[4][64 * 64];

    int bid = blockIdx.x;
    GJob jb = gj.j[0];
    if (bid >= jb.count) { bid -= jb.count; jb = gj.j[1]; }
    const int bn = bid % jb.nbx, bm = bid / jb.nbx;
    const int lda = jb.lda, ldb = jb.ldb;

    const int tid = threadIdx.x;
    const int w = tid >> 6, lane = tid & 63;
    const int wr = w >> 1, wc = w & 1;
    const int lr = lane & 15, lg = lane >> 4;

    const int s1 = tid, s2 = tid + 256;
    const int r1 = s1 >> 3, c1 = ((s1 & 7) ^ (r1 & 7)) << 3;
    const int r2 = s2 >> 3, c2 = ((s2 & 7) ^ (r2 & 7)) << 3;
    const unsigned short* Ag1 = jb.A + (size_t)(bm * 64 + r1) * lda + c1;
    const unsigned short* Ag2 = jb.A + (size_t)(bm * 64 + r2) * lda + c2;
    const unsigned short* Bg1 = jb.B + (size_t)(bn * 64 + r1) * ldb + c1;
    const unsigned short* Bg2 = jb.B + (size_t)(bn * 64 + r2) * ldb + c2;

    f32x4 acc[2][2];
#pragma unroll
    for (int mt = 0; mt < 2; ++mt)
#pragma unroll
        for (int nt = 0; nt < 2; ++nt) acc[mt][nt] = (f32x4){0.f, 0.f, 0.f, 0.f};

    const int nsteps = jb.K >> 6;
    STAGE_T(0, 0);
    if (nsteps > 1) STAGE_T(1, 64);
    if (nsteps > 2) STAGE_T(2, 128);

    for (int t = 0; t < nsteps; ++t) {
        WAIT_INFL(t);
        if (t + 3 < nsteps) STAGE_T((t + 3) & 3, (t + 3) << 6);
        const unsigned short* Ab = &As[t & 3][0];
        const unsigned short* Bb = &Bs[t & 3][0];
        s16x8 a[2][2], bfr[2][2];
#pragma unroll
        for (int mt = 0; mt < 2; ++mt) {
            const int ar = wr * 32 + mt * 16 + lr;
#pragma unroll
            for (int ks = 0; ks < 2; ++ks)
                a[mt][ks] = *(const s16x8*)&Ab[(ar * 8 + ((ks * 4 + lg) ^ (ar & 7))) * 8];
        }
#pragma unroll
        for (int nt = 0; nt < 2; ++nt) {
            const int br = wc * 32 + nt * 16 + lr;
#pragma unroll
            for (int ks = 0; ks < 2; ++ks)
                bfr[nt][ks] = *(const s16x8*)&Bb[(br * 8 + ((ks * 4 + lg) ^ (br & 7))) * 8];
        }
#pragma unroll
        for (int ks = 0; ks < 2; ++ks)
#pragma unroll
            for (int mt = 0; mt < 2; ++mt)
#pragma unroll
                for (int nt = 0; nt < 2; ++nt)
                    acc[mt][nt] = __builtin_amdgcn_mfma_f32_16x16x32_bf16(
                        a[mt][ks], bfr[nt][ks], acc[mt][nt], 0, 0, 0);
    }
#pragma unroll
    for (int nt = 0; nt < 2; ++nt) {
        const int col = bn * 64 + wc * 32 + nt * 16 + lr;
        const float bb = jb.bias ? jb.bias[col] : 0.0f;
#pragma unroll
        for (int mt = 0; mt < 2; ++mt) {
            const int rbase = bm * 64 + wr * 32 + mt * 16 + lg * 4;
#pragma unroll
            for (int r = 0; r < 4; ++r)
                jb.C[(size_t)(rbase + r) * jb.ldc + col] = acc[mt][nt][r] + bb;
        }
    }
}

// ---------------- deep-pipelined GEMM + fused LSTM activation epilogue -----
// B rows gate-interleaved (col = 4*unit + gate, gate order i,f,g,o).
__global__ __launch_bounds__(256) void sgemm_lstm(
    const unsigned short* __restrict__ A, int lda,
    const unsigned short* __restrict__ B, int ldb,
    const float* __restrict__ c_in,
    float* __restrict__ h_a, float* __restrict__ h_b,
    unsigned short* __restrict__ hbf, int hbf_ld,
    float* __restrict__ c_out, int K)
{
    __shared__ unsigned short As[4][64 * 64];
    __shared__ unsigned short Bs[4][64 * 64];

    const int tid = threadIdx.x;
    const int w = tid >> 6, lane = tid & 63;
    const int wr = w >> 1, wc = w & 1;
    const int lr = lane & 15, lg = lane >> 4;
    const int bm = blockIdx.y, bn = blockIdx.x;

    const int s1 = tid, s2 = tid + 256;
    const int r1 = s1 >> 3, c1 = ((s1 & 7) ^ (r1 & 7)) << 3;
    const int r2 = s2 >> 3, c2 = ((s2 & 7) ^ (r2 & 7)) << 3;
    const unsigned short* Ag1 = A + (size_t)(bm * 64 + r1) * lda + c1;
    const unsigned short* Ag2 = A + (size_t)(bm * 64 + r2) * lda + c2;
    const unsigned short* Bg1 = B + (size_t)(bn * 64 + r1) * ldb + c1;
    const unsigned short* Bg2 = B + (size_t)(bn * 64 + r2) * ldb + c2;

    f32x4 acc[2][2];
#pragma unroll
    for (int mt = 0; mt < 2; ++mt)
#pragma unroll
        for (int nt = 0; nt < 2; ++nt) acc[mt][nt] = (f32x4){0.f, 0.f, 0.f, 0.f};

    const int nsteps = K >> 6;
    STAGE_T(0, 0);
    if (nsteps > 1) STAGE_T(1, 64);
    if (nsteps > 2) STAGE_T(2, 128);

    for (int t = 0; t < nsteps; ++t) {
        WAIT_INFL(t);
        if (t + 3 < nsteps) STAGE_T((t + 3) & 3, (t + 3) << 6);
        const unsigned short* Ab = &As[t & 3][0];
        const unsigned short* Bb = &Bs[t & 3][0];
        s16x8 a[2][2], bfr[2][2];
#pragma unroll
        for (int mt = 0; mt < 2; ++mt) {
            const int ar = wr * 32 + mt * 16 + lr;
#pragma unroll
            for (int ks = 0; ks < 2; ++ks)
                a[mt][ks] = *(const s16x8*)&Ab[(ar * 8 + ((ks * 4 + lg) ^ (ar & 7))) * 8];
        }
#pragma unroll
        for (int nt = 0; nt < 2; ++nt) {
            const int br = wc * 32 + nt * 16 + lr;
#pragma unroll
            for (int ks = 0; ks < 2; ++ks)
                bfr[nt][ks] = *(const s16x8*)&Bb[(br * 8 + ((ks * 4 + lg) ^ (br & 7))) * 8];
        }
#pragma unroll
        for (int ks = 0; ks < 2; ++ks)
#pragma unroll
            for (int mt = 0; mt < 2; ++mt)
#pragma unroll
                for (int nt = 0; nt < 2; ++nt)
                    acc[mt][nt] = __builtin_amdgcn_mfma_f32_16x16x32_bf16(
                        a[mt][ks], bfr[nt][ks], acc[mt][nt], 0, 0, 0);
    }
    // epilogue: col = bn*64 + wc*32 + nt*16 + lr; gate = col&3 = lane&3
    const int gte  = lane & 3;
    const int base = lane & ~3;
#pragma unroll
    for (int nt = 0; nt < 2; ++nt) {
        const int col = bn * 64 + wc * 32 + nt * 16 + lr;
        const int u = col >> 2;     // unit index in [0,512)
#pragma unroll
        for (int mt = 0; mt < 2; ++mt) {
            const int rbase = bm * 64 + wr * 32 + mt * 16 + lg * 4;
#pragma unroll
            for (int r = 0; r < 4; ++r) {
                const float vv = acc[mt][nt][r];
                const float a  = (gte == 2) ? tanhf_fast(vv) : sigf(vv);
                const float ai = __shfl(a, base + 0);
                const float af = __shfl(a, base + 1);
                const float ag = __shfl(a, base + 2);
                const float ao = __shfl(a, base + 3);
                const int row = rbase + r;
                const float c  = c_in[(size_t)row * 512 + u];
                const float c2 = af * c + ai * ag;
                const float h2 = ao * tanhf_fast(c2);
                if (gte == 0)      c_out[(size_t)row * 512 + u] = c2;
                else if (gte == 1) h_a[(size_t)row * 512 + u] = h2;
                else if (gte == 2) { if (h_b) h_b[(size_t)row * 512 + u] = h2; }
                else if (hbf)      hbf[(size_t)row * hbf_ld + u] = f2bf(h2);
            }
        }
    }
}
#undef STAGE_T
#undef WAIT_INFL

// ---------------- fused deformable sampling + context attention ------------
// HEAD-SPLIT (R15): block = (batch row, head-half). 2048 blocks x 256 thr,
// 4 heads (64 points) per block, LDS ~14KB, ~64 VGPR -> up to 8 blocks/CU
// (4x the TLP of the old 512-thread version; its VALU floor was 2x exposed).
// obat (B,768) = [off(128) | aw_raw(128) | atth(512)]  (biases included)
__global__ __launch_bounds__(256, 4) void fused_att(
    const float* __restrict__ v,       // (1920, 512)
    const float* __restrict__ obat,    // (B, 768)
    const float* __restrict__ refp,    // (B, 4)
    const int*   __restrict__ shapes,  // (4,)
    const int*   __restrict__ starts,  // (4,)
    const unsigned short* __restrict__ Wb,  // (512, 64) bf16, = Wctx^T
    const float* __restrict__ bctx,    // (512,)
    const float* __restrict__ walpha,  // (512,)
    unsigned short* __restrict__ attdst)    // bf16, row stride 2048
{
    __shared__ unsigned short cf[64 * 64];    // 8 KB, XOR chunk-swizzled
    __shared__ float ba[512];                 // bctx + atth[b]
    __shared__ float wal[512];
    __shared__ float awb[64];
    __shared__ float dsum[64];
    __shared__ float dots4[4][64];

    const int b   = blockIdx.x >> 1;
    const int hh  = blockIdx.x & 1;           // head-half: heads hh*4 .. hh*4+3
    const int tid = threadIdx.x;

    // phase 0: attention-weight softmax (16 per head, 4 heads)
    if (tid < 64) awb[tid] = obat[b * 768 + 128 + hh * 64 + tid];
    __syncthreads();
    if (tid < 4) {
        float mx = -1e30f;
        for (int i = 0; i < 16; ++i) mx = fmaxf(mx, awb[tid * 16 + i]);
        float sum = 0.f;
        for (int i = 0; i < 16; ++i) { float e = exp2f_fast((awb[tid * 16 + i] - mx) * LOG2E); awb[tid * 16 + i] = e; sum += e; }
        float inv = rcpf(sum);
        for (int i = 0; i < 16; ++i) awb[tid * 16 + i] *= inv;
    }
    __syncthreads();

    // phase 1: bilinear sampling -> cf[p][d] = bf16(samp[d] * aw[p]); stage ba/wal
    ba[tid]        = bctx[tid]       + obat[b * 768 + 256 + tid];
    ba[tid + 256]  = bctx[tid + 256] + obat[b * 768 + 512 + tid];
    wal[tid]       = walpha[tid];
    wal[tid + 256] = walpha[tid + 256];
    {
        const int pl  = tid >> 2;         // local point 0..63
        const int sub = tid & 3;
        const int d0  = sub * 16;
        const int pg  = hh * 64 + pl;     // global point
        const int h   = pg >> 4;
        const int l   = (pg & 15) >> 2;
        const int Tlen = shapes[l];
        const int st   = starts[l];
        const float T  = (float)Tlen;
        const float refv = refp[b * 4 + l];
        const float offv = obat[b * 768 + pg];
        const float awv  = awb[pl];
        const float x   = (refv + offv * rcpf(T)) * T - 0.5f;  // exact: T is 2^k
        const float x0f = floorf(x);
        const float w1  = x - x0f;
        const int   x0  = (int)x0f;
        const float w0s = (x0 >= 0 && x0 < Tlen) ? (1.0f - w1) : 0.0f;
        const float w1s = (x0 + 1 >= 0 && x0 + 1 < Tlen) ? w1 : 0.0f;
        const int i0 = (min(max(x0, 0), Tlen - 1) + st) * 512 + h * 64;
        const int i1 = (min(max(x0 + 1, 0), Tlen - 1) + st) * 512 + h * 64;
        u16x8 o0, o1;
#pragma unroll
        for (int q = 0; q < 4; ++q) {
            const float4 a  = *(const float4*)&v[i0 + d0 + q * 4];
            const float4 bq = *(const float4*)&v[i1 + d0 + q * 4];
            unsigned short e0 = f2bf((a.x * w0s + bq.x * w1s) * awv);
            unsigned short e1 = f2bf((a.y * w0s + bq.y * w1s) * awv);
            unsigned short e2 = f2bf((a.z * w0s + bq.z * w1s) * awv);
            unsigned short e3 = f2bf((a.w * w0s + bq.w * w1s) * awv);
            if (q == 0) { o0[0] = e0; o0[1] = e1; o0[2] = e2; o0[3] = e3; }
            if (q == 1) { o0[4] = e0; o0[5] = e1; o0[6] = e2; o0[7] = e3; }
            if (q == 2) { o1[0] = e0; o1[1] = e1; o1[2] = e2; o1[3] = e3; }
            if (q == 3) { o1[4] = e0; o1[5] = e1; o1[6] = e2; o1[7] = e3; }
        }
        const int c0 = (sub * 2)     ^ (pl & 7);
        const int c1 = (sub * 2 + 1) ^ (pl & 7);
        *(u16x8*)&cf[pl * 64 + c0 * 8] = o0;
        *(u16x8*)&cf[pl * 64 + c1 * 8] = o1;
    }
    __syncthreads();

    // phase 2: dots[p] = sum_j tanh((cf@Wctx)[p][j] + ba[j]) * wal[j]  via MFMA
    // 4 waves; wave wn covers cols wn*128..wn*128+127; 4 M-tiles (64 rows).
    {
        const int wn   = tid >> 6, lane = tid & 63;
        const int lr   = lane & 15, lg = lane >> 4;

        s16x8 afrag[4][2];
#pragma unroll
        for (int mt = 0; mt < 4; ++mt) {
            const int row = mt * 16 + lr;
#pragma unroll
            for (int ks = 0; ks < 2; ++ks) {
                const int ch = (ks * 4 + lg) ^ (row & 7);
                afrag[mt][ks] = *(const s16x8*)&cf[row * 64 + ch * 8];
            }
        }
        f32x4 part[4];
#pragma unroll
        for (int mt = 0; mt < 4; ++mt) part[mt] = (f32x4){0.f, 0.f, 0.f, 0.f};

#pragma clang loop unroll(disable)
        for (int nt = 0; nt < 8; ++nt) {
            const int col = (wn * 8 + nt) * 16 + lr;
            const s16x8 b0 = *(const s16x8*)&Wb[col * 64 + lg * 8];
            const s16x8 b1 = *(const s16x8*)&Wb[col * 64 + 32 + lg * 8];
            const float bav = ba[col], wav = wal[col];
#pragma unroll
            for (int mt = 0; mt < 4; ++mt) {
                f32x4 acc = {0.f, 0.f, 0.f, 0.f};
                acc = __builtin_amdgcn_mfma_f32_16x16x32_bf16(afrag[mt][0], b0, acc, 0, 0, 0);
                acc = __builtin_amdgcn_mfma_f32_16x16x32_bf16(afrag[mt][1], b1, acc, 0, 0, 0);
#pragma unroll
                for (int r = 0; r < 4; ++r)
                    part[mt][r] += tanhf_fast(acc[r] + bav) * wav;
            }
        }
#pragma unroll
        for (int mt = 0; mt < 4; ++mt) {
#pragma unroll
            for (int r = 0; r < 4; ++r) {
                float s = part[mt][r];
                s += __shfl_xor(s, 1); s += __shfl_xor(s, 2);
                s += __shfl_xor(s, 4); s += __shfl_xor(s, 8);
                if (lr == 0) dots4[wn][mt * 16 + lg * 4 + r] = s;
            }
        }
    }
    __syncthreads();
    if (tid < 64)
        dsum[tid] = dots4[0][tid] + dots4[1][tid] + dots4[2][tid] + dots4[3][tid];
    __syncthreads();

    // phase 3: softmax over the 16 points of each of the 4 heads
    if (tid < 4) {
        float mx = -1e30f;
        for (int i = 0; i < 16; ++i) mx = fmaxf(mx, dsum[tid * 16 + i]);
        float sum = 0.f;
        for (int i = 0; i < 16; ++i) { float e = exp2f_fast((dsum[tid * 16 + i] - mx) * LOG2E); dsum[tid * 16 + i] = e; sum += e; }
        float inv = rcpf(sum);
        for (int i = 0; i < 16; ++i) dsum[tid * 16 + i] *= inv;
    }
    __syncthreads();

    // phase 4: att_res (bf16 into Acat): 4 heads x 64 d = 256 threads
    {
        const int hl = tid >> 6, d = tid & 63;
        const int ch = d >> 3, e = d & 7;
        float s = 0.f;
#pragma unroll
        for (int p = 0; p < 16; ++p) {
            const int row = hl * 16 + p;
            s += dsum[hl * 16 + p] * bf2f(cf[row * 64 + ((ch ^ (row & 7)) * 8) + e]);
        }
        attdst[(size_t)b * 2048 + hh * 256 + tid] = f2bf(s);
    }
}

extern "C" void kernel_launch(void* const* d_in, const int* in_sizes, int n_in,
                              void* d_out, int out_size, void* d_ws, size_t ws_size,
                              hipStream_t stream) {
    const float* xt     = (const float*)d_in[0];
    const float* h0     = (const float*)d_in[1];   // (2,1024,512)
    const float* c0     = (const float*)d_in[2];
    const float* query  = (const float*)d_in[3];   // (1,1024,512)
    const float* refp   = (const float*)d_in[4];   // (1,1024,4,1)
    const float* inflat = (const float*)d_in[5];   // (1,1920,512)
    const int*   shapes = (const int*)d_in[6];
    const int*   starts = (const int*)d_in[7];
    const float* Wv     = (const float*)d_in[9];   // (512,512) (K,N)
    const float* bv     = (const float*)d_in[10];
    const float* Woff   = (const float*)d_in[11];  // (1024,128) (K,N)
    const float* boff   = (const float*)d_in[12];
    const float* Wattw  = (const float*)d_in[13];  // (1024,128)
    const float* battw  = (const float*)d_in[14];
    const float* Wctx   = (const float*)d_in[15];  // (64,512)
    const float* bctx   = (const float*)d_in[16];
    const float* Wh2a   = (const float*)d_in[17];  // (512,512) (K,N)
    const float* bh2a   = (const float*)d_in[18];
    const float* walpha = (const float*)d_in[19];
    const float* Wih0   = (const float*)d_in[21];  // (2048,1536) (N,K)
    const float* Whh0   = (const float*)d_in[22];  // (2048,512)
    const float* Wih1   = (const float*)d_in[23];  // (2048,512)
    const float* Whh1   = (const float*)d_in[24];  // (2048,512)

    float* out = (float*)d_out;
    float* ws  = (float*)d_ws;

    // ws layout (f32 units), lifetime-overlapped
    float*          v     = ws;                                   // 983040
    float*          obat  = ws + 983040;                          // 1024x768 [off|aw|atth]
    unsigned short* Acat  = (unsigned short*)(ws + 1769472);      // 1024x2048 bf16
    unsigned short* Bcat0 = (unsigned short*)(ws + 2818048);      // 2048x2048 bf16 (gate-ilv)
    unsigned short* Ainf  = (unsigned short*)(ws + 4915200);      // 1920x512 bf16
    unsigned short* Wvt   = (unsigned short*)(ws + 5406720);      // 512x512 bf16
    unsigned short* Wcat  = (unsigned short*)(ws + 5537792);      // 768x1024 bf16
    unsigned short* Ahq   = (unsigned short*)(ws + 5931008);      // 1024x1024 bf16
    unsigned short* Wb    = (unsigned short*)(ws + 6455296);      // 512x64 bf16 (Wctx^T)
    float*          bcat  = ws + 6471680;                         // 768
    unsigned short* Ag1   = (unsigned short*)(ws + 7012352);      // 1024x1024 bf16
    unsigned short* Bcat1 = (unsigned short*)(ws + 7536640);      // 2048x1024 bf16 (gate-ilv)

    const float* h00    = h0;
    const float* h_last = h0 + 524288;     // h0[1]
    float* h1  = out + 524288;             // h_new[0]
    float* c1  = out + 1572864;            // c_new[0]
    float* h2a = out;                      // first output
    float* h2b = out + 1048576;            // h_new[1]
    float* c2  = out + 2097152;            // c_new[1]

    // --- prep: converts (1 launch), tiled transposes + zero-pad (1 launch), biases ---
    { CvtJobs cj;
      cj.j[0]  = { xt,     Acat,          512,  2048, 512,  524288,  0 };
      cj.j[1]  = { query,  Acat + 1024,   512,  2048, 512,  524288,  0 };
      cj.j[2]  = { h00,    Acat + 1536,   512,  2048, 512,  524288,  0 };
      cj.j[3]  = { h_last, Ahq,           512,  1024, 512,  524288,  0 };
      cj.j[4]  = { query,  Ahq + 512,     512,  1024, 512,  524288,  0 };
      cj.j[5]  = { h_last, Ag1 + 512,     512,  1024, 512,  524288,  0 };
      cj.j[6]  = { Wih0,   Bcat0,         1536, 2048, 1536, 3145728, 1 };
      cj.j[7]  = { Whh0,   Bcat0 + 1536,  512,  2048, 512,  1048576, 1 };
      cj.j[8]  = { Wih1,   Bcat1,         512,  1024, 512,  1048576, 1 };
      cj.j[9]  = { Whh1,   Bcat1 + 512,   512,  1024, 512,  1048576, 1 };
      cj.j[10] = { inflat, Ainf,          512,  512,  512,  983040,  0 };
      cvt_bf16<<<dim3(3072, 11), 256, 0, stream>>>(cj); }
    { TJobs tj;
      tj.j[0] = { Wv,      Wvt,                     512, 512,  512, 0 };
      tj.j[1] = { Woff,    Wcat,                    128, 1024, 1024, 0 };
      tj.j[2] = { Wattw,   Wcat + 128 * 1024,       128, 1024, 1024, 0 };
      tj.j[3] = { Wh2a,    Wcat + 256 * 1024,       512, 1024, 512, 0 };
      tj.j[4] = { Wctx,    Wb,                      512, 64,   64,  0 };
      tj.j[5] = { nullptr, Wcat + 256 * 1024 + 512, 512, 1024, 512, 0 }; // zero K-pad
      tcvt_bf16<<<dim3(256, 6), 256, 0, stream>>>(tj); }
    bias_cat3<<<1, 768, 0, stream>>>(boff, battw, bh2a, bcat);

    // --- value + obat GEMMs fused into ONE launch (432 blocks) ---
    { GJobs gj;
      gj.j[0] = { Ainf, 512,  Wvt,  512,  bv,   v,    512, 512,  8,  240 };  // 1920x512
      gj.j[1] = { Ahq,  1024, Wcat, 1024, bcat, obat, 768, 1024, 12, 192 };  // 1024x768
      sgemm2<<<432, 256, 0, stream>>>(gj); }

    // --- fused deformable sampling + context attention (writes Acat[:,512:1024]) ---
    fused_att<<<2048, 256, 0, stream>>>(v, obat, refp, shapes, starts,
                                        Wb, bctx, walpha, Acat + 512);

    // LSTM0: gates+activation fused; writes h1, c1, Ag1[:, :512] (bf16)
    sgemm_lstm<<<dim3(32, 16), 256, 0, stream>>>(Acat, 2048, Bcat0, 2048,
                                                 c0, h1, nullptr, Ag1, 1024, c1, 2048);
    // LSTM1: writes h2 (outputs 0 and h_new[1]), c2
    sgemm_lstm<<<dim3(32, 16), 256, 0, stream>>>(Ag1, 1024, Bcat1, 1024,
                                                 c0 + 524288, h1 - 524288, h2b, nullptr, 0, c2, 1024);
}

// Round 16
// 109.502 us; speedup vs baseline: 1.4432x; 1.0387x over previous
//
#include <hip/hip_runtime.h>
#include <math.h>

// Problem constants (ShowAttendTellCore)
//   B=1024, D_MODEL=512, N_HEADS=8, D_HEAD=64, N_LEVELS=4, N_POINTS=4
//   T_TOTAL=1920, RNN=512, ENC=512, ATT_HID=512
// Output layout (f32): h2 (524288) | h1 | h2 | c1 | c2   (total 2621440)

typedef __attribute__((ext_vector_type(8))) short          s16x8;
typedef __attribute__((ext_vector_type(8))) unsigned short u16x8;
typedef __attribute__((ext_vector_type(4))) float          f32x4;

#define LOG2E  1.4426950408889634f
#define LOG2E2 2.8853900817779268f

__device__ __forceinline__ float rcpf(float x) { return __builtin_amdgcn_rcpf(x); }
__device__ __forceinline__ float exp2f_fast(float x) { return __builtin_amdgcn_exp2f(x); }
__device__ __forceinline__ float sigf(float x) {
    return rcpf(1.0f + exp2f_fast(-x * LOG2E));
}
__device__ __forceinline__ float tanhf_fast(float x) {
    const float xc = fminf(fmaxf(x, -15.0f), 15.0f);
    const float e2 = exp2f_fast(xc * LOG2E2);
    return 1.0f - 2.0f * rcpf(e2 + 1.0f);
}
__device__ __forceinline__ unsigned short f2bf(float f) {   // RNE f32->bf16
    unsigned u = __float_as_uint(f);
    u += 0x7FFF + ((u >> 16) & 1);
    return (unsigned short)(u >> 16);
}
__device__ __forceinline__ float bf2f(unsigned short h) {
    return __uint_as_float(((unsigned)h) << 16);
}
// async global->LDS, 16B per lane
__device__ __forceinline__ void gld_lds16(const unsigned short* g, unsigned short* l) {
    __builtin_amdgcn_global_load_lds(
        (const __attribute__((address_space(1))) void*)g,
        (__attribute__((address_space(3))) void*)l, 16, 0, 0);
}

// ---------------- batched f32 -> bf16 strided converts (one launch) --------
// ilv != 0: LSTM gate-interleave of dst rows: row' = (row%512)*4 + row/512.
struct CvtJob { const float* src; unsigned short* dst; int sld, dld, cols, total, ilv; };
struct CvtJobs { CvtJob j[11]; };
__global__ __launch_bounds__(256) void cvt_bf16(CvtJobs cj) {
    const CvtJob jb = cj.j[blockIdx.y];
    const int i = (blockIdx.x * 256 + threadIdx.x) * 4;
    if (i >= jb.total) return;
    const int r = i / jb.cols, c = i - r * jb.cols;
    const int rd = jb.ilv ? (((r & 511) << 2) | (r >> 9)) : r;
    const float4 v4 = *(const float4*)&jb.src[(size_t)r * jb.sld + c];
    ushort4 o;
    o.x = f2bf(v4.x); o.y = f2bf(v4.y); o.z = f2bf(v4.z); o.w = f2bf(v4.w);
    *(ushort4*)&jb.dst[(size_t)rd * jb.dld + c] = o;
}

// transpose-convert via 32x32 LDS tile; src==nullptr -> zeros.
struct TJob { const float* src; unsigned short* dst; int N_, dld, K_, total; };
struct TJobs { TJob j[6]; };
__global__ __launch_bounds__(256) void tcvt_bf16(TJobs tj) {
    const TJob jb = tj.j[blockIdx.y];
    const int tilesN = jb.N_ >> 5, tilesK = jb.K_ >> 5;
    const int tile = blockIdx.x;
    if (tile >= tilesN * tilesK) return;
    const int tn0 = (tile % tilesN) << 5, tk0 = (tile / tilesN) << 5;
    __shared__ float lds[32][33];
    const int t = threadIdx.x;
    if (jb.src) {
#pragma unroll
        for (int q = 0; q < 4; ++q) {
            const int e = t + (q << 8);
            lds[e >> 5][e & 31] = jb.src[(size_t)(tk0 + (e >> 5)) * jb.N_ + tn0 + (e & 31)];
        }
        __syncthreads();
#pragma unroll
        for (int q = 0; q < 4; ++q) {
            const int e = t + (q << 8);
            const int n = e >> 5, k = e & 31;
            jb.dst[(size_t)(tn0 + n) * jb.dld + tk0 + k] = f2bf(lds[k][n]);
        }
    } else {
#pragma unroll
        for (int q = 0; q < 4; ++q) {
            const int e = t + (q << 8);
            jb.dst[(size_t)(tn0 + (e >> 5)) * jb.dld + tk0 + (e & 31)] = 0;
        }
    }
}

// ===== 64x64-tile, BK=64 staged GEMMs; XOR swizzle rule #21 ================

#define STAGE_T(buf, k0) do { \
        gld_lds16(Ag1 + (k0), &As[buf][s1 * 8]); \
        gld_lds16(Ag2 + (k0), &As[buf][s2 * 8]); \
        gld_lds16(Bg1 + (k0), &Bs[buf][s1 * 8]); \
        gld_lds16(Bg2 + (k0), &Bs[buf][s2 * 8]); } while (0)

// ---------------- 2-job staged GEMM (value + obat in ONE launch) -----------
// C = A @ B^T + bias(3-piece select: col<l0 -> b0[col]; <l1 -> b1[col-l0];
// else b2[col-l1]).  4-buffer deep pipeline, counted vmcnt.
struct GJob { const unsigned short* A; int lda; const unsigned short* B; int ldb;
              const float* b0; const float* b1; const float* b2; int l0, l1;
              float* C; int ldc; int K; int nbx; int count; };
struct GJobs { GJob j[2]; };
__global__ __launch_bounds__(256) void sgemm2(GJobs gj) {
    __shared__ unsigned short As[4][64 * 64];
    __shared__ unsigned short Bs[4][64 * 64];

    int bid = blockIdx.x;
    GJob jb = gj.j[0];
    if (bid >= jb.count) { bid -= jb.count; jb = gj.j[1]; }
    const int bn = bid % jb.nbx, bm = bid / jb.nbx;
    const int lda = jb.lda, ldb = jb.ldb;

    const int tid = threadIdx.x;
    const int w = tid >> 6, lane = tid & 63;
    const int wr = w >> 1, wc = w & 1;
    const int lr = lane & 15, lg = lane >> 4;

    const int s1 = tid, s2 = tid + 256;
    const int r1 = s1 >> 3, c1 = ((s1 & 7) ^ (r1 & 7)) << 3;
    const int r2 = s2 >> 3, c2 = ((s2 & 7) ^ (r2 & 7)) << 3;
    const unsigned short* Ag1 = jb.A + (size_t)(bm * 64 + r1) * lda + c1;
    const unsigned short* Ag2 = jb.A + (size_t)(bm * 64 + r2) * lda + c2;
    const unsigned short* Bg1 = jb.B + (size_t)(bn * 64 + r1) * ldb + c1;
    const unsigned short* Bg2 = jb.B + (size_t)(bn * 64 + r2) * ldb + c2;

    f32x4 acc[2][2];
#pragma unroll
    for (int mt = 0; mt < 2; ++mt)
#pragma unroll
        for (int nt = 0; nt < 2; ++nt) acc[mt][nt] = (f32x4){0.f, 0.f, 0.f, 0.f};

    const int nsteps = jb.K >> 6;
    STAGE_T(0, 0);
    if (nsteps > 1) STAGE_T(1, 64);
    if (nsteps > 2) STAGE_T(2, 128);

    for (int t = 0; t < nsteps; ++t) {
        const int infl = nsteps - 1 - t;
        if (infl >= 2)      asm volatile("s_waitcnt vmcnt(8)" ::: "memory");
        else if (infl == 1) asm volatile("s_waitcnt vmcnt(4)" ::: "memory");
        else                asm volatile("s_waitcnt vmcnt(0)" ::: "memory");
        __builtin_amdgcn_s_barrier();
        if (t + 3 < nsteps) STAGE_T((t + 3) & 3, (t + 3) << 6);
        const unsigned short* Ab = &As[t & 3][0];
        const unsigned short* Bb = &Bs[t & 3][0];
        s16x8 a[2][2], bfr[2][2];
#pragma unroll
        for (int mt = 0; mt < 2; ++mt) {
            const int ar = wr * 32 + mt * 16 + lr;
#pragma unroll
            for (int ks = 0; ks < 2; ++ks)
                a[mt][ks] = *(const s16x8*)&Ab[(ar * 8 + ((ks * 4 + lg) ^ (ar & 7))) * 8];
        }
#pragma unroll
        for (int nt = 0; nt < 2; ++nt) {
            const int br = wc * 32 + nt * 16 + lr;
#pragma unroll
            for (int ks = 0; ks < 2; ++ks)
                bfr[nt][ks] = *(const s16x8*)&Bb[(br * 8 + ((ks * 4 + lg) ^ (br & 7))) * 8];
        }
#pragma unroll
        for (int ks = 0; ks < 2; ++ks)
#pragma unroll
            for (int mt = 0; mt < 2; ++mt)
#pragma unroll
                for (int nt = 0; nt < 2; ++nt)
                    acc[mt][nt] = __builtin_amdgcn_mfma_f32_16x16x32_bf16(
                        a[mt][ks], bfr[nt][ks], acc[mt][nt], 0, 0, 0);
    }
#pragma unroll
    for (int nt = 0; nt < 2; ++nt) {
        const int col = bn * 64 + wc * 32 + nt * 16 + lr;
        float bb;
        if (col < jb.l0)      bb = jb.b0[col];
        else if (col < jb.l1) bb = jb.b1[col - jb.l0];
        else                  bb = jb.b2[col - jb.l1];
#pragma unroll
        for (int mt = 0; mt < 2; ++mt) {
            const int rbase = bm * 64 + wr * 32 + mt * 16 + lg * 4;
#pragma unroll
            for (int r = 0; r < 4; ++r)
                jb.C[(size_t)(rbase + r) * jb.ldc + col] = acc[mt][nt][r] + bb;
        }
    }
}

// ---------------- split-K2 partial GEMM for LSTM gates ---------------------
// N=2048 fixed (nbx=32), M=1024 (16 block rows), 512 blocks/slice x 2 slices.
// Slice s covers K cols [s*Kslice, (s+1)*Kslice); partial C -> gp[s] (bf16,
// ldc 2048). 3-buffer pipeline, counted vmcnt(4). B gate-interleaved.
__global__ __launch_bounds__(256) void sgemm_ks(
    const unsigned short* __restrict__ A, int lda,
    const unsigned short* __restrict__ B, int ldb,
    unsigned short* __restrict__ gp0, unsigned short* __restrict__ gp1,
    int Kslice)
{
    __shared__ unsigned short As[3][64 * 64];   // 8KB x3
    __shared__ unsigned short Bs[3][64 * 64];   // 8KB x3  (48KB total)

    const int slice = blockIdx.x >> 9;
    const int rblk  = blockIdx.x & 511;
    const int bn = rblk & 31, bm = rblk >> 5;
    const int koff = slice * Kslice;
    unsigned short* Cp = slice ? gp1 : gp0;

    const int tid = threadIdx.x;
    const int w = tid >> 6, lane = tid & 63;
    const int wr = w >> 1, wc = w & 1;
    const int lr = lane & 15, lg = lane >> 4;

    const int s1 = tid, s2 = tid + 256;
    const int r1 = s1 >> 3, c1 = ((s1 & 7) ^ (r1 & 7)) << 3;
    const int r2 = s2 >> 3, c2 = ((s2 & 7) ^ (r2 & 7)) << 3;
    const unsigned short* Ag1 = A + (size_t)(bm * 64 + r1) * lda + koff + c1;
    const unsigned short* Ag2 = A + (size_t)(bm * 64 + r2) * lda + koff + c2;
    const unsigned short* Bg1 = B + (size_t)(bn * 64 + r1) * ldb + koff + c1;
    const unsigned short* Bg2 = B + (size_t)(bn * 64 + r2) * ldb + koff + c2;

    f32x4 acc[2][2];
#pragma unroll
    for (int mt = 0; mt < 2; ++mt)
#pragma unroll
        for (int nt = 0; nt < 2; ++nt) acc[mt][nt] = (f32x4){0.f, 0.f, 0.f, 0.f};

    const int nsteps = Kslice >> 6;
    STAGE_T(0, 0);
    if (nsteps > 1) STAGE_T(1, 64);

    for (int t = 0; t < nsteps; ++t) {
        const int infl = nsteps - 1 - t;
        if (infl >= 1) asm volatile("s_waitcnt vmcnt(4)" ::: "memory");
        else           asm volatile("s_waitcnt vmcnt(0)" ::: "memory");
        __builtin_amdgcn_s_barrier();
        if (t + 2 < nsteps) {
            const int bw = (t + 2) % 3;
            STAGE_T(bw, (t + 2) << 6);
        }
        const unsigned short* Ab = &As[t % 3][0];
        const unsigned short* Bb = &Bs[t % 3][0];
        s16x8 a[2][2], bfr[2][2];
#pragma unroll
        for (int mt = 0; mt < 2; ++mt) {
            const int ar = wr * 32 + mt * 16 + lr;
#pragma unroll
            for (int ks = 0; ks < 2; ++ks)
                a[mt][ks] = *(const s16x8*)&Ab[(ar * 8 + ((ks * 4 + lg) ^ (ar & 7))) * 8];
        }
#pragma unroll
        for (int nt = 0; nt < 2; ++nt) {
            const int br = wc * 32 + nt * 16 + lr;
#pragma unroll
            for (int ks = 0; ks < 2; ++ks)
                bfr[nt][ks] = *(const s16x8*)&Bb[(br * 8 + ((ks * 4 + lg) ^ (br & 7))) * 8];
        }
#pragma unroll
        for (int ks = 0; ks < 2; ++ks)
#pragma unroll
            for (int mt = 0; mt < 2; ++mt)
#pragma unroll
                for (int nt = 0; nt < 2; ++nt)
                    acc[mt][nt] = __builtin_amdgcn_mfma_f32_16x16x32_bf16(
                        a[mt][ks], bfr[nt][ks], acc[mt][nt], 0, 0, 0);
    }
#pragma unroll
    for (int nt = 0; nt < 2; ++nt) {
        const int col = bn * 64 + wc * 32 + nt * 16 + lr;
#pragma unroll
        for (int mt = 0; mt < 2; ++mt) {
            const int rbase = bm * 64 + wr * 32 + mt * 16 + lg * 4;
#pragma unroll
            for (int r = 0; r < 4; ++r)
                Cp[(size_t)(rbase + r) * 2048 + col] = f2bf(acc[mt][nt][r]);
        }
    }
}
#undef STAGE_T

// ---------------- split-K reduce + LSTM activation -------------------------
// Gate-interleaved cols (col = 4*unit + gate): one ushort4 per (row,unit)
// per partial holds all 4 gates. 2048 blocks x 256 threads = 524288 units.
__global__ __launch_bounds__(256) void red_lstm(
    const unsigned short* __restrict__ g0, const unsigned short* __restrict__ g1,
    const float* __restrict__ c_in,
    float* __restrict__ h_a, float* __restrict__ h_b,
    unsigned short* __restrict__ hbf, int hbf_ld,
    float* __restrict__ c_out)
{
    const int id = blockIdx.x * 256 + threadIdx.x;   // row*512 + u
    const int row = id >> 9, u = id & 511;
    const size_t off = (size_t)row * 2048 + u * 4;
    const ushort4 p0 = *(const ushort4*)&g0[off];
    const ushort4 p1 = *(const ushort4*)&g1[off];
    const float gi = bf2f(p0.x) + bf2f(p1.x);
    const float gf = bf2f(p0.y) + bf2f(p1.y);
    const float gg = bf2f(p0.z) + bf2f(p1.z);
    const float go = bf2f(p0.w) + bf2f(p1.w);
    const float c  = c_in[id];
    const float c2 = sigf(gf) * c + sigf(gi) * tanhf_fast(gg);
    const float h2 = sigf(go) * tanhf_fast(c2);
    h_a[id] = h2;
    if (h_b) h_b[id] = h2;
    if (hbf) hbf[(size_t)row * hbf_ld + u] = f2bf(h2);
    c_out[id] = c2;
}

// ---------------- fused deformable sampling + context attention ------------
// Head-split: 2048 blocks x 256 thr, 4 heads/block (R15-proven).
__global__ __launch_bounds__(256, 4) void fused_att(
    const float* __restrict__ v,       // (1920, 512)
    const float* __restrict__ obat,    // (B, 768) [off|aw|atth]
    const float* __restrict__ refp,    // (B, 4)
    const int*   __restrict__ shapes,  // (4,)
    const int*   __restrict__ starts,  // (4,)
    const unsigned short* __restrict__ Wb,  // (512, 64) bf16, = Wctx^T
    const float* __restrict__ bctx,    // (512,)
    const float* __restrict__ walpha,  // (512,)
    unsigned short* __restrict__ attdst)    // bf16, row stride 2048
{
    __shared__ unsigned short cf[64 * 64];    // 8 KB, XOR chunk-swizzled
    __shared__ float ba[512];
    __shared__ float wal[512];
    __shared__ float awb[64];
    __shared__ float dsum[64];
    __shared__ float dots4[4][64];

    const int b   = blockIdx.x >> 1;
    const int hh  = blockIdx.x & 1;
    const int tid = threadIdx.x;

    if (tid < 64) awb[tid] = obat[b * 768 + 128 + hh * 64 + tid];
    __syncthreads();
    if (tid < 4) {
        float mx = -1e30f;
        for (int i = 0; i < 16; ++i) mx = fmaxf(mx, awb[tid * 16 + i]);
        float sum = 0.f;
        for (int i = 0; i < 16; ++i) { float e = exp2f_fast((awb[tid * 16 + i] - mx) * LOG2E); awb[tid * 16 + i] = e; sum += e; }
        float inv = rcpf(sum);
        for (int i = 0; i < 16; ++i) awb[tid * 16 + i] *= inv;
    }
    __syncthreads();

    ba[tid]        = bctx[tid]       + obat[b * 768 + 256 + tid];
    ba[tid + 256]  = bctx[tid + 256] + obat[b * 768 + 512 + tid];
    wal[tid]       = walpha[tid];
    wal[tid + 256] = walpha[tid + 256];
    {
        const int pl  = tid >> 2;
        const int sub = tid & 3;
        const int d0  = sub * 16;
        const int pg  = hh * 64 + pl;
        const int h   = pg >> 4;
        const int l   = (pg & 15) >> 2;
        const int Tlen = shapes[l];
        const int st   = starts[l];
        const float T  = (float)Tlen;
        const float refv = refp[b * 4 + l];
        const float offv = obat[b * 768 + pg];
        const float awv  = awb[pl];
        const float x   = (refv + offv * rcpf(T)) * T - 0.5f;  // exact: T is 2^k
        const float x0f = floorf(x);
        const float w1  = x - x0f;
        const int   x0  = (int)x0f;
        const float w0s = (x0 >= 0 && x0 < Tlen) ? (1.0f - w1) : 0.0f;
        const float w1s = (x0 + 1 >= 0 && x0 + 1 < Tlen) ? w1 : 0.0f;
        const int i0 = (min(max(x0, 0), Tlen - 1) + st) * 512 + h * 64;
        const int i1 = (min(max(x0 + 1, 0), Tlen - 1) + st) * 512 + h * 64;
        u16x8 o0, o1;
#pragma unroll
        for (int q = 0; q < 4; ++q) {
            const float4 a  = *(const float4*)&v[i0 + d0 + q * 4];
            const float4 bq = *(const float4*)&v[i1 + d0 + q * 4];
            unsigned short e0 = f2bf((a.x * w0s + bq.x * w1s) * awv);
            unsigned short e1 = f2bf((a.y * w0s + bq.y * w1s) * awv);
            unsigned short e2 = f2bf((a.z * w0s + bq.z * w1s) * awv);
            unsigned short e3 = f2bf((a.w * w0s + bq.w * w1s) * awv);
            if (q == 0) { o0[0] = e0; o0[1] = e1; o0[2] = e2; o0[3] = e3; }
            if (q == 1) { o0[4] = e0; o0[5] = e1; o0[6] = e2; o0[7] = e3; }
            if (q == 2) { o1[0] = e0; o1[1] = e1; o1[2] = e2; o1[3] = e3; }
            if (q == 3) { o1[4] = e0; o1[5] = e1; o1[6] = e2; o1[7] = e3; }
        }
        const int c0 = (sub * 2)     ^ (pl & 7);
        const int c1 = (sub * 2 + 1) ^ (pl & 7);
        *(u16x8*)&cf[pl * 64 + c0 * 8] = o0;
        *(u16x8*)&cf[pl * 64 + c1 * 8] = o1;
    }
    __syncthreads();

    {
        const int wn   = tid >> 6, lane = tid & 63;
        const int lr   = lane & 15, lg = lane >> 4;

        s16x8 afrag[4][2];
#pragma unroll
        for (int mt = 0; mt < 4; ++mt) {
            const int row = mt * 16 + lr;
#pragma unroll
            for (int ks = 0; ks < 2; ++ks) {
                const int ch = (ks * 4 + lg) ^ (row & 7);
                afrag[mt][ks] = *(const s16x8*)&cf[row * 64 + ch * 8];
            }
        }
        f32x4 part[4];
#pragma unroll
        for (int mt = 0; mt < 4; ++mt) part[mt] = (f32x4){0.f, 0.f, 0.f, 0.f};

#pragma clang loop unroll(disable)
        for (int nt = 0; nt < 8; ++nt) {
            const int col = (wn * 8 + nt) * 16 + lr;
            const s16x8 b0 = *(const s16x8*)&Wb[col * 64 + lg * 8];
            const s16x8 b1 = *(const s16x8*)&Wb[col * 64 + 32 + lg * 8];
            const float bav = ba[col], wav = wal[col];
#pragma unroll
            for (int mt = 0; mt < 4; ++mt) {
                f32x4 acc = {0.f, 0.f, 0.f, 0.f};
                acc = __builtin_amdgcn_mfma_f32_16x16x32_bf16(afrag[mt][0], b0, acc, 0, 0, 0);
                acc = __builtin_amdgcn_mfma_f32_16x16x32_bf16(afrag[mt][1], b1, acc, 0, 0, 0);
#pragma unroll
                for (int r = 0; r < 4; ++r)
                    part[mt][r] += tanhf_fast(acc[r] + bav) * wav;
            }
        }
#pragma unroll
        for (int mt = 0; mt < 4; ++mt) {
#pragma unroll
            for (int r = 0; r < 4; ++r) {
                float s = part[mt][r];
                s += __shfl_xor(s, 1); s += __shfl_xor(s, 2);
                s += __shfl_xor(s, 4); s += __shfl_xor(s, 8);
                if (lr == 0) dots4[wn][mt * 16 + lg * 4 + r] = s;
            }
        }
    }
    __syncthreads();
    if (tid < 64)
        dsum[tid] = dots4[0][tid] + dots4[1][tid] + dots4[2][tid] + dots4[3][tid];
    __syncthreads();

    if (tid < 4) {
        float mx = -1e30f;
        for (int i = 0; i < 16; ++i) mx = fmaxf(mx, dsum[tid * 16 + i]);
        float sum = 0.f;
        for (int i = 0; i < 16; ++i) { float e = exp2f_fast((dsum[tid * 16 + i] - mx) * LOG2E); dsum[tid * 16 + i] = e; sum += e; }
        float inv = rcpf(sum);
        for (int i = 0; i < 16; ++i) dsum[tid * 16 + i] *= inv;
    }
    __syncthreads();

    {
        const int hl = tid >> 6, d = tid & 63;
        const int ch = d >> 3, e = d & 7;
        float s = 0.f;
#pragma unroll
        for (int p = 0; p < 16; ++p) {
            const int row = hl * 16 + p;
            s += dsum[hl * 16 + p] * bf2f(cf[row * 64 + ((ch ^ (row & 7)) * 8) + e]);
        }
        attdst[(size_t)b * 2048 + hh * 256 + tid] = f2bf(s);
    }
}

extern "C" void kernel_launch(void* const* d_in, const int* in_sizes, int n_in,
                              void* d_out, int out_size, void* d_ws, size_t ws_size,
                              hipStream_t stream) {
    const float* xt     = (const float*)d_in[0];
    const float* h0     = (const float*)d_in[1];   // (2,1024,512)
    const float* c0     = (const float*)d_in[2];
    const float* query  = (const float*)d_in[3];   // (1,1024,512)
    const float* refp   = (const float*)d_in[4];   // (1,1024,4,1)
    const float* inflat = (const float*)d_in[5];   // (1,1920,512)
    const int*   shapes = (const int*)d_in[6];
    const int*   starts = (const int*)d_in[7];
    const float* Wv     = (const float*)d_in[9];   // (512,512) (K,N)
    const float* bv     = (const float*)d_in[10];
    const float* Woff   = (const float*)d_in[11];  // (1024,128) (K,N)
    const float* boff   = (const float*)d_in[12];
    const float* Wattw  = (const float*)d_in[13];  // (1024,128)
    const float* battw  = (const float*)d_in[14];
    const float* Wctx   = (const float*)d_in[15];  // (64,512)
    const float* bctx   = (const float*)d_in[16];
    const float* Wh2a   = (const float*)d_in[17];  // (512,512) (K,N)
    const float* bh2a   = (const float*)d_in[18];
    const float* walpha = (const float*)d_in[19];
    const float* Wih0   = (const float*)d_in[21];  // (2048,1536) (N,K)
    const float* Whh0   = (const float*)d_in[22];  // (2048,512)
    const float* Wih1   = (const float*)d_in[23];  // (2048,512)
    const float* Whh1   = (const float*)d_in[24];  // (2048,512)

    float* out = (float*)d_out;
    float* ws  = (float*)d_ws;

    // ws layout (f32 units), lifetime-overlapped
    float*          v     = ws;                                   // 983040
    float*          obat  = ws + 983040;                          // 1024x768 [off|aw|atth]
    unsigned short* Acat  = (unsigned short*)(ws + 1769472);      // 1024x2048 bf16
    unsigned short* Bcat0 = (unsigned short*)(ws + 2818048);      // 2048x2048 bf16 (gate-ilv)
    unsigned short* Ainf  = (unsigned short*)(ws + 4915200);      // 1920x512 bf16
    unsigned short* Wvt   = (unsigned short*)(ws + 5406720);      // 512x512 bf16
    unsigned short* Wcat  = (unsigned short*)(ws + 5537792);      // 768x1024 bf16
    unsigned short* Ahq   = (unsigned short*)(ws + 5931008);      // 1024x1024 bf16
    unsigned short* Wb    = (unsigned short*)(ws + 6455296);      // 512x64 bf16 (Wctx^T)
    unsigned short* Ag1   = (unsigned short*)(ws + 7012352);      // 1024x1024 bf16
    unsigned short* Bcat1 = (unsigned short*)(ws + 7536640);      // 2048x1024 bf16 (gate-ilv)
    // split-K partial buffers (bf16 1024x2048 each), in DEAD regions at use:
    //   gp0 over v+obat head (dead after fused_att); gp1 over Ainf..Ahq head
    unsigned short* gp0 = (unsigned short*)ws;                    // ws+0 .. +1048576
    unsigned short* gp1 = (unsigned short*)(ws + 4915200);        // .. +5963776

    const float* h00    = h0;
    const float* h_last = h0 + 524288;     // h0[1]
    float* h1  = out + 524288;             // h_new[0]
    float* c1  = out + 1572864;            // c_new[0]
    float* h2a = out;                      // first output
    float* h2b = out + 1048576;            // h_new[1]
    float* c2  = out + 2097152;            // c_new[1]

    // --- prep: converts (1 launch), tiled transposes + zero-pad (1 launch) ---
    { CvtJobs cj;
      cj.j[0]  = { xt,     Acat,          512,  2048, 512,  524288,  0 };
      cj.j[1]  = { query,  Acat + 1024,   512,  2048, 512,  524288,  0 };
      cj.j[2]  = { h00,    Acat + 1536,   512,  2048, 512,  524288,  0 };
      cj.j[3]  = { h_last, Ahq,           512,  1024, 512,  524288,  0 };
      cj.j[4]  = { query,  Ahq + 512,     512,  1024, 512,  524288,  0 };
      cj.j[5]  = { h_last, Ag1 + 512,     512,  1024, 512,  524288,  0 };
      cj.j[6]  = { Wih0,   Bcat0,         1536, 2048, 1536, 3145728, 1 };
      cj.j[7]  = { Whh0,   Bcat0 + 1536,  512,  2048, 512,  1048576, 1 };
      cj.j[8]  = { Wih1,   Bcat1,         512,  1024, 512,  1048576, 1 };
      cj.j[9]  = { Whh1,   Bcat1 + 512,   512,  1024, 512,  1048576, 1 };
      cj.j[10] = { inflat, Ainf,          512,  512,  512,  983040,  0 };
      cvt_bf16<<<dim3(3072, 11), 256, 0, stream>>>(cj); }
    { TJobs tj;
      tj.j[0] = { Wv,      Wvt,                     512, 512,  512, 0 };
      tj.j[1] = { Woff,    Wcat,                    128, 1024, 1024, 0 };
      tj.j[2] = { Wattw,   Wcat + 128 * 1024,       128, 1024, 1024, 0 };
      tj.j[3] = { Wh2a,    Wcat + 256 * 1024,       512, 1024, 512, 0 };
      tj.j[4] = { Wctx,    Wb,                      512, 64,   64,  0 };
      tj.j[5] = { nullptr, Wcat + 256 * 1024 + 512, 512, 1024, 512, 0 }; // zero K-pad
      tcvt_bf16<<<dim3(256, 6), 256, 0, stream>>>(tj); }

    // --- value + obat GEMMs fused into ONE launch (432 blocks, bias select) ---
    { GJobs gj;
      gj.j[0] = { Ainf, 512,  Wvt,  512,  bv,   bv,    bv,   0,   0,
                  v,    512, 512,  8,  240 };   // 1920x512: all cols -> bv[col]
      gj.j[1] = { Ahq,  1024, Wcat, 1024, boff, battw, bh2a, 128, 256,
                  obat, 768, 1024, 12, 192 };   // 1024x768: [boff|battw|bh2a]
      sgemm2<<<432, 256, 0, stream>>>(gj); }

    // --- fused deformable sampling + context attention (writes Acat[:,512:1024]) ---
    fused_att<<<2048, 256, 0, stream>>>(v, obat, refp, shapes, starts,
                                        Wb, bctx, walpha, Acat + 512);

    // LSTM0: split-K2 partials (1024 blocks, 3-4/CU) + fused reduce/act
    sgemm_ks<<<1024, 256, 0, stream>>>(Acat, 2048, Bcat0, 2048, gp0, gp1, 1024);
    red_lstm<<<2048, 256, 0, stream>>>(gp0, gp1, c0, h1, nullptr, Ag1, 1024, c1);
    // LSTM1: split-K2 partials + reduce/act (h2 -> out0 and h_new[1])
    sgemm_ks<<<1024, 256, 0, stream>>>(Ag1, 1024, Bcat1, 1024, gp0, gp1, 512);
    red_lstm<<<2048, 256, 0, stream>>>(gp0, gp1, c0 + 524288, h2a, h2b, nullptr, 0, c2);
}

// Round 17
// 105.223 us; speedup vs baseline: 1.5019x; 1.0407x over previous
//
#include <hip/hip_runtime.h>
#include <math.h>

// Problem constants (ShowAttendTellCore)
//   B=1024, D_MODEL=512, N_HEADS=8, D_HEAD=64, N_LEVELS=4, N_POINTS=4
//   T_TOTAL=1920, RNN=512, ENC=512, ATT_HID=512
// Output layout (f32): h2 (524288) | h1 | h2 | c1 | c2   (total 2621440)

typedef __attribute__((ext_vector_type(8))) short          s16x8;
typedef __attribute__((ext_vector_type(8))) unsigned short u16x8;
typedef __attribute__((ext_vector_type(4))) float          f32x4;

#define LOG2E  1.4426950408889634f
#define LOG2E2 2.8853900817779268f

__device__ __forceinline__ float rcpf(float x) { return __builtin_amdgcn_rcpf(x); }
__device__ __forceinline__ float exp2f_fast(float x) { return __builtin_amdgcn_exp2f(x); }
__device__ __forceinline__ float sigf(float x) {
    return rcpf(1.0f + exp2f_fast(-x * LOG2E));
}
__device__ __forceinline__ float tanhf_fast(float x) {
    const float xc = fminf(fmaxf(x, -15.0f), 15.0f);
    const float e2 = exp2f_fast(xc * LOG2E2);
    return 1.0f - 2.0f * rcpf(e2 + 1.0f);
}
__device__ __forceinline__ unsigned short f2bf(float f) {   // RNE f32->bf16
    unsigned u = __float_as_uint(f);
    u += 0x7FFF + ((u >> 16) & 1);
    return (unsigned short)(u >> 16);
}
__device__ __forceinline__ float bf2f(unsigned short h) {
    return __uint_as_float(((unsigned)h) << 16);
}
// async global->LDS, 16B per lane
__device__ __forceinline__ void gld_lds16(const unsigned short* g, unsigned short* l) {
    __builtin_amdgcn_global_load_lds(
        (const __attribute__((address_space(1))) void*)g,
        (__attribute__((address_space(3))) void*)l, 16, 0, 0);
}

// ---------------- unified prep kernel: converts + transposes, ONE launch ---
// mode 0: strided f32->bf16 copy (x4 vec);   block = 1024 elems
// mode 1: same + LSTM gate row-interleave (row' = (r%512)*4 + r/512)
// mode 2: 32x32 tile transpose-convert (sld = src row width N_); src==nullptr
//         means zero-fill the tile region. block = one 32x32 tile.
struct PJob { const float* src; unsigned short* dst; int sld, dld, cols, nblk, mode; };
struct PJobs { PJob j[17]; };
__global__ __launch_bounds__(256) void prep(PJobs pj) {
    __shared__ float lds[32][33];
    int bid = blockIdx.x, ji = 0;
    while (bid >= pj.j[ji].nblk) { bid -= pj.j[ji].nblk; ++ji; }
    const PJob jb = pj.j[ji];
    const int t = threadIdx.x;
    if (jb.mode <= 1) {
        const int i = (bid * 256 + t) * 4;
        const int r = i / jb.cols, c = i - r * jb.cols;
        const int rd = jb.mode ? (((r & 511) << 2) | (r >> 9)) : r;
        const float4 v4 = *(const float4*)&jb.src[(size_t)r * jb.sld + c];
        ushort4 o;
        o.x = f2bf(v4.x); o.y = f2bf(v4.y); o.z = f2bf(v4.z); o.w = f2bf(v4.w);
        *(ushort4*)&jb.dst[(size_t)rd * jb.dld + c] = o;
    } else {
        const int tilesN = jb.sld >> 5;
        const int tn0 = (bid % tilesN) << 5, tk0 = (bid / tilesN) << 5;
        if (jb.src) {
#pragma unroll
            for (int q = 0; q < 4; ++q) {
                const int e = t + (q << 8);
                lds[e >> 5][e & 31] = jb.src[(size_t)(tk0 + (e >> 5)) * jb.sld + tn0 + (e & 31)];
            }
            __syncthreads();
#pragma unroll
            for (int q = 0; q < 4; ++q) {
                const int e = t + (q << 8);
                const int n = e >> 5, k = e & 31;
                jb.dst[(size_t)(tn0 + n) * jb.dld + tk0 + k] = f2bf(lds[k][n]);
            }
        } else {
#pragma unroll
            for (int q = 0; q < 4; ++q) {
                const int e = t + (q << 8);
                jb.dst[(size_t)(tn0 + (e >> 5)) * jb.dld + tk0 + (e & 31)] = 0;
            }
        }
    }
}

// ===== 64x64-tile, BK=64 staged GEMMs; XOR swizzle rule #21 ================

#define STAGE_T(buf, k0) do { \
        gld_lds16(Ag1 + (k0), &As[buf][s1 * 8]); \
        gld_lds16(Ag2 + (k0), &As[buf][s2 * 8]); \
        gld_lds16(Bg1 + (k0), &Bs[buf][s1 * 8]); \
        gld_lds16(Bg2 + (k0), &Bs[buf][s2 * 8]); } while (0)

// ---------------- 2-job staged GEMM (value + obat in ONE launch) -----------
// C = A @ B^T + bias(3-piece select).  4-buffer deep pipeline, counted vmcnt.
struct GJob { const unsigned short* A; int lda; const unsigned short* B; int ldb;
              const float* b0; const float* b1; const float* b2; int l0, l1;
              float* C; int ldc; int K; int nbx; int count; };
struct GJobs { GJob j[2]; };
__global__ __launch_bounds__(256) void sgemm2(GJobs gj) {
    __shared__ unsigned short As[4][64 * 64];
    __shared__ unsigned short Bs[4][64 * 64];

    int bid = blockIdx.x;
    GJob jb = gj.j[0];
    if (bid >= jb.count) { bid -= jb.count; jb = gj.j[1]; }
    const int bn = bid % jb.nbx, bm = bid / jb.nbx;
    const int lda = jb.lda, ldb = jb.ldb;

    const int tid = threadIdx.x;
    const int w = tid >> 6, lane = tid & 63;
    const int wr = w >> 1, wc = w & 1;
    const int lr = lane & 15, lg = lane >> 4;

    const int s1 = tid, s2 = tid + 256;
    const int r1 = s1 >> 3, c1 = ((s1 & 7) ^ (r1 & 7)) << 3;
    const int r2 = s2 >> 3, c2 = ((s2 & 7) ^ (r2 & 7)) << 3;
    const unsigned short* Ag1 = jb.A + (size_t)(bm * 64 + r1) * lda + c1;
    const unsigned short* Ag2 = jb.A + (size_t)(bm * 64 + r2) * lda + c2;
    const unsigned short* Bg1 = jb.B + (size_t)(bn * 64 + r1) * ldb + c1;
    const unsigned short* Bg2 = jb.B + (size_t)(bn * 64 + r2) * ldb + c2;

    f32x4 acc[2][2];
#pragma unroll
    for (int mt = 0; mt < 2; ++mt)
#pragma unroll
        for (int nt = 0; nt < 2; ++nt) acc[mt][nt] = (f32x4){0.f, 0.f, 0.f, 0.f};

    const int nsteps = jb.K >> 6;
    STAGE_T(0, 0);
    if (nsteps > 1) STAGE_T(1, 64);
    if (nsteps > 2) STAGE_T(2, 128);

    for (int t = 0; t < nsteps; ++t) {
        const int infl = nsteps - 1 - t;
        if (infl >= 2)      asm volatile("s_waitcnt vmcnt(8)" ::: "memory");
        else if (infl == 1) asm volatile("s_waitcnt vmcnt(4)" ::: "memory");
        else                asm volatile("s_waitcnt vmcnt(0)" ::: "memory");
        __builtin_amdgcn_s_barrier();
        if (t + 3 < nsteps) STAGE_T((t + 3) & 3, (t + 3) << 6);
        const unsigned short* Ab = &As[t & 3][0];
        const unsigned short* Bb = &Bs[t & 3][0];
        s16x8 a[2][2], bfr[2][2];
#pragma unroll
        for (int mt = 0; mt < 2; ++mt) {
            const int ar = wr * 32 + mt * 16 + lr;
#pragma unroll
            for (int ks = 0; ks < 2; ++ks)
                a[mt][ks] = *(const s16x8*)&Ab[(ar * 8 + ((ks * 4 + lg) ^ (ar & 7))) * 8];
        }
#pragma unroll
        for (int nt = 0; nt < 2; ++nt) {
            const int br = wc * 32 + nt * 16 + lr;
#pragma unroll
            for (int ks = 0; ks < 2; ++ks)
                bfr[nt][ks] = *(const s16x8*)&Bb[(br * 8 + ((ks * 4 + lg) ^ (br & 7))) * 8];
        }
#pragma unroll
        for (int ks = 0; ks < 2; ++ks)
#pragma unroll
            for (int mt = 0; mt < 2; ++mt)
#pragma unroll
                for (int nt = 0; nt < 2; ++nt)
                    acc[mt][nt] = __builtin_amdgcn_mfma_f32_16x16x32_bf16(
                        a[mt][ks], bfr[nt][ks], acc[mt][nt], 0, 0, 0);
    }
#pragma unroll
    for (int nt = 0; nt < 2; ++nt) {
        const int col = bn * 64 + wc * 32 + nt * 16 + lr;
        float bb;
        if (col < jb.l0)      bb = jb.b0[col];
        else if (col < jb.l1) bb = jb.b1[col - jb.l0];
        else                  bb = jb.b2[col - jb.l1];
#pragma unroll
        for (int mt = 0; mt < 2; ++mt) {
            const int rbase = bm * 64 + wr * 32 + mt * 16 + lg * 4;
#pragma unroll
            for (int r = 0; r < 4; ++r)
                jb.C[(size_t)(rbase + r) * jb.ldc + col] = acc[mt][nt][r] + bb;
        }
    }
}

// ---------------- split-K2 partial GEMM for LSTM gates ---------------------
// N=2048 (nbx=32), M=1024 (16 bm), 512 blocks/slice x 2. XCD-chunked swizzle
// (T1, m157 pattern): blocks orig==x (mod 8) — same XCD under round-robin —
// compute 128 CONSECUTIVE tiles (4 bm-rows x all bn of one slice), so each
// XCD's unique operand bytes (~4.5MB) ~fit its private 4MB L2.
__global__ __launch_bounds__(256) void sgemm_ks(
    const unsigned short* __restrict__ A, int lda,
    const unsigned short* __restrict__ B, int ldb,
    unsigned short* __restrict__ gp0, unsigned short* __restrict__ gp1,
    int Kslice)
{
    __shared__ unsigned short As[3][64 * 64];   // 8KB x3
    __shared__ unsigned short Bs[3][64 * 64];   // 8KB x3  (48KB total)

    const int cb = ((blockIdx.x & 7) << 7) | (blockIdx.x >> 3);  // bijective on [0,1024)
    const int slice = cb >> 9;
    const int rblk  = cb & 511;
    const int bn = rblk & 31, bm = rblk >> 5;
    const int koff = slice * Kslice;
    unsigned short* Cp = slice ? gp1 : gp0;

    const int tid = threadIdx.x;
    const int w = tid >> 6, lane = tid & 63;
    const int wr = w >> 1, wc = w & 1;
    const int lr = lane & 15, lg = lane >> 4;

    const int s1 = tid, s2 = tid + 256;
    const int r1 = s1 >> 3, c1 = ((s1 & 7) ^ (r1 & 7)) << 3;
    const int r2 = s2 >> 3, c2 = ((s2 & 7) ^ (r2 & 7)) << 3;
    const unsigned short* Ag1 = A + (size_t)(bm * 64 + r1) * lda + koff + c1;
    const unsigned short* Ag2 = A + (size_t)(bm * 64 + r2) * lda + koff + c2;
    const unsigned short* Bg1 = B + (size_t)(bn * 64 + r1) * ldb + koff + c1;
    const unsigned short* Bg2 = B + (size_t)(bn * 64 + r2) * ldb + koff + c2;

    f32x4 acc[2][2];
#pragma unroll
    for (int mt = 0; mt < 2; ++mt)
#pragma unroll
        for (int nt = 0; nt < 2; ++nt) acc[mt][nt] = (f32x4){0.f, 0.f, 0.f, 0.f};

    const int nsteps = Kslice >> 6;
    STAGE_T(0, 0);
    if (nsteps > 1) STAGE_T(1, 64);

    for (int t = 0; t < nsteps; ++t) {
        const int infl = nsteps - 1 - t;
        if (infl >= 1) asm volatile("s_waitcnt vmcnt(4)" ::: "memory");
        else           asm volatile("s_waitcnt vmcnt(0)" ::: "memory");
        __builtin_amdgcn_s_barrier();
        if (t + 2 < nsteps) {
            const int bw = (t + 2) % 3;
            STAGE_T(bw, (t + 2) << 6);
        }
        const unsigned short* Ab = &As[t % 3][0];
        const unsigned short* Bb = &Bs[t % 3][0];
        s16x8 a[2][2], bfr[2][2];
#pragma unroll
        for (int mt = 0; mt < 2; ++mt) {
            const int ar = wr * 32 + mt * 16 + lr;
#pragma unroll
            for (int ks = 0; ks < 2; ++ks)
                a[mt][ks] = *(const s16x8*)&Ab[(ar * 8 + ((ks * 4 + lg) ^ (ar & 7))) * 8];
        }
#pragma unroll
        for (int nt = 0; nt < 2; ++nt) {
            const int br = wc * 32 + nt * 16 + lr;
#pragma unroll
            for (int ks = 0; ks < 2; ++ks)
                bfr[nt][ks] = *(const s16x8*)&Bb[(br * 8 + ((ks * 4 + lg) ^ (br & 7))) * 8];
        }
#pragma unroll
        for (int ks = 0; ks < 2; ++ks)
#pragma unroll
            for (int mt = 0; mt < 2; ++mt)
#pragma unroll
                for (int nt = 0; nt < 2; ++nt)
                    acc[mt][nt] = __builtin_amdgcn_mfma_f32_16x16x32_bf16(
                        a[mt][ks], bfr[nt][ks], acc[mt][nt], 0, 0, 0);
    }
#pragma unroll
    for (int nt = 0; nt < 2; ++nt) {
        const int col = bn * 64 + wc * 32 + nt * 16 + lr;
#pragma unroll
        for (int mt = 0; mt < 2; ++mt) {
            const int rbase = bm * 64 + wr * 32 + mt * 16 + lg * 4;
#pragma unroll
            for (int r = 0; r < 4; ++r)
                Cp[(size_t)(rbase + r) * 2048 + col] = f2bf(acc[mt][nt][r]);
        }
    }
}
#undef STAGE_T

// ---------------- split-K reduce + LSTM activation -------------------------
__global__ __launch_bounds__(256) void red_lstm(
    const unsigned short* __restrict__ g0, const unsigned short* __restrict__ g1,
    const float* __restrict__ c_in,
    float* __restrict__ h_a, float* __restrict__ h_b,
    unsigned short* __restrict__ hbf, int hbf_ld,
    float* __restrict__ c_out)
{
    const int id = blockIdx.x * 256 + threadIdx.x;   // row*512 + u
    const int row = id >> 9, u = id & 511;
    const size_t off = (size_t)row * 2048 + u * 4;
    const ushort4 p0 = *(const ushort4*)&g0[off];
    const ushort4 p1 = *(const ushort4*)&g1[off];
    const float gi = bf2f(p0.x) + bf2f(p1.x);
    const float gf = bf2f(p0.y) + bf2f(p1.y);
    const float gg = bf2f(p0.z) + bf2f(p1.z);
    const float go = bf2f(p0.w) + bf2f(p1.w);
    const float c  = c_in[id];
    const float c2 = sigf(gf) * c + sigf(gi) * tanhf_fast(gg);
    const float h2 = sigf(go) * tanhf_fast(c2);
    h_a[id] = h2;
    if (h_b) h_b[id] = h2;
    if (hbf) hbf[(size_t)row * hbf_ld + u] = f2bf(h2);
    c_out[id] = c2;
}

// ---------------- fused deformable sampling + context attention ------------
// Head-split: 2048 blocks x 256 thr, 4 heads/block (R15-proven).
__global__ __launch_bounds__(256, 4) void fused_att(
    const float* __restrict__ v,       // (1920, 512)
    const float* __restrict__ obat,    // (B, 768) [off|aw|atth]
    const float* __restrict__ refp,    // (B, 4)
    const int*   __restrict__ shapes,  // (4,)
    const int*   __restrict__ starts,  // (4,)
    const unsigned short* __restrict__ Wb,  // (512, 64) bf16, = Wctx^T
    const float* __restrict__ bctx,    // (512,)
    const float* __restrict__ walpha,  // (512,)
    unsigned short* __restrict__ attdst)    // bf16, row stride 2048
{
    __shared__ unsigned short cf[64 * 64];    // 8 KB, XOR chunk-swizzled
    __shared__ float ba[512];
    __shared__ float wal[512];
    __shared__ float awb[64];
    __shared__ float dsum[64];
    __shared__ float dots4[4][64];

    const int b   = blockIdx.x >> 1;
    const int hh  = blockIdx.x & 1;
    const int tid = threadIdx.x;

    if (tid < 64) awb[tid] = obat[b * 768 + 128 + hh * 64 + tid];
    __syncthreads();
    if (tid < 4) {
        float mx = -1e30f;
        for (int i = 0; i < 16; ++i) mx = fmaxf(mx, awb[tid * 16 + i]);
        float sum = 0.f;
        for (int i = 0; i < 16; ++i) { float e = exp2f_fast((awb[tid * 16 + i] - mx) * LOG2E); awb[tid * 16 + i] = e; sum += e; }
        float inv = rcpf(sum);
        for (int i = 0; i < 16; ++i) awb[tid * 16 + i] *= inv;
    }
    __syncthreads();

    ba[tid]        = bctx[tid]       + obat[b * 768 + 256 + tid];
    ba[tid + 256]  = bctx[tid + 256] + obat[b * 768 + 512 + tid];
    wal[tid]       = walpha[tid];
    wal[tid + 256] = walpha[tid + 256];
    {
        const int pl  = tid >> 2;
        const int sub = tid & 3;
        const int d0  = sub * 16;
        const int pg  = hh * 64 + pl;
        const int h   = pg >> 4;
        const int l   = (pg & 15) >> 2;
        const int Tlen = shapes[l];
        const int st   = starts[l];
        const float T  = (float)Tlen;
        const float refv = refp[b * 4 + l];
        const float offv = obat[b * 768 + pg];
        const float awv  = awb[pl];
        const float x   = (refv + offv * rcpf(T)) * T - 0.5f;  // exact: T is 2^k
        const float x0f = floorf(x);
        const float w1  = x - x0f;
        const int   x0  = (int)x0f;
        const float w0s = (x0 >= 0 && x0 < Tlen) ? (1.0f - w1) : 0.0f;
        const float w1s = (x0 + 1 >= 0 && x0 + 1 < Tlen) ? w1 : 0.0f;
        const int i0 = (min(max(x0, 0), Tlen - 1) + st) * 512 + h * 64;
        const int i1 = (min(max(x0 + 1, 0), Tlen - 1) + st) * 512 + h * 64;
        u16x8 o0, o1;
#pragma unroll
        for (int q = 0; q < 4; ++q) {
            const float4 a  = *(const float4*)&v[i0 + d0 + q * 4];
            const float4 bq = *(const float4*)&v[i1 + d0 + q * 4];
            unsigned short e0 = f2bf((a.x * w0s + bq.x * w1s) * awv);
            unsigned short e1 = f2bf((a.y * w0s + bq.y * w1s) * awv);
            unsigned short e2 = f2bf((a.z * w0s + bq.z * w1s) * awv);
            unsigned short e3 = f2bf((a.w * w0s + bq.w * w1s) * awv);
            if (q == 0) { o0[0] = e0; o0[1] = e1; o0[2] = e2; o0[3] = e3; }
            if (q == 1) { o0[4] = e0; o0[5] = e1; o0[6] = e2; o0[7] = e3; }
            if (q == 2) { o1[0] = e0; o1[1] = e1; o1[2] = e2; o1[3] = e3; }
            if (q == 3) { o1[4] = e0; o1[5] = e1; o1[6] = e2; o1[7] = e3; }
        }
        const int c0 = (sub * 2)     ^ (pl & 7);
        const int c1 = (sub * 2 + 1) ^ (pl & 7);
        *(u16x8*)&cf[pl * 64 + c0 * 8] = o0;
        *(u16x8*)&cf[pl * 64 + c1 * 8] = o1;
    }
    __syncthreads();

    {
        const int wn   = tid >> 6, lane = tid & 63;
        const int lr   = lane & 15, lg = lane >> 4;

        s16x8 afrag[4][2];
#pragma unroll
        for (int mt = 0; mt < 4; ++mt) {
            const int row = mt * 16 + lr;
#pragma unroll
            for (int ks = 0; ks < 2; ++ks) {
                const int ch = (ks * 4 + lg) ^ (row & 7);
                afrag[mt][ks] = *(const s16x8*)&cf[row * 64 + ch * 8];
            }
        }
        f32x4 part[4];
#pragma unroll
        for (int mt = 0; mt < 4; ++mt) part[mt] = (f32x4){0.f, 0.f, 0.f, 0.f};

#pragma clang loop unroll(disable)
        for (int nt = 0; nt < 8; ++nt) {
            const int col = (wn * 8 + nt) * 16 + lr;
            const s16x8 b0 = *(const s16x8*)&Wb[col * 64 + lg * 8];
            const s16x8 b1 = *(const s16x8*)&Wb[col * 64 + 32 + lg * 8];
            const float bav = ba[col], wav = wal[col];
#pragma unroll
            for (int mt = 0; mt < 4; ++mt) {
                f32x4 acc = {0.f, 0.f, 0.f, 0.f};
                acc = __builtin_amdgcn_mfma_f32_16x16x32_bf16(afrag[mt][0], b0, acc, 0, 0, 0);
                acc = __builtin_amdgcn_mfma_f32_16x16x32_bf16(afrag[mt][1], b1, acc, 0, 0, 0);
#pragma unroll
                for (int r = 0; r < 4; ++r)
                    part[mt][r] += tanhf_fast(acc[r] + bav) * wav;
            }
        }
#pragma unroll
        for (int mt = 0; mt < 4; ++mt) {
#pragma unroll
            for (int r = 0; r < 4; ++r) {
                float s = part[mt][r];
                s += __shfl_xor(s, 1); s += __shfl_xor(s, 2);
                s += __shfl_xor(s, 4); s += __shfl_xor(s, 8);
                if (lr == 0) dots4[wn][mt * 16 + lg * 4 + r] = s;
            }
        }
    }
    __syncthreads();
    if (tid < 64)
        dsum[tid] = dots4[0][tid] + dots4[1][tid] + dots4[2][tid] + dots4[3][tid];
    __syncthreads();

    if (tid < 4) {
        float mx = -1e30f;
        for (int i = 0; i < 16; ++i) mx = fmaxf(mx, dsum[tid * 16 + i]);
        float sum = 0.f;
        for (int i = 0; i < 16; ++i) { float e = exp2f_fast((dsum[tid * 16 + i] - mx) * LOG2E); dsum[tid * 16 + i] = e; sum += e; }
        float inv = rcpf(sum);
        for (int i = 0; i < 16; ++i) dsum[tid * 16 + i] *= inv;
    }
    __syncthreads();

    {
        const int hl = tid >> 6, d = tid & 63;
        const int ch = d >> 3, e = d & 7;
        float s = 0.f;
#pragma unroll
        for (int p = 0; p < 16; ++p) {
            const int row = hl * 16 + p;
            s += dsum[hl * 16 + p] * bf2f(cf[row * 64 + ((ch ^ (row & 7)) * 8) + e]);
        }
        attdst[(size_t)b * 2048 + hh * 256 + tid] = f2bf(s);
    }
}

extern "C" void kernel_launch(void* const* d_in, const int* in_sizes, int n_in,
                              void* d_out, int out_size, void* d_ws, size_t ws_size,
                              hipStream_t stream) {
    const float* xt     = (const float*)d_in[0];
    const float* h0     = (const float*)d_in[1];   // (2,1024,512)
    const float* c0     = (const float*)d_in[2];
    const float* query  = (const float*)d_in[3];   // (1,1024,512)
    const float* refp   = (const float*)d_in[4];   // (1,1024,4,1)
    const float* inflat = (const float*)d_in[5];   // (1,1920,512)
    const int*   shapes = (const int*)d_in[6];
    const int*   starts = (const int*)d_in[7];
    const float* Wv     = (const float*)d_in[9];   // (512,512) (K,N)
    const float* bv     = (const float*)d_in[10];
    const float* Woff   = (const float*)d_in[11];  // (1024,128) (K,N)
    const float* boff   = (const float*)d_in[12];
    const float* Wattw  = (const float*)d_in[13];  // (1024,128)
    const float* battw  = (const float*)d_in[14];
    const float* Wctx   = (const float*)d_in[15];  // (64,512)
    const float* bctx   = (const float*)d_in[16];
    const float* Wh2a   = (const float*)d_in[17];  // (512,512) (K,N)
    const float* bh2a   = (const float*)d_in[18];
    const float* walpha = (const float*)d_in[19];
    const float* Wih0   = (const float*)d_in[21];  // (2048,1536) (N,K)
    const float* Whh0   = (const float*)d_in[22];  // (2048,512)
    const float* Wih1   = (const float*)d_in[23];  // (2048,512)
    const float* Whh1   = (const float*)d_in[24];  // (2048,512)

    float* out = (float*)d_out;
    float* ws  = (float*)d_ws;

    // ws layout (f32 units), lifetime-overlapped
    float*          v     = ws;                                   // 983040
    float*          obat  = ws + 983040;                          // 1024x768 [off|aw|atth]
    unsigned short* Acat  = (unsigned short*)(ws + 1769472);      // 1024x2048 bf16
    unsigned short* Bcat0 = (unsigned short*)(ws + 2818048);      // 2048x2048 bf16 (gate-ilv)
    unsigned short* Ainf  = (unsigned short*)(ws + 4915200);      // 1920x512 bf16
    unsigned short* Wvt   = (unsigned short*)(ws + 5406720);      // 512x512 bf16
    unsigned short* Wcat  = (unsigned short*)(ws + 5537792);      // 768x1024 bf16
    unsigned short* Ahq   = (unsigned short*)(ws + 5931008);      // 1024x1024 bf16
    unsigned short* Wb    = (unsigned short*)(ws + 6455296);      // 512x64 bf16 (Wctx^T)
    unsigned short* Ag1   = (unsigned short*)(ws + 7012352);      // 1024x1024 bf16
    unsigned short* Bcat1 = (unsigned short*)(ws + 7536640);      // 2048x1024 bf16 (gate-ilv)
    // split-K partial buffers (bf16 1024x2048 each), in DEAD regions at use
    unsigned short* gp0 = (unsigned short*)ws;                    // ws+0 .. +1048576
    unsigned short* gp1 = (unsigned short*)(ws + 4915200);        // .. +5963776

    const float* h00    = h0;
    const float* h_last = h0 + 524288;     // h0[1]
    float* h1  = out + 524288;             // h_new[0]
    float* c1  = out + 1572864;            // c_new[0]
    float* h2a = out;                      // first output
    float* h2b = out + 1048576;            // h_new[1]
    float* c2  = out + 2097152;            // c_new[1]

    // --- prep: all converts + transposes + zero-pad in ONE launch -----------
    // mode<=1: nblk = total/1024; mode 2: nblk = (sld/32)*(K/32) tiles.
    { PJobs pj;
      pj.j[0]  = { xt,      Acat,          512,  2048, 512,  512,  0 };
      pj.j[1]  = { query,   Acat + 1024,   512,  2048, 512,  512,  0 };
      pj.j[2]  = { h00,     Acat + 1536,   512,  2048, 512,  512,  0 };
      pj.j[3]  = { h_last,  Ahq,           512,  1024, 512,  512,  0 };
      pj.j[4]  = { query,   Ahq + 512,     512,  1024, 512,  512,  0 };
      pj.j[5]  = { h_last,  Ag1 + 512,     512,  1024, 512,  512,  0 };
      pj.j[6]  = { Wih0,    Bcat0,         1536, 2048, 1536, 3072, 1 };
      pj.j[7]  = { Whh0,    Bcat0 + 1536,  512,  2048, 512,  1024, 1 };
      pj.j[8]  = { Wih1,    Bcat1,         512,  1024, 512,  1024, 1 };
      pj.j[9]  = { Whh1,    Bcat1 + 512,   512,  1024, 512,  1024, 1 };
      pj.j[10] = { inflat,  Ainf,          512,  512,  512,  960,  0 };
      pj.j[11] = { Wv,      Wvt,                     512, 512,  512, 256, 2 };
      pj.j[12] = { Woff,    Wcat,                    128, 1024, 1024, 128, 2 };
      pj.j[13] = { Wattw,   Wcat + 128 * 1024,       128, 1024, 1024, 128, 2 };
      pj.j[14] = { Wh2a,    Wcat + 256 * 1024,       512, 1024, 512, 256, 2 };
      pj.j[15] = { Wctx,    Wb,                      512, 64,   64,  32,  2 };
      pj.j[16] = { nullptr, Wcat + 256 * 1024 + 512, 512, 1024, 512, 256, 2 };
      prep<<<11232, 256, 0, stream>>>(pj); }

    // --- value + obat GEMMs fused into ONE launch (432 blocks, bias select) ---
    { GJobs gj;
      gj.j[0] = { Ainf, 512,  Wvt,  512,  bv,   bv,    bv,   0,   0,
                  v,    512, 512,  8,  240 };   // 1920x512: all cols -> bv[col]
      gj.j[1] = { Ahq,  1024, Wcat, 1024, boff, battw, bh2a, 128, 256,
                  obat, 768, 1024, 12, 192 };   // 1024x768: [boff|battw|bh2a]
      sgemm2<<<432, 256, 0, stream>>>(gj); }

    // --- fused deformable sampling + context attention (writes Acat[:,512:1024]) ---
    fused_att<<<2048, 256, 0, stream>>>(v, obat, refp, shapes, starts,
                                        Wb, bctx, walpha, Acat + 512);

    // LSTM0: split-K2 partials (XCD-swizzled) + fused reduce/act
    sgemm_ks<<<1024, 256, 0, stream>>>(Acat, 2048, Bcat0, 2048, gp0, gp1, 1024);
    red_lstm<<<2048, 256, 0, stream>>>(gp0, gp1, c0, h1, nullptr, Ag1, 1024, c1);
    // LSTM1: split-K2 partials + reduce/act (h2 -> out0 and h_new[1])
    sgemm_ks<<<1024, 256, 0, stream>>>(Ag1, 1024, Bcat1, 1024, gp0, gp1, 512);
    red_lstm<<<2048, 256, 0, stream>>>(gp0, gp1, c0 + 524288, h2a, h2b, nullptr, 0, c2);
}

// Round 18
// 97.006 us; speedup vs baseline: 1.6291x; 1.0847x over previous
//
#include <hip/hip_runtime.h>
#include <math.h>

// Problem constants (ShowAttendTellCore)
//   B=1024, D_MODEL=512, N_HEADS=8, D_HEAD=64, N_LEVELS=4, N_POINTS=4
//   T_TOTAL=1920, RNN=512, ENC=512, ATT_HID=512
// Output layout (f32): h2 (524288) | h1 | h2 | c1 | c2   (total 2621440)

typedef __attribute__((ext_vector_type(8))) short          s16x8;
typedef __attribute__((ext_vector_type(8))) unsigned short u16x8;
typedef __attribute__((ext_vector_type(4))) float          f32x4;

#define LOG2E  1.4426950408889634f
#define LOG2E2 2.8853900817779268f

__device__ __forceinline__ float rcpf(float x) { return __builtin_amdgcn_rcpf(x); }
__device__ __forceinline__ float exp2f_fast(float x) { return __builtin_amdgcn_exp2f(x); }
__device__ __forceinline__ float sigf(float x) {
    return rcpf(1.0f + exp2f_fast(-x * LOG2E));
}
__device__ __forceinline__ float tanhf_fast(float x) {
    const float xc = fminf(fmaxf(x, -15.0f), 15.0f);
    const float e2 = exp2f_fast(xc * LOG2E2);
    return 1.0f - 2.0f * rcpf(e2 + 1.0f);
}
__device__ __forceinline__ unsigned short f2bf(float f) {   // RNE f32->bf16
    unsigned u = __float_as_uint(f);
    u += 0x7FFF + ((u >> 16) & 1);
    return (unsigned short)(u >> 16);
}
__device__ __forceinline__ float bf2f(unsigned short h) {
    return __uint_as_float(((unsigned)h) << 16);
}
// async global->LDS, 16B per lane
__device__ __forceinline__ void gld_lds16(const unsigned short* g, unsigned short* l) {
    __builtin_amdgcn_global_load_lds(
        (const __attribute__((address_space(1))) void*)g,
        (__attribute__((address_space(3))) void*)l, 16, 0, 0);
}

// ---------------- unified prep kernel: converts + transposes, ONE launch ---
// mode 0: strided f32->bf16 copy (x4 vec);   block = 1024 elems
// mode 1: same + LSTM gate row-interleave (row' = (r%512)*4 + r/512)
// mode 2: 32x32 tile transpose-convert (sld = src row width N_); src==nullptr
//         means zero-fill the tile region. block = one 32x32 tile.
struct PJob { const float* src; unsigned short* dst; int sld, dld, cols, nblk, mode; };
struct PJobs { PJob j[17]; };
__global__ __launch_bounds__(256) void prep(PJobs pj) {
    __shared__ float lds[32][33];
    int bid = blockIdx.x, ji = 0;
    while (bid >= pj.j[ji].nblk) { bid -= pj.j[ji].nblk; ++ji; }
    const PJob jb = pj.j[ji];
    const int t = threadIdx.x;
    if (jb.mode <= 1) {
        const int i = (bid * 256 + t) * 4;
        const int r = i / jb.cols, c = i - r * jb.cols;
        const int rd = jb.mode ? (((r & 511) << 2) | (r >> 9)) : r;
        const float4 v4 = *(const float4*)&jb.src[(size_t)r * jb.sld + c];
        ushort4 o;
        o.x = f2bf(v4.x); o.y = f2bf(v4.y); o.z = f2bf(v4.z); o.w = f2bf(v4.w);
        *(ushort4*)&jb.dst[(size_t)rd * jb.dld + c] = o;
    } else {
        const int tilesN = jb.sld >> 5;
        const int tn0 = (bid % tilesN) << 5, tk0 = (bid / tilesN) << 5;
        if (jb.src) {
#pragma unroll
            for (int q = 0; q < 4; ++q) {
                const int e = t + (q << 8);
                lds[e >> 5][e & 31] = jb.src[(size_t)(tk0 + (e >> 5)) * jb.sld + tn0 + (e & 31)];
            }
            __syncthreads();
#pragma unroll
            for (int q = 0; q < 4; ++q) {
                const int e = t + (q << 8);
                const int n = e >> 5, k = e & 31;
                jb.dst[(size_t)(tn0 + n) * jb.dld + tk0 + k] = f2bf(lds[k][n]);
            }
        } else {
#pragma unroll
            for (int q = 0; q < 4; ++q) {
                const int e = t + (q << 8);
                jb.dst[(size_t)(tn0 + (e >> 5)) * jb.dld + tk0 + (e & 31)] = 0;
            }
        }
    }
}

// ===== staged GEMMs; XOR chunk swizzle per rule #21 ========================

#define STAGE_T(buf, k0) do { \
        gld_lds16(Ag1 + (k0), &As[buf][s1 * 8]); \
        gld_lds16(Ag2 + (k0), &As[buf][s2 * 8]); \
        gld_lds16(Bg1 + (k0), &Bs[buf][s1 * 8]); \
        gld_lds16(Bg2 + (k0), &Bs[buf][s2 * 8]); } while (0)

// ---------------- 2-job staged GEMM (value + obat in ONE launch) -----------
// BM=BN=64, BK=64; C = A @ B^T + bias(3-piece select). 4-buf deep pipeline.
struct GJob { const unsigned short* A; int lda; const unsigned short* B; int ldb;
              const float* b0; const float* b1; const float* b2; int l0, l1;
              float* C; int ldc; int K; int nbx; int count; };
struct GJobs { GJob j[2]; };
__global__ __launch_bounds__(256) void sgemm2(GJobs gj) {
    __shared__ unsigned short As[4][64 * 64];
    __shared__ unsigned short Bs[4][64 * 64];

    int bid = blockIdx.x;
    GJob jb = gj.j[0];
    if (bid >= jb.count) { bid -= jb.count; jb = gj.j[1]; }
    const int bn = bid % jb.nbx, bm = bid / jb.nbx;
    const int lda = jb.lda, ldb = jb.ldb;

    const int tid = threadIdx.x;
    const int w = tid >> 6, lane = tid & 63;
    const int wr = w >> 1, wc = w & 1;
    const int lr = lane & 15, lg = lane >> 4;

    const int s1 = tid, s2 = tid + 256;
    const int r1 = s1 >> 3, c1 = ((s1 & 7) ^ (r1 & 7)) << 3;
    const int r2 = s2 >> 3, c2 = ((s2 & 7) ^ (r2 & 7)) << 3;
    const unsigned short* Ag1 = jb.A + (size_t)(bm * 64 + r1) * lda + c1;
    const unsigned short* Ag2 = jb.A + (size_t)(bm * 64 + r2) * lda + c2;
    const unsigned short* Bg1 = jb.B + (size_t)(bn * 64 + r1) * ldb + c1;
    const unsigned short* Bg2 = jb.B + (size_t)(bn * 64 + r2) * ldb + c2;

    f32x4 acc[2][2];
#pragma unroll
    for (int mt = 0; mt < 2; ++mt)
#pragma unroll
        for (int nt = 0; nt < 2; ++nt) acc[mt][nt] = (f32x4){0.f, 0.f, 0.f, 0.f};

    const int nsteps = jb.K >> 6;
    STAGE_T(0, 0);
    if (nsteps > 1) STAGE_T(1, 64);
    if (nsteps > 2) STAGE_T(2, 128);

    for (int t = 0; t < nsteps; ++t) {
        const int infl = nsteps - 1 - t;
        if (infl >= 2)      asm volatile("s_waitcnt vmcnt(8)" ::: "memory");
        else if (infl == 1) asm volatile("s_waitcnt vmcnt(4)" ::: "memory");
        else                asm volatile("s_waitcnt vmcnt(0)" ::: "memory");
        __builtin_amdgcn_s_barrier();
        if (t + 3 < nsteps) STAGE_T((t + 3) & 3, (t + 3) << 6);
        const unsigned short* Ab = &As[t & 3][0];
        const unsigned short* Bb = &Bs[t & 3][0];
        s16x8 a[2][2], bfr[2][2];
#pragma unroll
        for (int mt = 0; mt < 2; ++mt) {
            const int ar = wr * 32 + mt * 16 + lr;
#pragma unroll
            for (int ks = 0; ks < 2; ++ks)
                a[mt][ks] = *(const s16x8*)&Ab[(ar * 8 + ((ks * 4 + lg) ^ (ar & 7))) * 8];
        }
#pragma unroll
        for (int nt = 0; nt < 2; ++nt) {
            const int br = wc * 32 + nt * 16 + lr;
#pragma unroll
            for (int ks = 0; ks < 2; ++ks)
                bfr[nt][ks] = *(const s16x8*)&Bb[(br * 8 + ((ks * 4 + lg) ^ (br & 7))) * 8];
        }
#pragma unroll
        for (int ks = 0; ks < 2; ++ks)
#pragma unroll
            for (int mt = 0; mt < 2; ++mt)
#pragma unroll
                for (int nt = 0; nt < 2; ++nt)
                    acc[mt][nt] = __builtin_amdgcn_mfma_f32_16x16x32_bf16(
                        a[mt][ks], bfr[nt][ks], acc[mt][nt], 0, 0, 0);
    }
#pragma unroll
    for (int nt = 0; nt < 2; ++nt) {
        const int col = bn * 64 + wc * 32 + nt * 16 + lr;
        float bb;
        if (col < jb.l0)      bb = jb.b0[col];
        else if (col < jb.l1) bb = jb.b1[col - jb.l0];
        else                  bb = jb.b2[col - jb.l1];
#pragma unroll
        for (int mt = 0; mt < 2; ++mt) {
            const int rbase = bm * 64 + wr * 32 + mt * 16 + lg * 4;
#pragma unroll
            for (int r = 0; r < 4; ++r)
                jb.C[(size_t)(rbase + r) * jb.ldc + col] = acc[mt][nt][r] + bb;
        }
    }
}
#undef STAGE_T

// ---------------- split-K2 partial GEMM for LSTM gates ---------------------
// R18: BM=64 BN=128 (wave 32x64, acc 2x4) -> 0.75 KB LDS-read per MFMA
// (was 1.0) since sgemm_ks is LDS-BW-bound. Grid 512 (2 blocks/CU, 72KB LDS).
// 3-buf, counted vmcnt(6) depth-2. XCD-chunked bijective swizzle on [0,512).
__global__ __launch_bounds__(256) void sgemm_ks(
    const unsigned short* __restrict__ A, int lda,
    const unsigned short* __restrict__ B, int ldb,
    unsigned short* __restrict__ gp0, unsigned short* __restrict__ gp1,
    int Kslice)
{
    __shared__ unsigned short As[3][64 * 64];    // 8KB x3
    __shared__ unsigned short Bs[3][128 * 64];   // 16KB x3  (72KB total)

    const int cb = ((blockIdx.x & 7) << 6) | (blockIdx.x >> 3);  // bijective [0,512)
    const int slice = cb >> 8;
    const int rblk  = cb & 255;
    const int bn = rblk & 15, bm = rblk >> 4;    // bn: 16 x 128 cols, bm: 16 x 64 rows
    const int koff = slice * Kslice;
    unsigned short* Cp = slice ? gp1 : gp0;

    const int tid = threadIdx.x;
    const int w = tid >> 6, lane = tid & 63;
    const int wr = w >> 1, wc = w & 1;
    const int lr = lane & 15, lg = lane >> 4;

    // staging slots: A 2 passes (512 slots), B 4 passes (1024 slots)
    const int s1 = tid, s2 = tid + 256, s3 = tid + 512, s4 = tid + 768;
    const int ra1 = s1 >> 3, ca1 = ((s1 & 7) ^ (ra1 & 7)) << 3;
    const int ra2 = s2 >> 3, ca2 = ((s2 & 7) ^ (ra2 & 7)) << 3;
    const int rb3 = s3 >> 3, cb3 = ((s3 & 7) ^ (rb3 & 7)) << 3;
    const int rb4 = s4 >> 3, cb4 = ((s4 & 7) ^ (rb4 & 7)) << 3;
    const unsigned short* Ag1 = A + (size_t)(bm * 64 + ra1) * lda + koff + ca1;
    const unsigned short* Ag2 = A + (size_t)(bm * 64 + ra2) * lda + koff + ca2;
    const unsigned short* Bg1 = B + (size_t)(bn * 128 + ra1) * ldb + koff + ca1;
    const unsigned short* Bg2 = B + (size_t)(bn * 128 + ra2) * ldb + koff + ca2;
    const unsigned short* Bg3 = B + (size_t)(bn * 128 + rb3) * ldb + koff + cb3;
    const unsigned short* Bg4 = B + (size_t)(bn * 128 + rb4) * ldb + koff + cb4;

#define STAGE_K(buf, k0) do { \
        gld_lds16(Ag1 + (k0), &As[buf][s1 * 8]); \
        gld_lds16(Ag2 + (k0), &As[buf][s2 * 8]); \
        gld_lds16(Bg1 + (k0), &Bs[buf][s1 * 8]); \
        gld_lds16(Bg2 + (k0), &Bs[buf][s2 * 8]); \
        gld_lds16(Bg3 + (k0), &Bs[buf][s3 * 8]); \
        gld_lds16(Bg4 + (k0), &Bs[buf][s4 * 8]); } while (0)

    f32x4 acc[2][4];
#pragma unroll
    for (int mt = 0; mt < 2; ++mt)
#pragma unroll
        for (int nt = 0; nt < 4; ++nt) acc[mt][nt] = (f32x4){0.f, 0.f, 0.f, 0.f};

    const int nsteps = Kslice >> 6;
    STAGE_K(0, 0);
    if (nsteps > 1) STAGE_K(1, 64);

    for (int t = 0; t < nsteps; ++t) {
        const int infl = nsteps - 1 - t;
        if (infl >= 1) asm volatile("s_waitcnt vmcnt(6)" ::: "memory");
        else           asm volatile("s_waitcnt vmcnt(0)" ::: "memory");
        __builtin_amdgcn_s_barrier();
        if (t + 2 < nsteps) {
            const int bw = (t + 2) % 3;
            STAGE_K(bw, (t + 2) << 6);
        }
        const unsigned short* Ab = &As[t % 3][0];
        const unsigned short* Bb = &Bs[t % 3][0];
        s16x8 a[2][2], bfr[4][2];
#pragma unroll
        for (int mt = 0; mt < 2; ++mt) {
            const int ar = wr * 32 + mt * 16 + lr;
#pragma unroll
            for (int ks = 0; ks < 2; ++ks)
                a[mt][ks] = *(const s16x8*)&Ab[(ar * 8 + ((ks * 4 + lg) ^ (ar & 7))) * 8];
        }
#pragma unroll
        for (int nt = 0; nt < 4; ++nt) {
            const int br = wc * 64 + nt * 16 + lr;
#pragma unroll
            for (int ks = 0; ks < 2; ++ks)
                bfr[nt][ks] = *(const s16x8*)&Bb[(br * 8 + ((ks * 4 + lg) ^ (br & 7))) * 8];
        }
#pragma unroll
        for (int ks = 0; ks < 2; ++ks)
#pragma unroll
            for (int mt = 0; mt < 2; ++mt)
#pragma unroll
                for (int nt = 0; nt < 4; ++nt)
                    acc[mt][nt] = __builtin_amdgcn_mfma_f32_16x16x32_bf16(
                        a[mt][ks], bfr[nt][ks], acc[mt][nt], 0, 0, 0);
    }
#undef STAGE_K
#pragma unroll
    for (int nt = 0; nt < 4; ++nt) {
        const int col = bn * 128 + wc * 64 + nt * 16 + lr;
#pragma unroll
        for (int mt = 0; mt < 2; ++mt) {
            const int rbase = bm * 64 + wr * 32 + mt * 16 + lg * 4;
#pragma unroll
            for (int r = 0; r < 4; ++r)
                Cp[(size_t)(rbase + r) * 2048 + col] = f2bf(acc[mt][nt][r]);
        }
    }
}

// ---------------- split-K reduce + LSTM activation -------------------------
__global__ __launch_bounds__(256) void red_lstm(
    const unsigned short* __restrict__ g0, const unsigned short* __restrict__ g1,
    const float* __restrict__ c_in,
    float* __restrict__ h_a, float* __restrict__ h_b,
    unsigned short* __restrict__ hbf, int hbf_ld,
    float* __restrict__ c_out)
{
    const int id = blockIdx.x * 256 + threadIdx.x;   // row*512 + u
    const int row = id >> 9, u = id & 511;
    const size_t off = (size_t)row * 2048 + u * 4;
    const ushort4 p0 = *(const ushort4*)&g0[off];
    const ushort4 p1 = *(const ushort4*)&g1[off];
    const float gi = bf2f(p0.x) + bf2f(p1.x);
    const float gf = bf2f(p0.y) + bf2f(p1.y);
    const float gg = bf2f(p0.z) + bf2f(p1.z);
    const float go = bf2f(p0.w) + bf2f(p1.w);
    const float c  = c_in[id];
    const float c2 = sigf(gf) * c + sigf(gi) * tanhf_fast(gg);
    const float h2 = sigf(go) * tanhf_fast(c2);
    h_a[id] = h2;
    if (h_b) h_b[id] = h2;
    if (hbf) hbf[(size_t)row * hbf_ld + u] = f2bf(h2);
    c_out[id] = c2;
}

// ---------------- fused deformable sampling + context attention ------------
// Head-split: 2048 blocks x 256 thr, 4 heads/block (R15-proven).
__global__ __launch_bounds__(256, 4) void fused_att(
    const float* __restrict__ v,       // (1920, 512)
    const float* __restrict__ obat,    // (B, 768) [off|aw|atth]
    const float* __restrict__ refp,    // (B, 4)
    const int*   __restrict__ shapes,  // (4,)
    const int*   __restrict__ starts,  // (4,)
    const unsigned short* __restrict__ Wb,  // (512, 64) bf16, = Wctx^T
    const float* __restrict__ bctx,    // (512,)
    const float* __restrict__ walpha,  // (512,)
    unsigned short* __restrict__ attdst)    // bf16, row stride 2048
{
    __shared__ unsigned short cf[64 * 64];    // 8 KB, XOR chunk-swizzled
    __shared__ float ba[512];
    __shared__ float wal[512];
    __shared__ float awb[64];
    __shared__ float dsum[64];
    __shared__ float dots4[4][64];

    const int b   = blockIdx.x >> 1;
    const int hh  = blockIdx.x & 1;
    const int tid = threadIdx.x;

    if (tid < 64) awb[tid] = obat[b * 768 + 128 + hh * 64 + tid];
    __syncthreads();
    if (tid < 4) {
        float mx = -1e30f;
        for (int i = 0; i < 16; ++i) mx = fmaxf(mx, awb[tid * 16 + i]);
        float sum = 0.f;
        for (int i = 0; i < 16; ++i) { float e = exp2f_fast((awb[tid * 16 + i] - mx) * LOG2E); awb[tid * 16 + i] = e; sum += e; }
        float inv = rcpf(sum);
        for (int i = 0; i < 16; ++i) awb[tid * 16 + i] *= inv;
    }
    __syncthreads();

    ba[tid]        = bctx[tid]       + obat[b * 768 + 256 + tid];
    ba[tid + 256]  = bctx[tid + 256] + obat[b * 768 + 512 + tid];
    wal[tid]       = walpha[tid];
    wal[tid + 256] = walpha[tid + 256];
    {
        const int pl  = tid >> 2;
        const int sub = tid & 3;
        const int d0  = sub * 16;
        const int pg  = hh * 64 + pl;
        const int h   = pg >> 4;
        const int l   = (pg & 15) >> 2;
        const int Tlen = shapes[l];
        const int st   = starts[l];
        const float T  = (float)Tlen;
        const float refv = refp[b * 4 + l];
        const float offv = obat[b * 768 + pg];
        const float awv  = awb[pl];
        const float x   = (refv + offv * rcpf(T)) * T - 0.5f;  // exact: T is 2^k
        const float x0f = floorf(x);
        const float w1  = x - x0f;
        const int   x0  = (int)x0f;
        const float w0s = (x0 >= 0 && x0 < Tlen) ? (1.0f - w1) : 0.0f;
        const float w1s = (x0 + 1 >= 0 && x0 + 1 < Tlen) ? w1 : 0.0f;
        const int i0 = (min(max(x0, 0), Tlen - 1) + st) * 512 + h * 64;
        const int i1 = (min(max(x0 + 1, 0), Tlen - 1) + st) * 512 + h * 64;
        u16x8 o0, o1;
#pragma unroll
        for (int q = 0; q < 4; ++q) {
            const float4 a  = *(const float4*)&v[i0 + d0 + q * 4];
            const float4 bq = *(const float4*)&v[i1 + d0 + q * 4];
            unsigned short e0 = f2bf((a.x * w0s + bq.x * w1s) * awv);
            unsigned short e1 = f2bf((a.y * w0s + bq.y * w1s) * awv);
            unsigned short e2 = f2bf((a.z * w0s + bq.z * w1s) * awv);
            unsigned short e3 = f2bf((a.w * w0s + bq.w * w1s) * awv);
            if (q == 0) { o0[0] = e0; o0[1] = e1; o0[2] = e2; o0[3] = e3; }
            if (q == 1) { o0[4] = e0; o0[5] = e1; o0[6] = e2; o0[7] = e3; }
            if (q == 2) { o1[0] = e0; o1[1] = e1; o1[2] = e2; o1[3] = e3; }
            if (q == 3) { o1[4] = e0; o1[5] = e1; o1[6] = e2; o1[7] = e3; }
        }
        const int c0 = (sub * 2)     ^ (pl & 7);
        const int c1 = (sub * 2 + 1) ^ (pl & 7);
        *(u16x8*)&cf[pl * 64 + c0 * 8] = o0;
        *(u16x8*)&cf[pl * 64 + c1 * 8] = o1;
    }
    __syncthreads();

    {
        const int wn   = tid >> 6, lane = tid & 63;
        const int lr   = lane & 15, lg = lane >> 4;

        s16x8 afrag[4][2];
#pragma unroll
        for (int mt = 0; mt < 4; ++mt) {
            const int row = mt * 16 + lr;
#pragma unroll
            for (int ks = 0; ks < 2; ++ks) {
                const int ch = (ks * 4 + lg) ^ (row & 7);
                afrag[mt][ks] = *(const s16x8*)&cf[row * 64 + ch * 8];
            }
        }
        f32x4 part[4];
#pragma unroll
        for (int mt = 0; mt < 4; ++mt) part[mt] = (f32x4){0.f, 0.f, 0.f, 0.f};

#pragma clang loop unroll(disable)
        for (int nt = 0; nt < 8; ++nt) {
            const int col = (wn * 8 + nt) * 16 + lr;
            const s16x8 b0 = *(const s16x8*)&Wb[col * 64 + lg * 8];
            const s16x8 b1 = *(const s16x8*)&Wb[col * 64 + 32 + lg * 8];
            const float bav = ba[col], wav = wal[col];
#pragma unroll
            for (int mt = 0; mt < 4; ++mt) {
                f32x4 acc = {0.f, 0.f, 0.f, 0.f};
                acc = __builtin_amdgcn_mfma_f32_16x16x32_bf16(afrag[mt][0], b0, acc, 0, 0, 0);
                acc = __builtin_amdgcn_mfma_f32_16x16x32_bf16(afrag[mt][1], b1, acc, 0, 0, 0);
#pragma unroll
                for (int r = 0; r < 4; ++r)
                    part[mt][r] += tanhf_fast(acc[r] + bav) * wav;
            }
        }
#pragma unroll
        for (int mt = 0; mt < 4; ++mt) {
#pragma unroll
            for (int r = 0; r < 4; ++r) {
                float s = part[mt][r];
                s += __shfl_xor(s, 1); s += __shfl_xor(s, 2);
                s += __shfl_xor(s, 4); s += __shfl_xor(s, 8);
                if (lr == 0) dots4[wn][mt * 16 + lg * 4 + r] = s;
            }
        }
    }
    __syncthreads();
    if (tid < 64)
        dsum[tid] = dots4[0][tid] + dots4[1][tid] + dots4[2][tid] + dots4[3][tid];
    __syncthreads();

    if (tid < 4) {
        float mx = -1e30f;
        for (int i = 0; i < 16; ++i) mx = fmaxf(mx, dsum[tid * 16 + i]);
        float sum = 0.f;
        for (int i = 0; i < 16; ++i) { float e = exp2f_fast((dsum[tid * 16 + i] - mx) * LOG2E); dsum[tid * 16 + i] = e; sum += e; }
        float inv = rcpf(sum);
        for (int i = 0; i < 16; ++i) dsum[tid * 16 + i] *= inv;
    }
    __syncthreads();

    {
        const int hl = tid >> 6, d = tid & 63;
        const int ch = d >> 3, e = d & 7;
        float s = 0.f;
#pragma unroll
        for (int p = 0; p < 16; ++p) {
            const int row = hl * 16 + p;
            s += dsum[hl * 16 + p] * bf2f(cf[row * 64 + ((ch ^ (row & 7)) * 8) + e]);
        }
        attdst[(size_t)b * 2048 + hh * 256 + tid] = f2bf(s);
    }
}

extern "C" void kernel_launch(void* const* d_in, const int* in_sizes, int n_in,
                              void* d_out, int out_size, void* d_ws, size_t ws_size,
                              hipStream_t stream) {
    const float* xt     = (const float*)d_in[0];
    const float* h0     = (const float*)d_in[1];   // (2,1024,512)
    const float* c0     = (const float*)d_in[2];
    const float* query  = (const float*)d_in[3];   // (1,1024,512)
    const float* refp   = (const float*)d_in[4];   // (1,1024,4,1)
    const float* inflat = (const float*)d_in[5];   // (1,1920,512)
    const int*   shapes = (const int*)d_in[6];
    const int*   starts = (const int*)d_in[7];
    const float* Wv     = (const float*)d_in[9];   // (512,512) (K,N)
    const float* bv     = (const float*)d_in[10];
    const float* Woff   = (const float*)d_in[11];  // (1024,128) (K,N)
    const float* boff   = (const float*)d_in[12];
    const float* Wattw  = (const float*)d_in[13];  // (1024,128)
    const float* battw  = (const float*)d_in[14];
    const float* Wctx   = (const float*)d_in[15];  // (64,512)
    const float* bctx   = (const float*)d_in[16];
    const float* Wh2a   = (const float*)d_in[17];  // (512,512) (K,N)
    const float* bh2a   = (const float*)d_in[18];
    const float* walpha = (const float*)d_in[19];
    const float* Wih0   = (const float*)d_in[21];  // (2048,1536) (N,K)
    const float* Whh0   = (const float*)d_in[22];  // (2048,512)
    const float* Wih1   = (const float*)d_in[23];  // (2048,512)
    const float* Whh1   = (const float*)d_in[24];  // (2048,512)

    float* out = (float*)d_out;
    float* ws  = (float*)d_ws;

    // ws layout (f32 units), lifetime-overlapped
    float*          v     = ws;                                   // 983040
    float*          obat  = ws + 983040;                          // 1024x768 [off|aw|atth]
    unsigned short* Acat  = (unsigned short*)(ws + 1769472);      // 1024x2048 bf16
    unsigned short* Bcat0 = (unsigned short*)(ws + 2818048);      // 2048x2048 bf16 (gate-ilv)
    unsigned short* Ainf  = (unsigned short*)(ws + 4915200);      // 1920x512 bf16
    unsigned short* Wvt   = (unsigned short*)(ws + 5406720);      // 512x512 bf16
    unsigned short* Wcat  = (unsigned short*)(ws + 5537792);      // 768x1024 bf16
    unsigned short* Ahq   = (unsigned short*)(ws + 5931008);      // 1024x1024 bf16
    unsigned short* Wb    = (unsigned short*)(ws + 6455296);      // 512x64 bf16 (Wctx^T)
    unsigned short* Ag1   = (unsigned short*)(ws + 7012352);      // 1024x1024 bf16
    unsigned short* Bcat1 = (unsigned short*)(ws + 7536640);      // 2048x1024 bf16 (gate-ilv)
    // split-K partial buffers (bf16 1024x2048 each), in DEAD regions at use
    unsigned short* gp0 = (unsigned short*)ws;                    // ws+0 .. +1048576
    unsigned short* gp1 = (unsigned short*)(ws + 4915200);        // .. +5963776

    const float* h00    = h0;
    const float* h_last = h0 + 524288;     // h0[1]
    float* h1  = out + 524288;             // h_new[0]
    float* c1  = out + 1572864;            // c_new[0]
    float* h2a = out;                      // first output
    float* h2b = out + 1048576;            // h_new[1]
    float* c2  = out + 2097152;            // c_new[1]

    // --- prep: all converts + transposes + zero-pad in ONE launch -----------
    { PJobs pj;
      pj.j[0]  = { xt,      Acat,          512,  2048, 512,  512,  0 };
      pj.j[1]  = { query,   Acat + 1024,   512,  2048, 512,  512,  0 };
      pj.j[2]  = { h00,     Acat + 1536,   512,  2048, 512,  512,  0 };
      pj.j[3]  = { h_last,  Ahq,           512,  1024, 512,  512,  0 };
      pj.j[4]  = { query,   Ahq + 512,     512,  1024, 512,  512,  0 };
      pj.j[5]  = { h_last,  Ag1 + 512,     512,  1024, 512,  512,  0 };
      pj.j[6]  = { Wih0,    Bcat0,         1536, 2048, 1536, 3072, 1 };
      pj.j[7]  = { Whh0,    Bcat0 + 1536,  512,  2048, 512,  1024, 1 };
      pj.j[8]  = { Wih1,    Bcat1,         512,  1024, 512,  1024, 1 };
      pj.j[9]  = { Whh1,    Bcat1 + 512,   512,  1024, 512,  1024, 1 };
      pj.j[10] = { inflat,  Ainf,          512,  512,  512,  960,  0 };
      pj.j[11] = { Wv,      Wvt,                     512, 512,  512, 256, 2 };
      pj.j[12] = { Woff,    Wcat,                    128, 1024, 1024, 128, 2 };
      pj.j[13] = { Wattw,   Wcat + 128 * 1024,       128, 1024, 1024, 128, 2 };
      pj.j[14] = { Wh2a,    Wcat + 256 * 1024,       512, 1024, 512, 256, 2 };
      pj.j[15] = { Wctx,    Wb,                      512, 64,   64,  32,  2 };
      pj.j[16] = { nullptr, Wcat + 256 * 1024 + 512, 512, 1024, 512, 256, 2 };
      prep<<<11232, 256, 0, stream>>>(pj); }

    // --- value + obat GEMMs fused into ONE launch (432 blocks, bias select) ---
    { GJobs gj;
      gj.j[0] = { Ainf, 512,  Wvt,  512,  bv,   bv,    bv,   0,   0,
                  v,    512, 512,  8,  240 };   // 1920x512: all cols -> bv[col]
      gj.j[1] = { Ahq,  1024, Wcat, 1024, boff, battw, bh2a, 128, 256,
                  obat, 768, 1024, 12, 192 };   // 1024x768: [boff|battw|bh2a]
      sgemm2<<<432, 256, 0, stream>>>(gj); }

    // --- fused deformable sampling + context attention (writes Acat[:,512:1024]) ---
    fused_att<<<2048, 256, 0, stream>>>(v, obat, refp, shapes, starts,
                                        Wb, bctx, walpha, Acat + 512);

    // LSTM0: split-K2 partials (BN=128 tiles, XCD-swizzled) + fused reduce/act
    sgemm_ks<<<512, 256, 0, stream>>>(Acat, 2048, Bcat0, 2048, gp0, gp1, 1024);
    red_lstm<<<2048, 256, 0, stream>>>(gp0, gp1, c0, h1, nullptr, Ag1, 1024, c1);
    // LSTM1: split-K2 partials + reduce/act (h2 -> out0 and h_new[1])
    sgemm_ks<<<512, 256, 0, stream>>>(Ag1, 1024, Bcat1, 1024, gp0, gp1, 512);
    red_lstm<<<2048, 256, 0, stream>>>(gp0, gp1, c0 + 524288, h2a, h2b, nullptr, 0, c2);
}